// Round 2
// baseline (4691.385 us; speedup 1.0000x reference)
//
#include <hip/hip_runtime.h>
#include <math.h>

// B=4, C=128, N=512, T=24, D=2, H=4, hd=32, WS=12, R=17, MLP=512
#define TOK 6291456   // 49152 * 128 floats (one full token buffer)

__device__ __forceinline__ float gelu_exact(float x){
    return 0.5f * x * (1.0f + erff(x * 0.70710678118654752f));
}

// ---------------------------------------------------------------------------
// s_mask normalizer. Probe ONLY the first 8704 bytes (in-bounds for u8/i32/f32
// storage of 8704 bools), classify by which byte residues are nonzero.
//   u8 : nonzero bytes at all residues        -> out[i] = raw[i]
//   i32: nonzero only at residue 0 (LE)       -> out[i] = raw[4i]
//   f32: nonzero only at residues 2,3 (0x3f80)-> out[i] = raw[4i+2]|raw[4i+3]
// ---------------------------------------------------------------------------
__global__ void normalize_mask(const unsigned char* __restrict__ raw,
                               unsigned char* __restrict__ outm){
    __shared__ int nz[4];
    if(threadIdx.x < 4) nz[threadIdx.x] = 0;
    __syncthreads();
    for(int i = threadIdx.x; i < 8704; i += 256){
        if(raw[i]) atomicOr(&nz[i & 3], 1);
    }
    __syncthreads();
    int mode; // 0=u8, 1=i32, 2=f32
    if(nz[1] | nz[2] | nz[3]) mode = nz[0] ? 0 : 2;
    else                      mode = 1;
    for(int i = threadIdx.x; i < 8704; i += 256){
        unsigned char v;
        if(mode == 0)      v = (raw[i] != 0);
        else if(mode == 1) v = (raw[4*i] != 0);
        else               v = ((raw[4*i+2] | raw[4*i+3]) != 0);
        outm[i] = v;
    }
}

// sec[m][n] = argmax_r assignment[m][n][r]  (exact one-hot f32)
__global__ void build_sec(const float* __restrict__ assign,
                          unsigned char* __restrict__ sec){
    int id = blockIdx.x * 256 + threadIdx.x;
    if(id >= 512*512) return;
    const float* p = assign + (size_t)id * 17;
    int rr = 0;
    #pragma unroll
    for(int r = 0; r < 17; r++) if(p[r] > 0.5f) rr = r;
    sec[id] = (unsigned char)rr;
}

// counting sort of each sec row -> perm (n grouped by bucket), bnd offsets
__global__ __launch_bounds__(64) void build_perm(const unsigned char* __restrict__ sec,
                                                 unsigned short* __restrict__ perm,
                                                 int* __restrict__ bnd){
    __shared__ unsigned char row[512];
    int m = blockIdx.x;
    int lane = threadIdx.x;
    for(int i = lane; i < 512; i += 64) row[i] = sec[m*512 + i];
    __syncthreads();
    int cnt = 0;
    if(lane < 17){
        for(int n = 0; n < 512; n++) cnt += (row[n] == lane);
    }
    int incl = cnt;
    for(int i = 1; i < 32; i <<= 1){
        int v = __shfl_up(incl, i);
        if(lane >= i) incl += v;
    }
    int start = incl - cnt;
    if(lane < 18) bnd[m*18 + lane] = start;
    if(lane < 17){
        int idx = start;
        for(int n = 0; n < 512; n++)
            if(row[n] == lane) perm[m*512 + (idx++)] = (unsigned short)n;
    }
}

// h[(b*N+n)*T+t][c] = x[b][c][n][t] + pos_emb[t][c]
__global__ __launch_bounds__(128) void stage0(const float* __restrict__ x,
                                              const float* __restrict__ pos,
                                              float* __restrict__ h){
    __shared__ float l[128*25];
    int bid = blockIdx.x;
    int b = bid >> 9, n = bid & 511;
    int tid = threadIdx.x;
    const float* xb = x + (size_t)b*1572864 + (size_t)n*24;
    for(int it = 0; it < 24; it++){
        int i = it*128 + tid;
        int c = i / 24, t = i % 24;
        l[c*25 + t] = xb[(size_t)c*12288 + t];
    }
    __syncthreads();
    float* hb = h + ((size_t)(b*512 + n)) * 24 * 128;
    for(int t = 0; t < 24; t++){
        hb[t*128 + tid] = l[tid*25 + t] + pos[t*128 + tid];
    }
}

// E[(b*T+t)*N+n][c] = A[(b*N+n)*T+t][c]
__global__ void t2s(const float* __restrict__ a, float* __restrict__ e){
    size_t idx = (size_t)blockIdx.x * 256 + threadIdx.x;
    int c = (int)(idx & 127);
    size_t rest = idx >> 7;
    int n = (int)(rest & 511); rest >>= 9;
    int t = (int)(rest % 24);
    int b = (int)(rest / 24);
    e[idx] = a[(((size_t)(b*512 + n))*24 + t)*128 + c];
}

// out[b][c][n][t] = E[(b*T+t)*N+n][c]
__global__ __launch_bounds__(128) void finalt(const float* __restrict__ e,
                                              float* __restrict__ out){
    __shared__ float l[128*25];
    int bid = blockIdx.x;
    int b = bid >> 9, n = bid & 511;
    int tid = threadIdx.x;
    for(int t = 0; t < 24; t++){
        l[tid*25 + t] = e[(((size_t)(b*24 + t))*512 + n)*128 + tid];
    }
    __syncthreads();
    float* ob = out + (size_t)b*1572864 + (size_t)n*24;
    for(int it = 0; it < 24; it++){
        int i = it*128 + tid;
        int c = i / 24, t = i % 24;
        ob[(size_t)c*12288 + t] = l[c*25 + t];
    }
}

// LayerNorm over C=128, one wave per token
__global__ __launch_bounds__(256) void ln_kernel(const float* __restrict__ in,
                                                 float* __restrict__ out,
                                                 const float* __restrict__ g,
                                                 const float* __restrict__ b){
    int w = threadIdx.x >> 6, lane = threadIdx.x & 63;
    int tok = blockIdx.x * 4 + w;
    const float* row = in + (size_t)tok * 128;
    float x0 = row[lane], x1 = row[lane + 64];
    float s  = x0 + x1;
    float s2 = x0*x0 + x1*x1;
    #pragma unroll
    for(int m = 1; m < 64; m <<= 1){
        s  += __shfl_xor(s,  m);
        s2 += __shfl_xor(s2, m);
    }
    float mean = s * (1.0f/128.0f);
    float var  = s2 * (1.0f/128.0f) - mean*mean;
    float rstd = rsqrtf(var + 1e-5f);
    float* o = out + (size_t)tok * 128;
    o[lane]      = (x0 - mean) * rstd * g[lane]      + b[lane];
    o[lane + 64] = (x1 - mean) * rstd * g[lane + 64] + b[lane + 64];
}

// fp32 GEMM out[M,N] = A[M,K] @ W[K,N] (+bias)(+gelu)(+res), 64x64 tile
template<bool BIAS, bool GELU, bool RES>
__global__ __launch_bounds__(256) void gemm64(const float* __restrict__ A,
                                              const float* __restrict__ W,
                                              const float* __restrict__ bias,
                                              const float* __restrict__ res,
                                              float* __restrict__ out,
                                              int N, int K){
    __shared__ float As[32*68];
    __shared__ float Ws[32*68];
    const int tid = threadIdx.x;
    const int tm = tid >> 4;
    const int tn = tid & 15;
    const int m0 = blockIdx.y * 64;
    const int n0 = blockIdx.x * 64;

    float acc[4][4];
    #pragma unroll
    for(int i = 0; i < 4; i++)
        #pragma unroll
        for(int j = 0; j < 4; j++) acc[i][j] = 0.0f;

    for(int k0 = 0; k0 < K; k0 += 32){
        __syncthreads();
        #pragma unroll
        for(int t = 0; t < 2; t++){
            int s = tid + t*256;
            int row = s >> 3, kq = s & 7;
            float4 a4 = *(const float4*)(A + (size_t)(m0 + row)*K + k0 + kq*4);
            As[(kq*4+0)*68 + row] = a4.x;
            As[(kq*4+1)*68 + row] = a4.y;
            As[(kq*4+2)*68 + row] = a4.z;
            As[(kq*4+3)*68 + row] = a4.w;
            int k = s >> 4, nq = s & 15;
            *(float4*)(Ws + k*68 + nq*4) =
                *(const float4*)(W + (size_t)(k0 + k)*N + n0 + nq*4);
        }
        __syncthreads();
        #pragma unroll
        for(int kk = 0; kk < 32; kk++){
            float4 av = *(const float4*)(As + kk*68 + tm*4);
            float4 bv = *(const float4*)(Ws + kk*68 + tn*4);
            acc[0][0] += av.x*bv.x; acc[0][1] += av.x*bv.y; acc[0][2] += av.x*bv.z; acc[0][3] += av.x*bv.w;
            acc[1][0] += av.y*bv.x; acc[1][1] += av.y*bv.y; acc[1][2] += av.y*bv.z; acc[1][3] += av.y*bv.w;
            acc[2][0] += av.z*bv.x; acc[2][1] += av.z*bv.y; acc[2][2] += av.z*bv.z; acc[2][3] += av.z*bv.w;
            acc[3][0] += av.w*bv.x; acc[3][1] += av.w*bv.y; acc[3][2] += av.w*bv.z; acc[3][3] += av.w*bv.w;
        }
    }

    float4 b4 = make_float4(0.f,0.f,0.f,0.f);
    if(BIAS) b4 = *(const float4*)(bias + n0 + tn*4);
    #pragma unroll
    for(int i = 0; i < 4; i++){
        int m = m0 + tm*4 + i;
        float4 v = make_float4(acc[i][0], acc[i][1], acc[i][2], acc[i][3]);
        if(BIAS){ v.x += b4.x; v.y += b4.y; v.z += b4.z; v.w += b4.w; }
        if(GELU){
            v.x = gelu_exact(v.x); v.y = gelu_exact(v.y);
            v.z = gelu_exact(v.z); v.w = gelu_exact(v.w);
        }
        if(RES){
            float4 r4 = *(const float4*)(res + (size_t)m*N + n0 + tn*4);
            v.x += r4.x; v.y += r4.y; v.z += r4.z; v.w += r4.w;
        }
        *(float4*)(out + (size_t)m*N + n0 + tn*4) = v;
    }
}

// temporal windowed causal attention; qkv rows [q|k|v] 384 wide
__global__ __launch_bounds__(256) void tattn(const float* __restrict__ qkv,
                                             float* __restrict__ out){
    __shared__ float l[12*388];
    int w = blockIdx.x;
    const float* src = qkv + (size_t)w * 12 * 384;
    for(int i = threadIdx.x; i < 12*384; i += 256){
        int q = i / 384, c = i % 384;
        l[q*388 + c] = src[i];
    }
    __syncthreads();
    int h = threadIdx.x >> 6, lane = threadIdx.x & 63;
    if(lane < 12){
        int q = lane;
        const float scale = 0.17677669529663687f;
        float qv[32];
        #pragma unroll
        for(int d = 0; d < 32; d++) qv[d] = l[q*388 + h*32 + d];
        float sc[12];
        #pragma unroll
        for(int k = 0; k < 12; k++){
            float dot = 0.f;
            #pragma unroll
            for(int d = 0; d < 32; d++) dot += qv[d] * l[k*388 + 128 + h*32 + d];
            sc[k] = (k <= q) ? dot * scale : -1e30f;
        }
        float mx = sc[0];
        #pragma unroll
        for(int k = 1; k < 12; k++) mx = fmaxf(mx, sc[k]);
        float sum = 0.f;
        #pragma unroll
        for(int k = 0; k < 12; k++){ sc[k] = expf(sc[k] - mx); sum += sc[k]; }
        float inv = 1.0f / sum;
        float* orow = out + (size_t)(w*12 + q) * 128 + h*32;
        #pragma unroll
        for(int d = 0; d < 32; d++){
            float o = 0.f;
            #pragma unroll
            for(int k = 0; k < 12; k++) o += sc[k] * l[k*388 + 256 + h*32 + d];
            orow[d] = o * inv;
        }
    }
}

// fused spatial attention over one chunk of bt values; pointers are chunk-base
__global__ __launch_bounds__(256) void sattn(const float* __restrict__ qbuf,
                                             const float* __restrict__ skv,
                                             const unsigned short* __restrict__ perm,
                                             const int* __restrict__ bnd,
                                             const unsigned char* __restrict__ mask,
                                             const float* __restrict__ bias,
                                             float* __restrict__ out){
    __shared__ float kv[2][17][256];
    __shared__ float ql[2][128];
    __shared__ float lg[2][4][17];
    __shared__ float al[2][4][17];
    __shared__ unsigned short pml[2][512];
    __shared__ int bndl[2][18];
    __shared__ int mkl[2][17];

    int bid = blockIdx.x;
    int b  = bid >> 8;          // bt index within chunk
    int m0 = (bid & 255) * 2;
    int tid = threadIdx.x;

    { int mi = tid >> 7, c = tid & 127;
      ql[mi][c] = qbuf[((size_t)(b*512 + m0 + mi))*128 + c]; }
    for(int i = tid; i < 1024; i += 256){
        int mi = i >> 9, j = i & 511;
        pml[mi][j] = perm[(m0 + mi)*512 + j];
    }
    if(tid < 36){ int mi = tid/18, r = tid%18; bndl[mi][r] = bnd[(m0+mi)*18 + r]; }
    if(tid < 34){ int mi = tid/17, r = tid%17; mkl[mi][r] = mask[(m0+mi)*17 + r]; }
    __syncthreads();

    const float* skvb = skv + (size_t)b*512*256 + tid;
    #pragma unroll
    for(int mi = 0; mi < 2; mi++){
        for(int r = 0; r < 17; r++){
            if(mkl[mi][r]) continue;
            int s = bndl[mi][r], e = bndl[mi][r+1];
            float a0=0.f, a1=0.f, a2=0.f, a3=0.f;
            int i = s;
            for(; i + 4 <= e; i += 4){
                a0 += skvb[(int)pml[mi][i  ] * 256];
                a1 += skvb[(int)pml[mi][i+1] * 256];
                a2 += skvb[(int)pml[mi][i+2] * 256];
                a3 += skvb[(int)pml[mi][i+3] * 256];
            }
            for(; i < e; i++) a0 += skvb[(int)pml[mi][i] * 256];
            kv[mi][r][tid] = (a0 + a1) + (a2 + a3);
        }
    }
    __syncthreads();

    { int h = tid >> 6; int mi = (tid >> 5) & 1; int d = tid & 31;
      float qv = ql[mi][h*32 + d];
      for(int r = 0; r < 17; r++){
          if(mkl[mi][r]) continue;
          float v = qv * kv[mi][r][h*32 + d];
          v += __shfl_xor(v, 16); v += __shfl_xor(v, 8);
          v += __shfl_xor(v, 4);  v += __shfl_xor(v, 2); v += __shfl_xor(v, 1);
          if(d == 0) lg[mi][h][r] = v * 0.17677669529663687f + bias[h*17 + r];
      }
    }
    __syncthreads();

    if(tid < 8){
        int mi = tid >> 2, h = tid & 3;
        float mx = -1e30f;
        for(int r = 0; r < 17; r++) if(!mkl[mi][r]) mx = fmaxf(mx, lg[mi][h][r]);
        float sum = 0.f;
        for(int r = 0; r < 17; r++){
            if(!mkl[mi][r]){ float e = expf(lg[mi][h][r] - mx); al[mi][h][r] = e; sum += e; }
            else al[mi][h][r] = 0.f;
        }
        float inv = 1.0f / sum;
        for(int r = 0; r < 17; r++) al[mi][h][r] *= inv;
    }
    __syncthreads();

    { int mi = tid >> 7, c = tid & 127, h = c >> 5;
      float o = 0.f;
      for(int r = 0; r < 17; r++){
          if(mkl[mi][r]) continue;
          o += al[mi][h][r] * kv[mi][r][128 + c];
      }
      out[((size_t)(b*512 + m0 + mi))*128 + c] = o;
    }
}

// ---------------------------------------------------------------------------
extern "C" void kernel_launch(void* const* d_in, const int* in_sizes, int n_in,
                              void* d_out, int out_size, void* d_ws, size_t ws_size,
                              hipStream_t stream){
    const float* x        = (const float*)d_in[0];
    const float* pos      = (const float*)d_in[1];
    const float* t_qkv_w  = (const float*)d_in[2];
    const float* t_proj_w = (const float*)d_in[3];
    const float* t_proj_b = (const float*)d_in[4];
    const float* t_ln_g   = (const float*)d_in[5];
    const float* t_ln_b   = (const float*)d_in[6];
    const float* t_ff_w1  = (const float*)d_in[7];
    const float* t_ff_b1  = (const float*)d_in[8];
    const float* t_ff_w2  = (const float*)d_in[9];
    const float* t_ff_b2  = (const float*)d_in[10];
    const float* assign   = (const float*)d_in[11];
    const unsigned char* s_mask_raw = (const unsigned char*)d_in[12];  // dict order!
    const float* s_q_w    = (const float*)d_in[13];
    const float* s_kv_w   = (const float*)d_in[14];
    const float* s_bias   = (const float*)d_in[15];
    const float* s_proj_w = (const float*)d_in[16];
    const float* s_proj_b = (const float*)d_in[17];
    const float* s_ln_g   = (const float*)d_in[18];
    const float* s_ln_b   = (const float*)d_in[19];
    const float* s_ff_w1  = (const float*)d_in[20];
    const float* s_ff_b1  = (const float*)d_in[21];
    const float* s_ff_w2  = (const float*)d_in[22];
    const float* s_ff_b2  = (const float*)d_in[23];

    float* ws = (float*)d_ws;
    float* Cb = (float*)d_out;   // reused as full-M scratch (attn out / LN out)

    // CH=1 (unchunked) needs ~153 MB of ws; CH=4 needs ~51.2 MB.
    const int CH = (ws_size >= (size_t)160*1024*1024) ? 1 : 4;
    float* A  = ws;                                    // temporal tokens / spatial scratch(CH=4)
    float* TS = ws + TOK;                              // temporal scratch
    float* E  = (CH==1) ? (ws + 5*(size_t)TOK) : (ws + TOK);   // spatial tokens
    float* SS = (CH==1) ? TS : A;                      // spatial scratch
    char*  sb = (char*)(ws + ((CH==1)? 6*(size_t)TOK : 2*(size_t)TOK));
    unsigned char*  sec   = (unsigned char*)sb;              // 262144 B
    unsigned short* perm  = (unsigned short*)(sb + 262144);  // 524288 B
    int*            bnd   = (int*)(sb + 786432);             // 36864 B
    unsigned char*  maskn = (unsigned char*)(sb + 823296);   // 8704 B

    const int rows = 49152 / CH;       // M rows per chunk (multiple of 1536)
    const int nb   = 96 / CH;          // bt values per spatial chunk

    normalize_mask<<<1, 256, 0, stream>>>(s_mask_raw, maskn);
    build_sec<<<1024, 256, 0, stream>>>(assign, sec);
    build_perm<<<512, 64, 0, stream>>>(sec, perm, bnd);
    stage0<<<2048, 128, 0, stream>>>(x, pos, A);

    for(int d = 0; d < 2; d++){
        for(int c = 0; c < CH; c++){
            const float* Ac = A + (size_t)c*rows*128;
            gemm64<false,false,false><<<dim3(6, rows/64), 256, 0, stream>>>(
                Ac, t_qkv_w + d*49152, nullptr, nullptr, TS, 384, 128);
            tattn<<<rows/12, 256, 0, stream>>>(TS, Cb + (size_t)c*rows*128);
        }
        gemm64<true,false,true><<<dim3(2,768), 256, 0, stream>>>(
            Cb, t_proj_w + d*16384, t_proj_b + d*128, A, A, 128, 128);
        ln_kernel<<<12288, 256, 0, stream>>>(A, Cb, t_ln_g + d*128, t_ln_b + d*128);
        for(int c = 0; c < CH; c++){
            float* Ac = A + (size_t)c*rows*128;
            gemm64<true,true,false><<<dim3(8, rows/64), 256, 0, stream>>>(
                Cb + (size_t)c*rows*128, t_ff_w1 + d*65536, t_ff_b1 + d*512,
                nullptr, TS, 512, 128);
            gemm64<true,false,true><<<dim3(2, rows/64), 256, 0, stream>>>(
                TS, t_ff_w2 + d*65536, t_ff_b2 + d*128, Ac, Ac, 128, 512);
        }
    }

    t2s<<<24576, 256, 0, stream>>>(A, E);

    for(int d = 0; d < 2; d++){
        gemm64<false,false,false><<<dim3(2,768), 256, 0, stream>>>(
            E, s_q_w + d*16384, nullptr, nullptr, Cb, 128, 128);
        for(int c = 0; c < CH; c++){
            float* Ec = E + (size_t)c*nb*512*128;
            float* att = SS + (size_t)nb*512*256;
            gemm64<false,false,false><<<dim3(4, nb*512/64), 256, 0, stream>>>(
                Ec, s_kv_w + d*32768, nullptr, nullptr, SS, 256, 128);
            sattn<<<nb*256, 256, 0, stream>>>(
                Cb + (size_t)c*nb*512*128, SS, perm, bnd, maskn, s_bias + d*68, att);
            gemm64<true,false,true><<<dim3(2, nb*512/64), 256, 0, stream>>>(
                att, s_proj_w + d*16384, s_proj_b + d*128, Ec, Ec, 128, 128);
        }
        ln_kernel<<<12288, 256, 0, stream>>>(E, Cb, s_ln_g + d*128, s_ln_b + d*128);
        for(int c = 0; c < CH; c++){
            float* Ec = E + (size_t)c*rows*128;
            gemm64<true,true,false><<<dim3(8, rows/64), 256, 0, stream>>>(
                Cb + (size_t)c*rows*128, s_ff_w1 + d*65536, s_ff_b1 + d*512,
                nullptr, SS, 512, 128);
            gemm64<true,false,true><<<dim3(2, rows/64), 256, 0, stream>>>(
                SS, s_ff_w2 + d*65536, s_ff_b2 + d*128, Ec, Ec, 128, 512);
        }
    }

    finalt<<<2048, 128, 0, stream>>>(E, (float*)d_out);
}

// Round 3
// 3009.327 us; speedup vs baseline: 1.5589x; 1.5589x over previous
//
#include <hip/hip_runtime.h>
#include <math.h>

// B=4, C=128, N=512, T=24, D=2, H=4, hd=32, WS=12, R=17, MLP=512
#define TOK 6291456   // 49152 * 128 floats (one full token buffer)

__device__ __forceinline__ float gelu_exact(float x){
    return 0.5f * x * (1.0f + erff(x * 0.70710678118654752f));
}
__device__ __forceinline__ void f4add(float4& a, const float4 b){
    a.x += b.x; a.y += b.y; a.z += b.z; a.w += b.w;
}

// ---------------------------------------------------------------------------
// s_mask normalizer (probe first 8704 bytes only; classify u8/i32/f32 layout)
// ---------------------------------------------------------------------------
__global__ void normalize_mask(const unsigned char* __restrict__ raw,
                               unsigned char* __restrict__ outm){
    __shared__ int nz[4];
    if(threadIdx.x < 4) nz[threadIdx.x] = 0;
    __syncthreads();
    for(int i = threadIdx.x; i < 8704; i += 256){
        if(raw[i]) atomicOr(&nz[i & 3], 1);
    }
    __syncthreads();
    int mode; // 0=u8, 1=i32, 2=f32
    if(nz[1] | nz[2] | nz[3]) mode = nz[0] ? 0 : 2;
    else                      mode = 1;
    for(int i = threadIdx.x; i < 8704; i += 256){
        unsigned char v;
        if(mode == 0)      v = (raw[i] != 0);
        else if(mode == 1) v = (raw[4*i] != 0);
        else               v = ((raw[4*i+2] | raw[4*i+3]) != 0);
        outm[i] = v;
    }
}

// sec[m][n] = argmax_r assignment[m][n][r]  (exact one-hot f32)
__global__ void build_sec(const float* __restrict__ assign,
                          unsigned char* __restrict__ sec){
    int id = blockIdx.x * 256 + threadIdx.x;
    if(id >= 512*512) return;
    const float* p = assign + (size_t)id * 17;
    int rr = 0;
    #pragma unroll
    for(int r = 0; r < 17; r++) if(p[r] > 0.5f) rr = r;
    sec[id] = (unsigned char)rr;
}

// counting sort of each sec row -> perm/bnd, plus greedy LPT bucket->wave map
__global__ __launch_bounds__(64) void build_perm(const unsigned char* __restrict__ sec,
                                                 const unsigned char* __restrict__ maskn,
                                                 unsigned short* __restrict__ perm,
                                                 int* __restrict__ bnd,
                                                 unsigned char* __restrict__ gmap){
    __shared__ unsigned char row[512];
    __shared__ int cnts[17];
    int m = blockIdx.x;
    int lane = threadIdx.x;
    for(int i = lane; i < 512; i += 64) row[i] = sec[m*512 + i];
    __syncthreads();
    int cnt = 0;
    if(lane < 17){
        for(int n = 0; n < 512; n++) cnt += (row[n] == lane);
        cnts[lane] = cnt;
    }
    int incl = cnt;
    for(int i = 1; i < 32; i <<= 1){
        int v = __shfl_up(incl, i);
        if(lane >= i) incl += v;
    }
    int start = incl - cnt;
    if(lane < 18) bnd[m*18 + lane] = start;
    if(lane < 17){
        int idx = start;
        for(int n = 0; n < 512; n++)
            if(row[n] == lane) perm[m*512 + (idx++)] = (unsigned short)n;
    }
    __syncthreads();
    if(lane == 0){
        // greedy LPT: assign unmasked buckets to 4 waves, balancing row counts
        int   sz[17]; int used[17]; int load[4] = {0,0,0,0};
        unsigned char gm[17];
        for(int r = 0; r < 17; r++){
            sz[r] = maskn[m*17 + r] ? 0 : cnts[r];
            used[r] = 0; gm[r] = 0;
        }
        for(int it = 0; it < 17; it++){
            int best = -1, bs = -1;
            for(int r = 0; r < 17; r++)
                if(!used[r] && sz[r] > bs){ bs = sz[r]; best = r; }
            int bin = 0;
            for(int g = 1; g < 4; g++) if(load[g] < load[bin]) bin = g;
            used[best] = 1; gm[best] = (unsigned char)bin; load[bin] += sz[best];
        }
        for(int r = 0; r < 17; r++) gmap[m*17 + r] = gm[r];
    }
}

// h[(b*N+n)*T+t][c] = x[b][c][n][t] + pos_emb[t][c]
__global__ __launch_bounds__(128) void stage0(const float* __restrict__ x,
                                              const float* __restrict__ pos,
                                              float* __restrict__ h){
    __shared__ float l[128*25];
    int bid = blockIdx.x;
    int b = bid >> 9, n = bid & 511;
    int tid = threadIdx.x;
    const float* xb = x + (size_t)b*1572864 + (size_t)n*24;
    for(int it = 0; it < 24; it++){
        int i = it*128 + tid;
        int c = i / 24, t = i % 24;
        l[c*25 + t] = xb[(size_t)c*12288 + t];
    }
    __syncthreads();
    float* hb = h + ((size_t)(b*512 + n)) * 24 * 128;
    for(int t = 0; t < 24; t++){
        hb[t*128 + tid] = l[tid*25 + t] + pos[t*128 + tid];
    }
}

// E[(b*T+t)*N+n][c] = A[(b*N+n)*T+t][c]
__global__ void t2s(const float* __restrict__ a, float* __restrict__ e){
    size_t idx = (size_t)blockIdx.x * 256 + threadIdx.x;
    int c = (int)(idx & 127);
    size_t rest = idx >> 7;
    int n = (int)(rest & 511); rest >>= 9;
    int t = (int)(rest % 24);
    int b = (int)(rest / 24);
    e[idx] = a[(((size_t)(b*512 + n))*24 + t)*128 + c];
}

// out[b][c][n][t] = E[(b*T+t)*N+n][c]
__global__ __launch_bounds__(128) void finalt(const float* __restrict__ e,
                                              float* __restrict__ out){
    __shared__ float l[128*25];
    int bid = blockIdx.x;
    int b = bid >> 9, n = bid & 511;
    int tid = threadIdx.x;
    for(int t = 0; t < 24; t++){
        l[tid*25 + t] = e[(((size_t)(b*24 + t))*512 + n)*128 + tid];
    }
    __syncthreads();
    float* ob = out + (size_t)b*1572864 + (size_t)n*24;
    for(int it = 0; it < 24; it++){
        int i = it*128 + tid;
        int c = i / 24, t = i % 24;
        ob[(size_t)c*12288 + t] = l[c*25 + t];
    }
}

// LayerNorm over C=128, one wave per token
__global__ __launch_bounds__(256) void ln_kernel(const float* __restrict__ in,
                                                 float* __restrict__ out,
                                                 const float* __restrict__ g,
                                                 const float* __restrict__ b){
    int w = threadIdx.x >> 6, lane = threadIdx.x & 63;
    int tok = blockIdx.x * 4 + w;
    const float* row = in + (size_t)tok * 128;
    float x0 = row[lane], x1 = row[lane + 64];
    float s  = x0 + x1;
    float s2 = x0*x0 + x1*x1;
    #pragma unroll
    for(int m = 1; m < 64; m <<= 1){
        s  += __shfl_xor(s,  m);
        s2 += __shfl_xor(s2, m);
    }
    float mean = s * (1.0f/128.0f);
    float var  = s2 * (1.0f/128.0f) - mean*mean;
    float rstd = rsqrtf(var + 1e-5f);
    float* o = out + (size_t)tok * 128;
    o[lane]      = (x0 - mean) * rstd * g[lane]      + b[lane];
    o[lane + 64] = (x1 - mean) * rstd * g[lane + 64] + b[lane + 64];
}

// fp32 GEMM out[M,N] = A[M,K] @ W[K,N] (+bias)(+gelu)(+res), 64x64 tile
template<bool BIAS, bool GELU, bool RES>
__global__ __launch_bounds__(256) void gemm64(const float* __restrict__ A,
                                              const float* __restrict__ W,
                                              const float* __restrict__ bias,
                                              const float* __restrict__ res,
                                              float* __restrict__ out,
                                              int N, int K){
    __shared__ float As[32*68];
    __shared__ float Ws[32*68];
    const int tid = threadIdx.x;
    const int tm = tid >> 4;
    const int tn = tid & 15;
    const int m0 = blockIdx.y * 64;
    const int n0 = blockIdx.x * 64;

    float acc[4][4];
    #pragma unroll
    for(int i = 0; i < 4; i++)
        #pragma unroll
        for(int j = 0; j < 4; j++) acc[i][j] = 0.0f;

    for(int k0 = 0; k0 < K; k0 += 32){
        __syncthreads();
        #pragma unroll
        for(int t = 0; t < 2; t++){
            int s = tid + t*256;
            int row = s >> 3, kq = s & 7;
            float4 a4 = *(const float4*)(A + (size_t)(m0 + row)*K + k0 + kq*4);
            As[(kq*4+0)*68 + row] = a4.x;
            As[(kq*4+1)*68 + row] = a4.y;
            As[(kq*4+2)*68 + row] = a4.z;
            As[(kq*4+3)*68 + row] = a4.w;
            int k = s >> 4, nq = s & 15;
            *(float4*)(Ws + k*68 + nq*4) =
                *(const float4*)(W + (size_t)(k0 + k)*N + n0 + nq*4);
        }
        __syncthreads();
        #pragma unroll
        for(int kk = 0; kk < 32; kk++){
            float4 av = *(const float4*)(As + kk*68 + tm*4);
            float4 bv = *(const float4*)(Ws + kk*68 + tn*4);
            acc[0][0] += av.x*bv.x; acc[0][1] += av.x*bv.y; acc[0][2] += av.x*bv.z; acc[0][3] += av.x*bv.w;
            acc[1][0] += av.y*bv.x; acc[1][1] += av.y*bv.y; acc[1][2] += av.y*bv.z; acc[1][3] += av.y*bv.w;
            acc[2][0] += av.z*bv.x; acc[2][1] += av.z*bv.y; acc[2][2] += av.z*bv.z; acc[2][3] += av.z*bv.w;
            acc[3][0] += av.w*bv.x; acc[3][1] += av.w*bv.y; acc[3][2] += av.w*bv.z; acc[3][3] += av.w*bv.w;
        }
    }

    float4 b4 = make_float4(0.f,0.f,0.f,0.f);
    if(BIAS) b4 = *(const float4*)(bias + n0 + tn*4);
    #pragma unroll
    for(int i = 0; i < 4; i++){
        int m = m0 + tm*4 + i;
        float4 v = make_float4(acc[i][0], acc[i][1], acc[i][2], acc[i][3]);
        if(BIAS){ v.x += b4.x; v.y += b4.y; v.z += b4.z; v.w += b4.w; }
        if(GELU){
            v.x = gelu_exact(v.x); v.y = gelu_exact(v.y);
            v.z = gelu_exact(v.z); v.w = gelu_exact(v.w);
        }
        if(RES){
            float4 r4 = *(const float4*)(res + (size_t)m*N + n0 + tn*4);
            v.x += r4.x; v.y += r4.y; v.z += r4.z; v.w += r4.w;
        }
        *(float4*)(out + (size_t)m*N + n0 + tn*4) = v;
    }
}

// temporal windowed causal attention; qkv rows [q|k|v] 384 wide
__global__ __launch_bounds__(256) void tattn(const float* __restrict__ qkv,
                                             float* __restrict__ out){
    __shared__ float l[12*388];
    int w = blockIdx.x;
    const float* src = qkv + (size_t)w * 12 * 384;
    for(int i = threadIdx.x; i < 12*384; i += 256){
        int q = i / 384, c = i % 384;
        l[q*388 + c] = src[i];
    }
    __syncthreads();
    int h = threadIdx.x >> 6, lane = threadIdx.x & 63;
    if(lane < 12){
        int q = lane;
        const float scale = 0.17677669529663687f;
        float qv[32];
        #pragma unroll
        for(int d = 0; d < 32; d++) qv[d] = l[q*388 + h*32 + d];
        float sc[12];
        #pragma unroll
        for(int k = 0; k < 12; k++){
            float dot = 0.f;
            #pragma unroll
            for(int d = 0; d < 32; d++) dot += qv[d] * l[k*388 + 128 + h*32 + d];
            sc[k] = (k <= q) ? dot * scale : -1e30f;
        }
        float mx = sc[0];
        #pragma unroll
        for(int k = 1; k < 12; k++) mx = fmaxf(mx, sc[k]);
        float sum = 0.f;
        #pragma unroll
        for(int k = 0; k < 12; k++){ sc[k] = expf(sc[k] - mx); sum += sc[k]; }
        float inv = 1.0f / sum;
        float* orow = out + (size_t)(w*12 + q) * 128 + h*32;
        #pragma unroll
        for(int d = 0; d < 32; d++){
            float o = 0.f;
            #pragma unroll
            for(int k = 0; k < 12; k++) o += sc[k] * l[k*388 + 256 + h*32 + d];
            orow[d] = o * inv;
        }
    }
}

// ---------------------------------------------------------------------------
// fused spatial attention. Phase 2 rework: lane owns a float4 channel-quad
// (64 lanes x 16B = full 1KB row per wave-instr); wave g owns the buckets
// with gmap[m][r]==g (greedy-balanced in build_perm) -> no cross-wave combine.
// ---------------------------------------------------------------------------
__global__ __launch_bounds__(256) void sattn(const float* __restrict__ qbuf,
                                             const float* __restrict__ skv,
                                             const unsigned short* __restrict__ perm,
                                             const int* __restrict__ bnd,
                                             const unsigned char* __restrict__ mask,
                                             const unsigned char* __restrict__ gmap,
                                             const float* __restrict__ bias,
                                             float* __restrict__ out){
    __shared__ float kv[2][17][256];
    __shared__ float ql[2][128];
    __shared__ float lg[2][4][17];
    __shared__ float al[2][4][17];
    __shared__ unsigned short pml[2][512];
    __shared__ int bndl[2][18];
    __shared__ int mkl[2][17];
    __shared__ int gml[2][17];

    int bid = blockIdx.x;
    int b  = bid >> 8;          // bt index within chunk
    int m0 = (bid & 255) * 2;
    int tid = threadIdx.x;

    { int mi = tid >> 7, c = tid & 127;
      ql[mi][c] = qbuf[((size_t)(b*512 + m0 + mi))*128 + c]; }
    for(int i = tid; i < 1024; i += 256){
        int mi = i >> 9, j = i & 511;
        pml[mi][j] = perm[(m0 + mi)*512 + j];
    }
    if(tid < 36){ int mi = tid/18, r = tid%18; bndl[mi][r] = bnd[(m0+mi)*18 + r]; }
    if(tid < 34){ int mi = tid/17, r = tid%17; mkl[mi][r] = mask[(m0+mi)*17 + r]; }
    if(tid >= 64 && tid < 98){
        int j = tid - 64; int mi = j/17, r = j%17;
        gml[mi][r] = gmap[(m0+mi)*17 + r];
    }
    __syncthreads();

    // phase 2: segmented bucket sums, float4 per lane, buckets per wave
    { int g = tid >> 6, lane = tid & 63;
      const float* skvb = skv + (size_t)b*512*256 + lane*4;
      #pragma unroll
      for(int mi = 0; mi < 2; mi++){
          for(int r = 0; r < 17; r++){
              if(mkl[mi][r] || gml[mi][r] != g) continue;
              int s = bndl[mi][r], e = bndl[mi][r+1];
              float4 a0 = make_float4(0,0,0,0), a1 = a0, a2 = a0, a3 = a0;
              int i = s;
              for(; i + 4 <= e; i += 4){
                  f4add(a0, *(const float4*)(skvb + (int)pml[mi][i  ] * 256));
                  f4add(a1, *(const float4*)(skvb + (int)pml[mi][i+1] * 256));
                  f4add(a2, *(const float4*)(skvb + (int)pml[mi][i+2] * 256));
                  f4add(a3, *(const float4*)(skvb + (int)pml[mi][i+3] * 256));
              }
              for(; i < e; i++)
                  f4add(a0, *(const float4*)(skvb + (int)pml[mi][i] * 256));
              f4add(a0, a1); f4add(a2, a3); f4add(a0, a2);
              *(float4*)(&kv[mi][r][lane*4]) = a0;
          }
      }
    }
    __syncthreads();

    // phase 3: logits
    { int h = tid >> 6; int mi = (tid >> 5) & 1; int d = tid & 31;
      float qv = ql[mi][h*32 + d];
      for(int r = 0; r < 17; r++){
          if(mkl[mi][r]) continue;
          float v = qv * kv[mi][r][h*32 + d];
          v += __shfl_xor(v, 16); v += __shfl_xor(v, 8);
          v += __shfl_xor(v, 4);  v += __shfl_xor(v, 2); v += __shfl_xor(v, 1);
          if(d == 0) lg[mi][h][r] = v * 0.17677669529663687f + bias[h*17 + r];
      }
    }
    __syncthreads();

    // phase 4: softmax over unmasked r
    if(tid < 8){
        int mi = tid >> 2, h = tid & 3;
        float mx = -1e30f;
        for(int r = 0; r < 17; r++) if(!mkl[mi][r]) mx = fmaxf(mx, lg[mi][h][r]);
        float sum = 0.f;
        for(int r = 0; r < 17; r++){
            if(!mkl[mi][r]){ float e = expf(lg[mi][h][r] - mx); al[mi][h][r] = e; sum += e; }
            else al[mi][h][r] = 0.f;
        }
        float inv = 1.0f / sum;
        for(int r = 0; r < 17; r++) al[mi][h][r] *= inv;
    }
    __syncthreads();

    // phase 5: out = sum_r a[r] * V[r]
    { int mi = tid >> 7, c = tid & 127, h = c >> 5;
      float o = 0.f;
      for(int r = 0; r < 17; r++){
          if(mkl[mi][r]) continue;
          o += al[mi][h][r] * kv[mi][r][128 + c];
      }
      out[((size_t)(b*512 + m0 + mi))*128 + c] = o;
    }
}

// ---------------------------------------------------------------------------
extern "C" void kernel_launch(void* const* d_in, const int* in_sizes, int n_in,
                              void* d_out, int out_size, void* d_ws, size_t ws_size,
                              hipStream_t stream){
    const float* x        = (const float*)d_in[0];
    const float* pos      = (const float*)d_in[1];
    const float* t_qkv_w  = (const float*)d_in[2];
    const float* t_proj_w = (const float*)d_in[3];
    const float* t_proj_b = (const float*)d_in[4];
    const float* t_ln_g   = (const float*)d_in[5];
    const float* t_ln_b   = (const float*)d_in[6];
    const float* t_ff_w1  = (const float*)d_in[7];
    const float* t_ff_b1  = (const float*)d_in[8];
    const float* t_ff_w2  = (const float*)d_in[9];
    const float* t_ff_b2  = (const float*)d_in[10];
    const float* assign   = (const float*)d_in[11];
    const unsigned char* s_mask_raw = (const unsigned char*)d_in[12];  // dict order!
    const float* s_q_w    = (const float*)d_in[13];
    const float* s_kv_w   = (const float*)d_in[14];
    const float* s_bias   = (const float*)d_in[15];
    const float* s_proj_w = (const float*)d_in[16];
    const float* s_proj_b = (const float*)d_in[17];
    const float* s_ln_g   = (const float*)d_in[18];
    const float* s_ln_b   = (const float*)d_in[19];
    const float* s_ff_w1  = (const float*)d_in[20];
    const float* s_ff_b1  = (const float*)d_in[21];
    const float* s_ff_w2  = (const float*)d_in[22];
    const float* s_ff_b2  = (const float*)d_in[23];

    float* ws = (float*)d_ws;
    float* Cb = (float*)d_out;   // reused as full-M scratch (attn out / LN out)

    // CH=1 (unchunked) needs ~153 MB of ws; CH=4 needs ~51.2 MB.
    const int CH = (ws_size >= (size_t)160*1024*1024) ? 1 : 4;
    float* A  = ws;
    float* TS = ws + TOK;
    float* E  = (CH==1) ? (ws + 5*(size_t)TOK) : (ws + TOK);
    float* SS = (CH==1) ? TS : A;
    char*  sb = (char*)(ws + ((CH==1)? 6*(size_t)TOK : 2*(size_t)TOK));
    unsigned char*  sec   = (unsigned char*)sb;              // 262144 B
    unsigned short* perm  = (unsigned short*)(sb + 262144);  // 524288 B
    int*            bnd   = (int*)(sb + 786432);             // 36864 B
    unsigned char*  maskn = (unsigned char*)(sb + 823296);   // 8704 B
    unsigned char*  gmap  = (unsigned char*)(sb + 832000);   // 8704 B

    const int rows = 49152 / CH;       // M rows per chunk
    const int nb   = 96 / CH;          // bt values per spatial chunk

    normalize_mask<<<1, 256, 0, stream>>>(s_mask_raw, maskn);
    build_sec<<<1024, 256, 0, stream>>>(assign, sec);
    build_perm<<<512, 64, 0, stream>>>(sec, maskn, perm, bnd, gmap);
    stage0<<<2048, 128, 0, stream>>>(x, pos, A);

    for(int d = 0; d < 2; d++){
        for(int c = 0; c < CH; c++){
            const float* Ac = A + (size_t)c*rows*128;
            gemm64<false,false,false><<<dim3(6, rows/64), 256, 0, stream>>>(
                Ac, t_qkv_w + d*49152, nullptr, nullptr, TS, 384, 128);
            tattn<<<rows/12, 256, 0, stream>>>(TS, Cb + (size_t)c*rows*128);
        }
        gemm64<true,false,true><<<dim3(2,768), 256, 0, stream>>>(
            Cb, t_proj_w + d*16384, t_proj_b + d*128, A, A, 128, 128);
        ln_kernel<<<12288, 256, 0, stream>>>(A, Cb, t_ln_g + d*128, t_ln_b + d*128);
        for(int c = 0; c < CH; c++){
            float* Ac = A + (size_t)c*rows*128;
            gemm64<true,true,false><<<dim3(8, rows/64), 256, 0, stream>>>(
                Cb + (size_t)c*rows*128, t_ff_w1 + d*65536, t_ff_b1 + d*512,
                nullptr, TS, 512, 128);
            gemm64<true,false,true><<<dim3(2, rows/64), 256, 0, stream>>>(
                TS, t_ff_w2 + d*65536, t_ff_b2 + d*128, Ac, Ac, 128, 512);
        }
    }

    t2s<<<24576, 256, 0, stream>>>(A, E);

    for(int d = 0; d < 2; d++){
        gemm64<false,false,false><<<dim3(2,768), 256, 0, stream>>>(
            E, s_q_w + d*16384, nullptr, nullptr, Cb, 128, 128);
        for(int c = 0; c < CH; c++){
            float* Ec = E + (size_t)c*nb*512*128;
            float* att = SS + (size_t)nb*512*256;
            gemm64<false,false,false><<<dim3(4, nb*512/64), 256, 0, stream>>>(
                Ec, s_kv_w + d*32768, nullptr, nullptr, SS, 256, 128);
            sattn<<<nb*256, 256, 0, stream>>>(
                Cb + (size_t)c*nb*512*128, SS, perm, bnd, maskn, gmap,
                s_bias + d*68, att);
            gemm64<true,false,true><<<dim3(2, nb*512/64), 256, 0, stream>>>(
                att, s_proj_w + d*16384, s_proj_b + d*128, Ec, Ec, 128, 128);
        }
        ln_kernel<<<12288, 256, 0, stream>>>(E, Cb, s_ln_g + d*128, s_ln_b + d*128);
        for(int c = 0; c < CH; c++){
            float* Ec = E + (size_t)c*rows*128;
            gemm64<true,true,false><<<dim3(8, rows/64), 256, 0, stream>>>(
                Cb + (size_t)c*rows*128, s_ff_w1 + d*65536, s_ff_b1 + d*512,
                nullptr, SS, 512, 128);
            gemm64<true,false,true><<<dim3(2, rows/64), 256, 0, stream>>>(
                SS, s_ff_w2 + d*65536, s_ff_b2 + d*128, Ec, Ec, 128, 512);
        }
    }

    finalt<<<2048, 128, 0, stream>>>(E, (float*)d_out);
}

// Round 4
// 2850.046 us; speedup vs baseline: 1.6461x; 1.0559x over previous
//
#include <hip/hip_runtime.h>
#include <math.h>

// B=4, C=128, N=512, T=24, D=2, H=4, hd=32, WS=12, R=17, MLP=512
#define TOK 6291456   // 49152 * 128 floats (one full token buffer)

__device__ __forceinline__ float gelu_exact(float x){
    return 0.5f * x * (1.0f + erff(x * 0.70710678118654752f));
}
__device__ __forceinline__ void f4add(float4& a, const float4 b){
    a.x += b.x; a.y += b.y; a.z += b.z; a.w += b.w;
}
__device__ __forceinline__ unsigned short f2bf(float f){
    unsigned u = __float_as_uint(f);
    unsigned r = (u + 0x7FFF + ((u >> 16) & 1)) >> 16;   // RTN-even
    return (unsigned short)r;
}
__device__ __forceinline__ float bf2f(unsigned short s){
    return __uint_as_float(((unsigned)s) << 16);
}
__device__ __forceinline__ float4 bf4_to_f4(ushort4 u){
    return make_float4(bf2f(u.x), bf2f(u.y), bf2f(u.z), bf2f(u.w));
}

// ---------------------------------------------------------------------------
// s_mask normalizer (probe first 8704 bytes only; classify u8/i32/f32 layout)
// ---------------------------------------------------------------------------
__global__ void normalize_mask(const unsigned char* __restrict__ raw,
                               unsigned char* __restrict__ outm){
    __shared__ int nz[4];
    if(threadIdx.x < 4) nz[threadIdx.x] = 0;
    __syncthreads();
    for(int i = threadIdx.x; i < 8704; i += 256){
        if(raw[i]) atomicOr(&nz[i & 3], 1);
    }
    __syncthreads();
    int mode; // 0=u8, 1=i32, 2=f32
    if(nz[1] | nz[2] | nz[3]) mode = nz[0] ? 0 : 2;
    else                      mode = 1;
    for(int i = threadIdx.x; i < 8704; i += 256){
        unsigned char v;
        if(mode == 0)      v = (raw[i] != 0);
        else if(mode == 1) v = (raw[4*i] != 0);
        else               v = ((raw[4*i+2] | raw[4*i+3]) != 0);
        outm[i] = v;
    }
}

// sec[m][n] = argmax_r assignment[m][n][r]  (exact one-hot f32)
__global__ void build_sec(const float* __restrict__ assign,
                          unsigned char* __restrict__ sec){
    int id = blockIdx.x * 256 + threadIdx.x;
    if(id >= 512*512) return;
    const float* p = assign + (size_t)id * 17;
    int rr = 0;
    #pragma unroll
    for(int r = 0; r < 17; r++) if(p[r] > 0.5f) rr = r;
    sec[id] = (unsigned char)rr;
}

// counting sort of each sec row -> perm/bnd, plus greedy LPT bucket->wave map
__global__ __launch_bounds__(64) void build_perm(const unsigned char* __restrict__ sec,
                                                 const unsigned char* __restrict__ maskn,
                                                 unsigned short* __restrict__ perm,
                                                 int* __restrict__ bnd,
                                                 unsigned char* __restrict__ gmap){
    __shared__ unsigned char row[512];
    __shared__ int cnts[17];
    int m = blockIdx.x;
    int lane = threadIdx.x;
    for(int i = lane; i < 512; i += 64) row[i] = sec[m*512 + i];
    __syncthreads();
    int cnt = 0;
    if(lane < 17){
        for(int n = 0; n < 512; n++) cnt += (row[n] == lane);
        cnts[lane] = cnt;
    }
    int incl = cnt;
    for(int i = 1; i < 32; i <<= 1){
        int v = __shfl_up(incl, i);
        if(lane >= i) incl += v;
    }
    int start = incl - cnt;
    if(lane < 18) bnd[m*18 + lane] = start;
    if(lane < 17){
        int idx = start;
        for(int n = 0; n < 512; n++)
            if(row[n] == lane) perm[m*512 + (idx++)] = (unsigned short)n;
    }
    __syncthreads();
    if(lane == 0){
        int   sz[17]; int used[17]; int load[4] = {0,0,0,0};
        unsigned char gm[17];
        for(int r = 0; r < 17; r++){
            sz[r] = maskn[m*17 + r] ? 0 : cnts[r];
            used[r] = 0; gm[r] = 0;
        }
        for(int it = 0; it < 17; it++){
            int best = -1, bs = -1;
            for(int r = 0; r < 17; r++)
                if(!used[r] && sz[r] > bs){ bs = sz[r]; best = r; }
            int bin = 0;
            for(int g = 1; g < 4; g++) if(load[g] < load[bin]) bin = g;
            used[best] = 1; gm[best] = (unsigned char)bin; load[bin] += sz[best];
        }
        for(int r = 0; r < 17; r++) gmap[m*17 + r] = gm[r];
    }
}

// h[(b*N+n)*T+t][c] = x[b][c][n][t] + pos_emb[t][c]
__global__ __launch_bounds__(128) void stage0(const float* __restrict__ x,
                                              const float* __restrict__ pos,
                                              float* __restrict__ h){
    __shared__ float l[128*25];
    int bid = blockIdx.x;
    int b = bid >> 9, n = bid & 511;
    int tid = threadIdx.x;
    const float* xb = x + (size_t)b*1572864 + (size_t)n*24;
    for(int it = 0; it < 24; it++){
        int i = it*128 + tid;
        int c = i / 24, t = i % 24;
        l[c*25 + t] = xb[(size_t)c*12288 + t];
    }
    __syncthreads();
    float* hb = h + ((size_t)(b*512 + n)) * 24 * 128;
    for(int t = 0; t < 24; t++){
        hb[t*128 + tid] = l[tid*25 + t] + pos[t*128 + tid];
    }
}

// E[(b*T+t)*N+n][c] = A[(b*N+n)*T+t][c]
__global__ void t2s(const float* __restrict__ a, float* __restrict__ e){
    size_t idx = (size_t)blockIdx.x * 256 + threadIdx.x;
    int c = (int)(idx & 127);
    size_t rest = idx >> 7;
    int n = (int)(rest & 511); rest >>= 9;
    int t = (int)(rest % 24);
    int b = (int)(rest / 24);
    e[idx] = a[(((size_t)(b*512 + n))*24 + t)*128 + c];
}

// out[b][c][n][t] = E[(b*T+t)*N+n][c]
__global__ __launch_bounds__(128) void finalt(const float* __restrict__ e,
                                              float* __restrict__ out){
    __shared__ float l[128*25];
    int bid = blockIdx.x;
    int b = bid >> 9, n = bid & 511;
    int tid = threadIdx.x;
    for(int t = 0; t < 24; t++){
        l[tid*25 + t] = e[(((size_t)(b*24 + t))*512 + n)*128 + tid];
    }
    __syncthreads();
    float* ob = out + (size_t)b*1572864 + (size_t)n*24;
    for(int it = 0; it < 24; it++){
        int i = it*128 + tid;
        int c = i / 24, t = i % 24;
        ob[(size_t)c*12288 + t] = l[c*25 + t];
    }
}

// LayerNorm over C=128, one wave per token
__global__ __launch_bounds__(256) void ln_kernel(const float* __restrict__ in,
                                                 float* __restrict__ out,
                                                 const float* __restrict__ g,
                                                 const float* __restrict__ b){
    int w = threadIdx.x >> 6, lane = threadIdx.x & 63;
    int tok = blockIdx.x * 4 + w;
    const float* row = in + (size_t)tok * 128;
    float x0 = row[lane], x1 = row[lane + 64];
    float s  = x0 + x1;
    float s2 = x0*x0 + x1*x1;
    #pragma unroll
    for(int m = 1; m < 64; m <<= 1){
        s  += __shfl_xor(s,  m);
        s2 += __shfl_xor(s2, m);
    }
    float mean = s * (1.0f/128.0f);
    float var  = s2 * (1.0f/128.0f) - mean*mean;
    float rstd = rsqrtf(var + 1e-5f);
    float* o = out + (size_t)tok * 128;
    o[lane]      = (x0 - mean) * rstd * g[lane]      + b[lane];
    o[lane + 64] = (x1 - mean) * rstd * g[lane + 64] + b[lane + 64];
}

// fp32 GEMM out[M,N] = A[M,K] @ W[K,N] (+bias)(+gelu)(+res), 64x64 tile.
// OBF16: store output as bf16 (RTN) instead of f32.
template<bool BIAS, bool GELU, bool RES, bool OBF16>
__global__ __launch_bounds__(256) void gemm64(const float* __restrict__ A,
                                              const float* __restrict__ W,
                                              const float* __restrict__ bias,
                                              const float* __restrict__ res,
                                              void* __restrict__ outv,
                                              int N, int K){
    __shared__ float As[32*68];
    __shared__ float Ws[32*68];
    const int tid = threadIdx.x;
    const int tm = tid >> 4;
    const int tn = tid & 15;
    const int m0 = blockIdx.y * 64;
    const int n0 = blockIdx.x * 64;

    float acc[4][4];
    #pragma unroll
    for(int i = 0; i < 4; i++)
        #pragma unroll
        for(int j = 0; j < 4; j++) acc[i][j] = 0.0f;

    for(int k0 = 0; k0 < K; k0 += 32){
        __syncthreads();
        #pragma unroll
        for(int t = 0; t < 2; t++){
            int s = tid + t*256;
            int row = s >> 3, kq = s & 7;
            float4 a4 = *(const float4*)(A + (size_t)(m0 + row)*K + k0 + kq*4);
            As[(kq*4+0)*68 + row] = a4.x;
            As[(kq*4+1)*68 + row] = a4.y;
            As[(kq*4+2)*68 + row] = a4.z;
            As[(kq*4+3)*68 + row] = a4.w;
            int k = s >> 4, nq = s & 15;
            *(float4*)(Ws + k*68 + nq*4) =
                *(const float4*)(W + (size_t)(k0 + k)*N + n0 + nq*4);
        }
        __syncthreads();
        #pragma unroll
        for(int kk = 0; kk < 32; kk++){
            float4 av = *(const float4*)(As + kk*68 + tm*4);
            float4 bv = *(const float4*)(Ws + kk*68 + tn*4);
            acc[0][0] += av.x*bv.x; acc[0][1] += av.x*bv.y; acc[0][2] += av.x*bv.z; acc[0][3] += av.x*bv.w;
            acc[1][0] += av.y*bv.x; acc[1][1] += av.y*bv.y; acc[1][2] += av.y*bv.z; acc[1][3] += av.y*bv.w;
            acc[2][0] += av.z*bv.x; acc[2][1] += av.z*bv.y; acc[2][2] += av.z*bv.z; acc[2][3] += av.z*bv.w;
            acc[3][0] += av.w*bv.x; acc[3][1] += av.w*bv.y; acc[3][2] += av.w*bv.z; acc[3][3] += av.w*bv.w;
        }
    }

    float4 b4 = make_float4(0.f,0.f,0.f,0.f);
    if(BIAS) b4 = *(const float4*)(bias + n0 + tn*4);
    #pragma unroll
    for(int i = 0; i < 4; i++){
        int m = m0 + tm*4 + i;
        float4 v = make_float4(acc[i][0], acc[i][1], acc[i][2], acc[i][3]);
        if(BIAS){ v.x += b4.x; v.y += b4.y; v.z += b4.z; v.w += b4.w; }
        if(GELU){
            v.x = gelu_exact(v.x); v.y = gelu_exact(v.y);
            v.z = gelu_exact(v.z); v.w = gelu_exact(v.w);
        }
        if(RES){
            float4 r4 = *(const float4*)(res + (size_t)m*N + n0 + tn*4);
            v.x += r4.x; v.y += r4.y; v.z += r4.z; v.w += r4.w;
        }
        if(OBF16){
            ushort4 o;
            o.x = f2bf(v.x); o.y = f2bf(v.y); o.z = f2bf(v.z); o.w = f2bf(v.w);
            *(ushort4*)((unsigned short*)outv + (size_t)m*N + n0 + tn*4) = o;
        }else{
            *(float4*)((float*)outv + (size_t)m*N + n0 + tn*4) = v;
        }
    }
}

// temporal windowed causal attention; qkv rows [q|k|v] 384 wide
__global__ __launch_bounds__(256) void tattn(const float* __restrict__ qkv,
                                             float* __restrict__ out){
    __shared__ float l[12*388];
    int w = blockIdx.x;
    const float* src = qkv + (size_t)w * 12 * 384;
    for(int i = threadIdx.x; i < 12*384; i += 256){
        int q = i / 384, c = i % 384;
        l[q*388 + c] = src[i];
    }
    __syncthreads();
    int h = threadIdx.x >> 6, lane = threadIdx.x & 63;
    if(lane < 12){
        int q = lane;
        const float scale = 0.17677669529663687f;
        float qv[32];
        #pragma unroll
        for(int d = 0; d < 32; d++) qv[d] = l[q*388 + h*32 + d];
        float sc[12];
        #pragma unroll
        for(int k = 0; k < 12; k++){
            float dot = 0.f;
            #pragma unroll
            for(int d = 0; d < 32; d++) dot += qv[d] * l[k*388 + 128 + h*32 + d];
            sc[k] = (k <= q) ? dot * scale : -1e30f;
        }
        float mx = sc[0];
        #pragma unroll
        for(int k = 1; k < 12; k++) mx = fmaxf(mx, sc[k]);
        float sum = 0.f;
        #pragma unroll
        for(int k = 0; k < 12; k++){ sc[k] = expf(sc[k] - mx); sum += sc[k]; }
        float inv = 1.0f / sum;
        float* orow = out + (size_t)(w*12 + q) * 128 + h*32;
        #pragma unroll
        for(int d = 0; d < 32; d++){
            float o = 0.f;
            #pragma unroll
            for(int k = 0; k < 12; k++) o += sc[k] * l[k*388 + 256 + h*32 + d];
            orow[d] = o * inv;
        }
    }
}

// ---------------------------------------------------------------------------
// fused spatial attention. skv is bf16 (256 ch/row = 512 B). Phase 2: lane
// owns a bf16x4 channel-quad; wave g owns gmap buckets. XCD swizzle: blocks
// sharing a bt value land on one XCD so its skv slab stays L2-resident.
// nb8 = (#bt values in this launch)/8.
// ---------------------------------------------------------------------------
__global__ __launch_bounds__(256) void sattn(const float* __restrict__ qbuf,
                                             const unsigned short* __restrict__ skv,
                                             const unsigned short* __restrict__ perm,
                                             const int* __restrict__ bnd,
                                             const unsigned char* __restrict__ mask,
                                             const unsigned char* __restrict__ gmap,
                                             const float* __restrict__ bias,
                                             float* __restrict__ out,
                                             int nb8){
    __shared__ float kv[2][17][256];
    __shared__ float ql[2][128];
    __shared__ float lg[2][4][17];
    __shared__ float al[2][4][17];
    __shared__ unsigned short pml[2][512];
    __shared__ int bndl[2][18];
    __shared__ int mkl[2][17];
    __shared__ int gml[2][17];

    int bid = blockIdx.x;
    int b  = (bid & 7) * nb8 + ((bid >> 3) >> 8);   // XCD-grouped bt
    int m0 = ((bid >> 3) & 255) * 2;
    int tid = threadIdx.x;

    { int mi = tid >> 7, c = tid & 127;
      ql[mi][c] = qbuf[((size_t)(b*512 + m0 + mi))*128 + c]; }
    for(int i = tid; i < 1024; i += 256){
        int mi = i >> 9, j = i & 511;
        pml[mi][j] = perm[(m0 + mi)*512 + j];
    }
    if(tid < 36){ int mi = tid/18, r = tid%18; bndl[mi][r] = bnd[(m0+mi)*18 + r]; }
    if(tid < 34){ int mi = tid/17, r = tid%17; mkl[mi][r] = mask[(m0+mi)*17 + r]; }
    if(tid >= 64 && tid < 98){
        int j = tid - 64; int mi = j/17, r = j%17;
        gml[mi][r] = gmap[(m0+mi)*17 + r];
    }
    __syncthreads();

    // phase 2: segmented bucket sums, bf16x4 per lane, buckets per wave
    { int g = tid >> 6, lane = tid & 63;
      const unsigned short* skvb = skv + (size_t)b*512*256 + lane*4;
      #pragma unroll
      for(int mi = 0; mi < 2; mi++){
          for(int r = 0; r < 17; r++){
              if(mkl[mi][r] || gml[mi][r] != g) continue;
              int s = bndl[mi][r], e = bndl[mi][r+1];
              float4 a0 = make_float4(0,0,0,0), a1 = a0, a2 = a0, a3 = a0;
              int i = s;
              for(; i + 4 <= e; i += 4){
                  f4add(a0, bf4_to_f4(*(const ushort4*)(skvb + (int)pml[mi][i  ] * 256)));
                  f4add(a1, bf4_to_f4(*(const ushort4*)(skvb + (int)pml[mi][i+1] * 256)));
                  f4add(a2, bf4_to_f4(*(const ushort4*)(skvb + (int)pml[mi][i+2] * 256)));
                  f4add(a3, bf4_to_f4(*(const ushort4*)(skvb + (int)pml[mi][i+3] * 256)));
              }
              for(; i < e; i++)
                  f4add(a0, bf4_to_f4(*(const ushort4*)(skvb + (int)pml[mi][i] * 256)));
              f4add(a0, a1); f4add(a2, a3); f4add(a0, a2);
              *(float4*)(&kv[mi][r][lane*4]) = a0;
          }
      }
    }
    __syncthreads();

    // phase 3: logits
    { int h = tid >> 6; int mi = (tid >> 5) & 1; int d = tid & 31;
      float qv = ql[mi][h*32 + d];
      for(int r = 0; r < 17; r++){
          if(mkl[mi][r]) continue;
          float v = qv * kv[mi][r][h*32 + d];
          v += __shfl_xor(v, 16); v += __shfl_xor(v, 8);
          v += __shfl_xor(v, 4);  v += __shfl_xor(v, 2); v += __shfl_xor(v, 1);
          if(d == 0) lg[mi][h][r] = v * 0.17677669529663687f + bias[h*17 + r];
      }
    }
    __syncthreads();

    // phase 4: softmax over unmasked r
    if(tid < 8){
        int mi = tid >> 2, h = tid & 3;
        float mx = -1e30f;
        for(int r = 0; r < 17; r++) if(!mkl[mi][r]) mx = fmaxf(mx, lg[mi][h][r]);
        float sum = 0.f;
        for(int r = 0; r < 17; r++){
            if(!mkl[mi][r]){ float e = expf(lg[mi][h][r] - mx); al[mi][h][r] = e; sum += e; }
            else al[mi][h][r] = 0.f;
        }
        float inv = 1.0f / sum;
        for(int r = 0; r < 17; r++) al[mi][h][r] *= inv;
    }
    __syncthreads();

    // phase 5: out = sum_r a[r] * V[r]
    { int mi = tid >> 7, c = tid & 127, h = c >> 5;
      float o = 0.f;
      for(int r = 0; r < 17; r++){
          if(mkl[mi][r]) continue;
          o += al[mi][h][r] * kv[mi][r][128 + c];
      }
      out[((size_t)(b*512 + m0 + mi))*128 + c] = o;
    }
}

// ---------------------------------------------------------------------------
extern "C" void kernel_launch(void* const* d_in, const int* in_sizes, int n_in,
                              void* d_out, int out_size, void* d_ws, size_t ws_size,
                              hipStream_t stream){
    const float* x        = (const float*)d_in[0];
    const float* pos      = (const float*)d_in[1];
    const float* t_qkv_w  = (const float*)d_in[2];
    const float* t_proj_w = (const float*)d_in[3];
    const float* t_proj_b = (const float*)d_in[4];
    const float* t_ln_g   = (const float*)d_in[5];
    const float* t_ln_b   = (const float*)d_in[6];
    const float* t_ff_w1  = (const float*)d_in[7];
    const float* t_ff_b1  = (const float*)d_in[8];
    const float* t_ff_w2  = (const float*)d_in[9];
    const float* t_ff_b2  = (const float*)d_in[10];
    const float* assign   = (const float*)d_in[11];
    const unsigned char* s_mask_raw = (const unsigned char*)d_in[12];  // dict order!
    const float* s_q_w    = (const float*)d_in[13];
    const float* s_kv_w   = (const float*)d_in[14];
    const float* s_bias   = (const float*)d_in[15];
    const float* s_proj_w = (const float*)d_in[16];
    const float* s_proj_b = (const float*)d_in[17];
    const float* s_ln_g   = (const float*)d_in[18];
    const float* s_ln_b   = (const float*)d_in[19];
    const float* s_ff_w1  = (const float*)d_in[20];
    const float* s_ff_b1  = (const float*)d_in[21];
    const float* s_ff_w2  = (const float*)d_in[22];
    const float* s_ff_b2  = (const float*)d_in[23];

    float* ws = (float*)d_ws;
    float* Cb = (float*)d_out;   // reused as full-M scratch (q buf / LN out)

    // CH=1 (unchunked) needs ~153 MB of ws; CH=4 needs ~51.2 MB.
    const int CH = (ws_size >= (size_t)160*1024*1024) ? 1 : 4;
    float* A  = ws;
    float* TS = ws + TOK;
    float* E  = (CH==1) ? (ws + 5*(size_t)TOK) : (ws + TOK);
    float* SS = (CH==1) ? TS : A;
    char*  sb = (char*)(ws + ((CH==1)? 6*(size_t)TOK : 2*(size_t)TOK));
    unsigned char*  sec   = (unsigned char*)sb;              // 262144 B
    unsigned short* perm  = (unsigned short*)(sb + 262144);  // 524288 B
    int*            bnd   = (int*)(sb + 786432);             // 36864 B
    unsigned char*  maskn = (unsigned char*)(sb + 823296);   // 8704 B
    unsigned char*  gmap  = (unsigned char*)(sb + 832000);   // 8704 B

    const int rows = 49152 / CH;       // M rows per chunk
    const int nb   = 96 / CH;          // bt values per spatial chunk

    normalize_mask<<<1, 256, 0, stream>>>(s_mask_raw, maskn);
    build_sec<<<1024, 256, 0, stream>>>(assign, sec);
    build_perm<<<512, 64, 0, stream>>>(sec, maskn, perm, bnd, gmap);
    stage0<<<2048, 128, 0, stream>>>(x, pos, A);

    for(int d = 0; d < 2; d++){
        for(int c = 0; c < CH; c++){
            const float* Ac = A + (size_t)c*rows*128;
            gemm64<false,false,false,false><<<dim3(6, rows/64), 256, 0, stream>>>(
                Ac, t_qkv_w + d*49152, nullptr, nullptr, TS, 384, 128);
            tattn<<<rows/12, 256, 0, stream>>>(TS, Cb + (size_t)c*rows*128);
        }
        gemm64<true,false,true,false><<<dim3(2,768), 256, 0, stream>>>(
            Cb, t_proj_w + d*16384, t_proj_b + d*128, A, A, 128, 128);
        ln_kernel<<<12288, 256, 0, stream>>>(A, Cb, t_ln_g + d*128, t_ln_b + d*128);
        for(int c = 0; c < CH; c++){
            float* Ac = A + (size_t)c*rows*128;
            gemm64<true,true,false,false><<<dim3(8, rows/64), 256, 0, stream>>>(
                Cb + (size_t)c*rows*128, t_ff_w1 + d*65536, t_ff_b1 + d*512,
                nullptr, TS, 512, 128);
            gemm64<true,false,true,false><<<dim3(2, rows/64), 256, 0, stream>>>(
                TS, t_ff_w2 + d*65536, t_ff_b2 + d*128, Ac, Ac, 128, 512);
        }
    }

    t2s<<<24576, 256, 0, stream>>>(A, E);

    for(int d = 0; d < 2; d++){
        gemm64<false,false,false,false><<<dim3(2,768), 256, 0, stream>>>(
            E, s_q_w + d*16384, nullptr, nullptr, Cb, 128, 128);
        for(int c = 0; c < CH; c++){
            float* Ec = E + (size_t)c*nb*512*128;
            unsigned short* skv_u = (unsigned short*)SS;            // nb*512*256 bf16
            float* att = SS + (size_t)nb*512*128;                    // after skv (f32 units)
            gemm64<false,false,false,true><<<dim3(4, nb*512/64), 256, 0, stream>>>(
                Ec, s_kv_w + d*32768, nullptr, nullptr, skv_u, 256, 128);
            sattn<<<nb*256, 256, 0, stream>>>(
                Cb + (size_t)c*nb*512*128, skv_u, perm, bnd, maskn, gmap,
                s_bias + d*68, att, nb/8);
            gemm64<true,false,true,false><<<dim3(2, nb*512/64), 256, 0, stream>>>(
                att, s_proj_w + d*16384, s_proj_b + d*128, Ec, Ec, 128, 128);
        }
        ln_kernel<<<12288, 256, 0, stream>>>(E, Cb, s_ln_g + d*128, s_ln_b + d*128);
        for(int c = 0; c < CH; c++){
            float* Ec = E + (size_t)c*rows*128;
            gemm64<true,true,false,false><<<dim3(8, rows/64), 256, 0, stream>>>(
                Cb + (size_t)c*rows*128, s_ff_w1 + d*65536, s_ff_b1 + d*512,
                nullptr, SS, 512, 128);
            gemm64<true,false,true,false><<<dim3(2, rows/64), 256, 0, stream>>>(
                SS, s_ff_w2 + d*65536, s_ff_b2 + d*128, Ec, Ec, 128, 512);
        }
    }

    finalt<<<2048, 128, 0, stream>>>(E, (float*)d_out);
}

// Round 6
// 2278.809 us; speedup vs baseline: 2.0587x; 1.2507x over previous
//
#include <hip/hip_runtime.h>
#include <math.h>

// B=4, C=128, N=512, T=24, D=2, H=4, hd=32, WS=12, R=17, MLP=512
#define TOK 6291456   // 49152 * 128 floats (one full token buffer)

typedef _Float16 half8 __attribute__((ext_vector_type(8)));
typedef __attribute__((ext_vector_type(4))) float f32x4;

__device__ __forceinline__ float gelu_exact(float x){
    return 0.5f * x * (1.0f + erff(x * 0.70710678118654752f));
}
__device__ __forceinline__ void f4add(float4& a, const float4 b){
    a.x += b.x; a.y += b.y; a.z += b.z; a.w += b.w;
}
__device__ __forceinline__ unsigned short f2h(float f){
    return __builtin_bit_cast(unsigned short, (_Float16)f);
}
__device__ __forceinline__ float h2f(unsigned short s){
    return (float)__builtin_bit_cast(_Float16, s);
}
__device__ __forceinline__ float4 h4_to_f4(ushort4 u){
    return make_float4(h2f(u.x), h2f(u.y), h2f(u.z), h2f(u.w));
}

// ---------------------------------------------------------------------------
// s_mask normalizer (probe first 8704 bytes only; classify u8/i32/f32 layout)
// ---------------------------------------------------------------------------
__global__ void normalize_mask(const unsigned char* __restrict__ raw,
                               unsigned char* __restrict__ outm){
    __shared__ int nz[4];
    if(threadIdx.x < 4) nz[threadIdx.x] = 0;
    __syncthreads();
    for(int i = threadIdx.x; i < 8704; i += 256){
        if(raw[i]) atomicOr(&nz[i & 3], 1);
    }
    __syncthreads();
    int mode; // 0=u8, 1=i32, 2=f32
    if(nz[1] | nz[2] | nz[3]) mode = nz[0] ? 0 : 2;
    else                      mode = 1;
    for(int i = threadIdx.x; i < 8704; i += 256){
        unsigned char v;
        if(mode == 0)      v = (raw[i] != 0);
        else if(mode == 1) v = (raw[4*i] != 0);
        else               v = ((raw[4*i+2] | raw[4*i+3]) != 0);
        outm[i] = v;
    }
}

// sec[m][n] = argmax_r assignment[m][n][r]  (exact one-hot f32)
__global__ void build_sec(const float* __restrict__ assign,
                          unsigned char* __restrict__ sec){
    int id = blockIdx.x * 256 + threadIdx.x;
    if(id >= 512*512) return;
    const float* p = assign + (size_t)id * 17;
    int rr = 0;
    #pragma unroll
    for(int r = 0; r < 17; r++) if(p[r] > 0.5f) rr = r;
    sec[id] = (unsigned char)rr;
}

// counting sort of each sec row -> perm/bnd, plus greedy LPT bucket->wave map
__global__ __launch_bounds__(64) void build_perm(const unsigned char* __restrict__ sec,
                                                 const unsigned char* __restrict__ maskn,
                                                 unsigned short* __restrict__ perm,
                                                 int* __restrict__ bnd,
                                                 unsigned char* __restrict__ gmap){
    __shared__ unsigned char row[512];
    __shared__ int cnts[17];
    int m = blockIdx.x;
    int lane = threadIdx.x;
    for(int i = lane; i < 512; i += 64) row[i] = sec[m*512 + i];
    __syncthreads();
    int cnt = 0;
    if(lane < 17){
        for(int n = 0; n < 512; n++) cnt += (row[n] == lane);
        cnts[lane] = cnt;
    }
    int incl = cnt;
    for(int i = 1; i < 32; i <<= 1){
        int v = __shfl_up(incl, i);
        if(lane >= i) incl += v;
    }
    int start = incl - cnt;
    if(lane < 18) bnd[m*18 + lane] = start;
    if(lane < 17){
        int idx = start;
        for(int n = 0; n < 512; n++)
            if(row[n] == lane) perm[m*512 + (idx++)] = (unsigned short)n;
    }
    __syncthreads();
    if(lane == 0){
        int   sz[17]; int used[17]; int load[4] = {0,0,0,0};
        unsigned char gm[17];
        for(int r = 0; r < 17; r++){
            sz[r] = maskn[m*17 + r] ? 0 : cnts[r];
            used[r] = 0; gm[r] = 0;
        }
        for(int it = 0; it < 17; it++){
            int best = -1, bs = -1;
            for(int r = 0; r < 17; r++)
                if(!used[r] && sz[r] > bs){ bs = sz[r]; best = r; }
            int bin = 0;
            for(int g = 1; g < 4; g++) if(load[g] < load[bin]) bin = g;
            used[best] = 1; gm[best] = (unsigned char)bin; load[bin] += sz[best];
        }
        for(int r = 0; r < 17; r++) gmap[m*17 + r] = gm[r];
    }
}

// h[(b*N+n)*T+t][c] = x[b][c][n][t] + pos_emb[t][c]
__global__ __launch_bounds__(128) void stage0(const float* __restrict__ x,
                                              const float* __restrict__ pos,
                                              float* __restrict__ h){
    __shared__ float l[128*25];
    int bid = blockIdx.x;
    int b = bid >> 9, n = bid & 511;
    int tid = threadIdx.x;
    const float* xb = x + (size_t)b*1572864 + (size_t)n*24;
    for(int it = 0; it < 24; it++){
        int i = it*128 + tid;
        int c = i / 24, t = i % 24;
        l[c*25 + t] = xb[(size_t)c*12288 + t];
    }
    __syncthreads();
    float* hb = h + ((size_t)(b*512 + n)) * 24 * 128;
    for(int t = 0; t < 24; t++){
        hb[t*128 + tid] = l[tid*25 + t] + pos[t*128 + tid];
    }
}

// E[(b*T+t)*N+n][c] = A[(b*N+n)*T+t][c]
__global__ void t2s(const float* __restrict__ a, float* __restrict__ e){
    size_t idx = (size_t)blockIdx.x * 256 + threadIdx.x;
    int c = (int)(idx & 127);
    size_t rest = idx >> 7;
    int n = (int)(rest & 511); rest >>= 9;
    int t = (int)(rest % 24);
    int b = (int)(rest / 24);
    e[idx] = a[(((size_t)(b*512 + n))*24 + t)*128 + c];
}

// out[b][c][n][t] = E[(b*T+t)*N+n][c]
__global__ __launch_bounds__(128) void finalt(const float* __restrict__ e,
                                              float* __restrict__ out){
    __shared__ float l[128*25];
    int bid = blockIdx.x;
    int b = bid >> 9, n = bid & 511;
    int tid = threadIdx.x;
    for(int t = 0; t < 24; t++){
        l[tid*25 + t] = e[(((size_t)(b*24 + t))*512 + n)*128 + tid];
    }
    __syncthreads();
    float* ob = out + (size_t)b*1572864 + (size_t)n*24;
    for(int it = 0; it < 24; it++){
        int i = it*128 + tid;
        int c = i / 24, t = i % 24;
        ob[(size_t)c*12288 + t] = l[c*25 + t];
    }
}

// LayerNorm over C=128, one wave per token
__global__ __launch_bounds__(256) void ln_kernel(const float* __restrict__ in,
                                                 float* __restrict__ out,
                                                 const float* __restrict__ g,
                                                 const float* __restrict__ b){
    int w = threadIdx.x >> 6, lane = threadIdx.x & 63;
    int tok = blockIdx.x * 4 + w;
    const float* row = in + (size_t)tok * 128;
    float x0 = row[lane], x1 = row[lane + 64];
    float s  = x0 + x1;
    float s2 = x0*x0 + x1*x1;
    #pragma unroll
    for(int m = 1; m < 64; m <<= 1){
        s  += __shfl_xor(s,  m);
        s2 += __shfl_xor(s2, m);
    }
    float mean = s * (1.0f/128.0f);
    float var  = s2 * (1.0f/128.0f) - mean*mean;
    float rstd = rsqrtf(var + 1e-5f);
    float* o = out + (size_t)tok * 128;
    o[lane]      = (x0 - mean) * rstd * g[lane]      + b[lane];
    o[lane + 64] = (x1 - mean) * rstd * g[lane + 64] + b[lane + 64];
}

// ---------------------------------------------------------------------------
// fp16 MFMA GEMM: out[M,N] = A[M,K] @ W[K,N] (+bias)(+gelu)(+res).
// 128x64 tile, 256 thr (4 waves), mfma_f32_16x16x32_f16, fp32 accum.
// A,W are fp32 in global; staged to LDS as fp16 (RTE, v_cvt_f16_f32).
// M%128==0, N%64==0, K%32==0. LDS row stride 40 halves (80 B).
// ---------------------------------------------------------------------------
#define LDA 40
template<bool BIAS, bool GELU, bool RES, bool OF16>
__global__ __launch_bounds__(256) void gemm_mfma(const float* __restrict__ A,
                                                 const float* __restrict__ W,
                                                 const float* __restrict__ bias,
                                                 const float* __restrict__ res,
                                                 void* __restrict__ outv,
                                                 int N, int K){
    __shared__ unsigned short As[128*LDA];
    __shared__ unsigned short Ws[64*LDA];
    const int tid = threadIdx.x;
    const int w = tid >> 6, l = tid & 63;
    const int m0 = blockIdx.y * 128;
    const int n0 = blockIdx.x * 64;

    f32x4 acc[2][4];
    #pragma unroll
    for(int i = 0; i < 2; i++)
        #pragma unroll
        for(int nt = 0; nt < 4; nt++) acc[i][nt] = (f32x4){0.f,0.f,0.f,0.f};

    for(int k0 = 0; k0 < K; k0 += 32){
        __syncthreads();
        // A stage: 2 passes x 64 rows; thread: row=tid>>2, kq=(tid&3)*8
        #pragma unroll
        for(int p = 0; p < 2; p++){
            int r  = (tid >> 2) + p*64;
            int kq = (tid & 3) * 8;
            const float* src = A + (size_t)(m0 + r)*K + k0 + kq;
            float4 v0 = *(const float4*)(src);
            float4 v1 = *(const float4*)(src + 4);
            int4 pk;
            pk.x = (int)((unsigned)f2h(v0.x) | ((unsigned)f2h(v0.y) << 16));
            pk.y = (int)((unsigned)f2h(v0.z) | ((unsigned)f2h(v0.w) << 16));
            pk.z = (int)((unsigned)f2h(v1.x) | ((unsigned)f2h(v1.y) << 16));
            pk.w = (int)((unsigned)f2h(v1.z) | ((unsigned)f2h(v1.w) << 16));
            *(int4*)(&As[r*LDA + kq]) = pk;
        }
        // W stage (transposed to Ws[n][k]): thread: n=tid&63, kb=(tid>>6)*8
        {
            int n  = tid & 63;
            int kb = (tid >> 6) * 8;
            const float* src = W + (size_t)(k0 + kb)*N + n0 + n;
            float v0 = src[0],           v1 = src[(size_t)N];
            float v2 = src[(size_t)2*N], v3 = src[(size_t)3*N];
            float v4 = src[(size_t)4*N], v5 = src[(size_t)5*N];
            float v6 = src[(size_t)6*N], v7 = src[(size_t)7*N];
            int4 pk;
            pk.x = (int)((unsigned)f2h(v0) | ((unsigned)f2h(v1) << 16));
            pk.y = (int)((unsigned)f2h(v2) | ((unsigned)f2h(v3) << 16));
            pk.z = (int)((unsigned)f2h(v4) | ((unsigned)f2h(v5) << 16));
            pk.w = (int)((unsigned)f2h(v6) | ((unsigned)f2h(v7) << 16));
            *(int4*)(&Ws[n*LDA + kb]) = pk;
        }
        __syncthreads();
        // A-frag: lane holds A[m=l&15][k=(l>>4)*8+j]; B-frag: B[k][n=l&15]
        half8 a0 = *(const half8*)(&As[(w*32      + (l & 15))*LDA + (l >> 4)*8]);
        half8 a1 = *(const half8*)(&As[(w*32 + 16 + (l & 15))*LDA + (l >> 4)*8]);
        #pragma unroll
        for(int nt = 0; nt < 4; nt++){
            half8 b = *(const half8*)(&Ws[(nt*16 + (l & 15))*LDA + (l >> 4)*8]);
            acc[0][nt] = __builtin_amdgcn_mfma_f32_16x16x32_f16(a0, b, acc[0][nt], 0, 0, 0);
            acc[1][nt] = __builtin_amdgcn_mfma_f32_16x16x32_f16(a1, b, acc[1][nt], 0, 0, 0);
        }
    }

    // epilogue: C/D layout col=lane&15, row=(lane>>4)*4+reg  [m89-verified]
    const int col = l & 15, rg = l >> 4;
    #pragma unroll
    for(int i = 0; i < 2; i++){
        #pragma unroll
        for(int nt = 0; nt < 4; nt++){
            int n = n0 + nt*16 + col;
            float bv = BIAS ? bias[n] : 0.f;
            #pragma unroll
            for(int reg = 0; reg < 4; reg++){
                int m = m0 + w*32 + i*16 + rg*4 + reg;
                float v = acc[i][nt][reg] + bv;
                if(GELU) v = gelu_exact(v);
                if(RES)  v += res[(size_t)m*N + n];
                if(OF16) ((unsigned short*)outv)[(size_t)m*N + n] = f2h(v);
                else     ((float*)outv)[(size_t)m*N + n] = v;
            }
        }
    }
}

// temporal windowed causal attention; qkv rows [q|k|v] 384 wide
__global__ __launch_bounds__(256) void tattn(const float* __restrict__ qkv,
                                             float* __restrict__ out){
    __shared__ float l[12*388];
    int w = blockIdx.x;
    const float* src = qkv + (size_t)w * 12 * 384;
    for(int i = threadIdx.x; i < 12*384; i += 256){
        int q = i / 384, c = i % 384;
        l[q*388 + c] = src[i];
    }
    __syncthreads();
    int h = threadIdx.x >> 6, lane = threadIdx.x & 63;
    if(lane < 12){
        int q = lane;
        const float scale = 0.17677669529663687f;
        float qv[32];
        #pragma unroll
        for(int d = 0; d < 32; d++) qv[d] = l[q*388 + h*32 + d];
        float sc[12];
        #pragma unroll
        for(int k = 0; k < 12; k++){
            float dot = 0.f;
            #pragma unroll
            for(int d = 0; d < 32; d++) dot += qv[d] * l[k*388 + 128 + h*32 + d];
            sc[k] = (k <= q) ? dot * scale : -1e30f;
        }
        float mx = sc[0];
        #pragma unroll
        for(int k = 1; k < 12; k++) mx = fmaxf(mx, sc[k]);
        float sum = 0.f;
        #pragma unroll
        for(int k = 0; k < 12; k++){ sc[k] = expf(sc[k] - mx); sum += sc[k]; }
        float inv = 1.0f / sum;
        float* orow = out + (size_t)(w*12 + q) * 128 + h*32;
        #pragma unroll
        for(int d = 0; d < 32; d++){
            float o = 0.f;
            #pragma unroll
            for(int k = 0; k < 12; k++) o += sc[k] * l[k*388 + 256 + h*32 + d];
            orow[d] = o * inv;
        }
    }
}

// ---------------------------------------------------------------------------
// fused spatial attention; skv rows are fp16 (256 ch = 512 B)
// ---------------------------------------------------------------------------
__global__ __launch_bounds__(256) void sattn(const float* __restrict__ qbuf,
                                             const unsigned short* __restrict__ skv,
                                             const unsigned short* __restrict__ perm,
                                             const int* __restrict__ bnd,
                                             const unsigned char* __restrict__ mask,
                                             const unsigned char* __restrict__ gmap,
                                             const float* __restrict__ bias,
                                             float* __restrict__ out,
                                             int nb8){
    __shared__ float kv[2][17][256];
    __shared__ float ql[2][128];
    __shared__ float lg[2][4][17];
    __shared__ float al[2][4][17];
    __shared__ unsigned short pml[2][512];
    __shared__ int bndl[2][18];
    __shared__ int mkl[2][17];
    __shared__ int gml[2][17];

    int bid = blockIdx.x;
    int b  = (bid & 7) * nb8 + ((bid >> 3) >> 8);   // XCD-grouped bt
    int m0 = ((bid >> 3) & 255) * 2;
    int tid = threadIdx.x;

    { int mi = tid >> 7, c = tid & 127;
      ql[mi][c] = qbuf[((size_t)(b*512 + m0 + mi))*128 + c]; }
    for(int i = tid; i < 1024; i += 256){
        int mi = i >> 9, j = i & 511;
        pml[mi][j] = perm[(m0 + mi)*512 + j];
    }
    if(tid < 36){ int mi = tid/18, r = tid%18; bndl[mi][r] = bnd[(m0+mi)*18 + r]; }
    if(tid < 34){ int mi = tid/17, r = tid%17; mkl[mi][r] = mask[(m0+mi)*17 + r]; }
    if(tid >= 64 && tid < 98){
        int j = tid - 64; int mi = j/17, r = j%17;
        gml[mi][r] = gmap[(m0+mi)*17 + r];
    }
    __syncthreads();

    { int g = tid >> 6, lane = tid & 63;
      const unsigned short* skvb = skv + (size_t)b*512*256 + lane*4;
      #pragma unroll
      for(int mi = 0; mi < 2; mi++){
          for(int r = 0; r < 17; r++){
              if(mkl[mi][r] || gml[mi][r] != g) continue;
              int s = bndl[mi][r], e = bndl[mi][r+1];
              float4 a0 = make_float4(0,0,0,0), a1 = a0, a2 = a0, a3 = a0;
              int i = s;
              for(; i + 4 <= e; i += 4){
                  f4add(a0, h4_to_f4(*(const ushort4*)(skvb + (int)pml[mi][i  ] * 256)));
                  f4add(a1, h4_to_f4(*(const ushort4*)(skvb + (int)pml[mi][i+1] * 256)));
                  f4add(a2, h4_to_f4(*(const ushort4*)(skvb + (int)pml[mi][i+2] * 256)));
                  f4add(a3, h4_to_f4(*(const ushort4*)(skvb + (int)pml[mi][i+3] * 256)));
              }
              for(; i < e; i++)
                  f4add(a0, h4_to_f4(*(const ushort4*)(skvb + (int)pml[mi][i] * 256)));
              f4add(a0, a1); f4add(a2, a3); f4add(a0, a2);
              *(float4*)(&kv[mi][r][lane*4]) = a0;
          }
      }
    }
    __syncthreads();

    { int h = tid >> 6; int mi = (tid >> 5) & 1; int d = tid & 31;
      float qv = ql[mi][h*32 + d];
      for(int r = 0; r < 17; r++){
          if(mkl[mi][r]) continue;
          float v = qv * kv[mi][r][h*32 + d];
          v += __shfl_xor(v, 16); v += __shfl_xor(v, 8);
          v += __shfl_xor(v, 4);  v += __shfl_xor(v, 2); v += __shfl_xor(v, 1);
          if(d == 0) lg[mi][h][r] = v * 0.17677669529663687f + bias[h*17 + r];
      }
    }
    __syncthreads();

    if(tid < 8){
        int mi = tid >> 2, h = tid & 3;
        float mx = -1e30f;
        for(int r = 0; r < 17; r++) if(!mkl[mi][r]) mx = fmaxf(mx, lg[mi][h][r]);
        float sum = 0.f;
        for(int r = 0; r < 17; r++){
            if(!mkl[mi][r]){ float e = expf(lg[mi][h][r] - mx); al[mi][h][r] = e; sum += e; }
            else al[mi][h][r] = 0.f;
        }
        float inv = 1.0f / sum;
        for(int r = 0; r < 17; r++) al[mi][h][r] *= inv;
    }
    __syncthreads();

    { int mi = tid >> 7, c = tid & 127, h = c >> 5;
      float o = 0.f;
      for(int r = 0; r < 17; r++){
          if(mkl[mi][r]) continue;
          o += al[mi][h][r] * kv[mi][r][128 + c];
      }
      out[((size_t)(b*512 + m0 + mi))*128 + c] = o;
    }
}

// ---------------------------------------------------------------------------
extern "C" void kernel_launch(void* const* d_in, const int* in_sizes, int n_in,
                              void* d_out, int out_size, void* d_ws, size_t ws_size,
                              hipStream_t stream){
    const float* x        = (const float*)d_in[0];
    const float* pos      = (const float*)d_in[1];
    const float* t_qkv_w  = (const float*)d_in[2];
    const float* t_proj_w = (const float*)d_in[3];
    const float* t_proj_b = (const float*)d_in[4];
    const float* t_ln_g   = (const float*)d_in[5];
    const float* t_ln_b   = (const float*)d_in[6];
    const float* t_ff_w1  = (const float*)d_in[7];
    const float* t_ff_b1  = (const float*)d_in[8];
    const float* t_ff_w2  = (const float*)d_in[9];
    const float* t_ff_b2  = (const float*)d_in[10];
    const float* assign   = (const float*)d_in[11];
    const unsigned char* s_mask_raw = (const unsigned char*)d_in[12];  // dict order!
    const float* s_q_w    = (const float*)d_in[13];
    const float* s_kv_w   = (const float*)d_in[14];
    const float* s_bias   = (const float*)d_in[15];
    const float* s_proj_w = (const float*)d_in[16];
    const float* s_proj_b = (const float*)d_in[17];
    const float* s_ln_g   = (const float*)d_in[18];
    const float* s_ln_b   = (const float*)d_in[19];
    const float* s_ff_w1  = (const float*)d_in[20];
    const float* s_ff_b1  = (const float*)d_in[21];
    const float* s_ff_w2  = (const float*)d_in[22];
    const float* s_ff_b2  = (const float*)d_in[23];

    float* ws = (float*)d_ws;
    float* Cb = (float*)d_out;   // reused as full-M scratch (q buf / LN out)

    // CH=1 (unchunked) needs ~153 MB of ws; CH=4 needs ~51.2 MB.
    const int CH = (ws_size >= (size_t)160*1024*1024) ? 1 : 4;
    float* A  = ws;
    float* TS = ws + TOK;
    float* E  = (CH==1) ? (ws + 5*(size_t)TOK) : (ws + TOK);
    float* SS = (CH==1) ? TS : A;
    char*  sb = (char*)(ws + ((CH==1)? 6*(size_t)TOK : 2*(size_t)TOK));
    unsigned char*  sec   = (unsigned char*)sb;              // 262144 B
    unsigned short* perm  = (unsigned short*)(sb + 262144);  // 524288 B
    int*            bnd   = (int*)(sb + 786432);             // 36864 B
    unsigned char*  maskn = (unsigned char*)(sb + 823296);   // 8704 B
    unsigned char*  gmap  = (unsigned char*)(sb + 832000);   // 8704 B

    const int rows = 49152 / CH;       // M rows per chunk (multiple of 128)
    const int nb   = 96 / CH;          // bt values per spatial chunk

    normalize_mask<<<1, 256, 0, stream>>>(s_mask_raw, maskn);
    build_sec<<<1024, 256, 0, stream>>>(assign, sec);
    build_perm<<<512, 64, 0, stream>>>(sec, maskn, perm, bnd, gmap);
    stage0<<<2048, 128, 0, stream>>>(x, pos, A);

    for(int d = 0; d < 2; d++){
        for(int c = 0; c < CH; c++){
            const float* Ac = A + (size_t)c*rows*128;
            gemm_mfma<false,false,false,false><<<dim3(6, rows/128), 256, 0, stream>>>(
                Ac, t_qkv_w + d*49152, nullptr, nullptr, TS, 384, 128);
            tattn<<<rows/12, 256, 0, stream>>>(TS, Cb + (size_t)c*rows*128);
        }
        gemm_mfma<true,false,true,false><<<dim3(2,384), 256, 0, stream>>>(
            Cb, t_proj_w + d*16384, t_proj_b + d*128, A, A, 128, 128);
        ln_kernel<<<12288, 256, 0, stream>>>(A, Cb, t_ln_g + d*128, t_ln_b + d*128);
        for(int c = 0; c < CH; c++){
            float* Ac = A + (size_t)c*rows*128;
            gemm_mfma<true,true,false,false><<<dim3(8, rows/128), 256, 0, stream>>>(
                Cb + (size_t)c*rows*128, t_ff_w1 + d*65536, t_ff_b1 + d*512,
                nullptr, TS, 512, 128);
            gemm_mfma<true,false,true,false><<<dim3(2, rows/128), 256, 0, stream>>>(
                TS, t_ff_w2 + d*65536, t_ff_b2 + d*128, Ac, Ac, 128, 512);
        }
    }

    t2s<<<24576, 256, 0, stream>>>(A, E);

    for(int d = 0; d < 2; d++){
        gemm_mfma<false,false,false,false><<<dim3(2,384), 256, 0, stream>>>(
            E, s_q_w + d*16384, nullptr, nullptr, Cb, 128, 128);
        for(int c = 0; c < CH; c++){
            float* Ec = E + (size_t)c*nb*512*128;
            unsigned short* skv_u = (unsigned short*)SS;            // nb*512*256 fp16
            float* att = SS + (size_t)nb*512*128;                    // after skv (f32 units)
            gemm_mfma<false,false,false,true><<<dim3(4, nb*512/128), 256, 0, stream>>>(
                Ec, s_kv_w + d*32768, nullptr, nullptr, skv_u, 256, 128);
            sattn<<<nb*256, 256, 0, stream>>>(
                Cb + (size_t)c*nb*512*128, skv_u, perm, bnd, maskn, gmap,
                s_bias + d*68, att, nb/8);
            gemm_mfma<true,false,true,false><<<dim3(2, nb*512/128), 256, 0, stream>>>(
                att, s_proj_w + d*16384, s_proj_b + d*128, Ec, Ec, 128, 128);
        }
        ln_kernel<<<12288, 256, 0, stream>>>(E, Cb, s_ln_g + d*128, s_ln_b + d*128);
        for(int c = 0; c < CH; c++){
            float* Ec = E + (size_t)c*rows*128;
            gemm_mfma<true,true,false,false><<<dim3(8, rows/128), 256, 0, stream>>>(
                Cb + (size_t)c*rows*128, s_ff_w1 + d*65536, s_ff_b1 + d*512,
                nullptr, SS, 512, 128);
            gemm_mfma<true,false,true,false><<<dim3(2, rows/128), 256, 0, stream>>>(
                SS, s_ff_w2 + d*65536, s_ff_b2 + d*128, Ec, Ec, 128, 512);
        }
    }

    finalt<<<2048, 128, 0, stream>>>(E, (float*)d_out);
}

// Round 7
// 2180.411 us; speedup vs baseline: 2.1516x; 1.0451x over previous
//
#include <hip/hip_runtime.h>
#include <math.h>

// B=4, C=128, N=512, T=24, D=2, H=4, hd=32, WS=12, R=17, MLP=512
#define TOK 6291456   // 49152 * 128 floats (one full token buffer)

typedef _Float16 half8 __attribute__((ext_vector_type(8)));
typedef _Float16 h4 __attribute__((ext_vector_type(4)));
typedef __attribute__((ext_vector_type(4))) float f32x4;

__device__ __forceinline__ float gelu_exact(float x){
    return 0.5f * x * (1.0f + erff(x * 0.70710678118654752f));
}
__device__ __forceinline__ unsigned short f2h(float f){
    return __builtin_bit_cast(unsigned short, (_Float16)f);
}
__device__ __forceinline__ float h2f(unsigned short s){
    return (float)__builtin_bit_cast(_Float16, s);
}

// ---------------------------------------------------------------------------
// s_mask normalizer (probe first 8704 bytes only; classify u8/i32/f32 layout)
// ---------------------------------------------------------------------------
__global__ void normalize_mask(const unsigned char* __restrict__ raw,
                               unsigned char* __restrict__ outm){
    __shared__ int nz[4];
    if(threadIdx.x < 4) nz[threadIdx.x] = 0;
    __syncthreads();
    for(int i = threadIdx.x; i < 8704; i += 256){
        if(raw[i]) atomicOr(&nz[i & 3], 1);
    }
    __syncthreads();
    int mode; // 0=u8, 1=i32, 2=f32
    if(nz[1] | nz[2] | nz[3]) mode = nz[0] ? 0 : 2;
    else                      mode = 1;
    for(int i = threadIdx.x; i < 8704; i += 256){
        unsigned char v;
        if(mode == 0)      v = (raw[i] != 0);
        else if(mode == 1) v = (raw[4*i] != 0);
        else               v = ((raw[4*i+2] | raw[4*i+3]) != 0);
        outm[i] = v;
    }
}

// sec[m][n] = argmax_r assignment[m][n][r]  (exact one-hot f32)
__global__ void build_sec(const float* __restrict__ assign,
                          unsigned char* __restrict__ sec){
    int id = blockIdx.x * 256 + threadIdx.x;
    if(id >= 512*512) return;
    const float* p = assign + (size_t)id * 17;
    int rr = 0;
    #pragma unroll
    for(int r = 0; r < 17; r++) if(p[r] > 0.5f) rr = r;
    sec[id] = (unsigned char)rr;
}

// counting sort of each sec row -> perm/bnd, plus greedy LPT bucket->wave map
__global__ __launch_bounds__(64) void build_perm(const unsigned char* __restrict__ sec,
                                                 const unsigned char* __restrict__ maskn,
                                                 unsigned short* __restrict__ perm,
                                                 int* __restrict__ bnd,
                                                 unsigned char* __restrict__ gmap){
    __shared__ unsigned char row[512];
    __shared__ int cnts[17];
    int m = blockIdx.x;
    int lane = threadIdx.x;
    for(int i = lane; i < 512; i += 64) row[i] = sec[m*512 + i];
    __syncthreads();
    int cnt = 0;
    if(lane < 17){
        for(int n = 0; n < 512; n++) cnt += (row[n] == lane);
        cnts[lane] = cnt;
    }
    int incl = cnt;
    for(int i = 1; i < 32; i <<= 1){
        int v = __shfl_up(incl, i);
        if(lane >= i) incl += v;
    }
    int start = incl - cnt;
    if(lane < 18) bnd[m*18 + lane] = start;
    if(lane < 17){
        int idx = start;
        for(int n = 0; n < 512; n++)
            if(row[n] == lane) perm[m*512 + (idx++)] = (unsigned short)n;
    }
    __syncthreads();
    if(lane == 0){
        int   sz[17]; int used[17]; int load[4] = {0,0,0,0};
        unsigned char gm[17];
        for(int r = 0; r < 17; r++){
            sz[r] = maskn[m*17 + r] ? 0 : cnts[r];
            used[r] = 0; gm[r] = 0;
        }
        for(int it = 0; it < 17; it++){
            int best = -1, bs = -1;
            for(int r = 0; r < 17; r++)
                if(!used[r] && sz[r] > bs){ bs = sz[r]; best = r; }
            int bin = 0;
            for(int g = 1; g < 4; g++) if(load[g] < load[bin]) bin = g;
            used[best] = 1; gm[best] = (unsigned char)bin; load[bin] += sz[best];
        }
        for(int r = 0; r < 17; r++) gmap[m*17 + r] = gm[r];
    }
}

// h[(b*N+n)*T+t][c] = x[b][c][n][t] + pos_emb[t][c]
__global__ __launch_bounds__(128) void stage0(const float* __restrict__ x,
                                              const float* __restrict__ pos,
                                              float* __restrict__ h){
    __shared__ float l[128*25];
    int bid = blockIdx.x;
    int b = bid >> 9, n = bid & 511;
    int tid = threadIdx.x;
    const float* xb = x + (size_t)b*1572864 + (size_t)n*24;
    for(int it = 0; it < 24; it++){
        int i = it*128 + tid;
        int c = i / 24, t = i % 24;
        l[c*25 + t] = xb[(size_t)c*12288 + t];
    }
    __syncthreads();
    float* hb = h + ((size_t)(b*512 + n)) * 24 * 128;
    for(int t = 0; t < 24; t++){
        hb[t*128 + tid] = l[tid*25 + t] + pos[t*128 + tid];
    }
}

// E[(b*T+t)*N+n][c] = A[(b*N+n)*T+t][c]
__global__ void t2s(const float* __restrict__ a, float* __restrict__ e){
    size_t idx = (size_t)blockIdx.x * 256 + threadIdx.x;
    int c = (int)(idx & 127);
    size_t rest = idx >> 7;
    int n = (int)(rest & 511); rest >>= 9;
    int t = (int)(rest % 24);
    int b = (int)(rest / 24);
    e[idx] = a[(((size_t)(b*512 + n))*24 + t)*128 + c];
}

// out[b][c][n][t] = E[(b*T+t)*N+n][c]
__global__ __launch_bounds__(128) void finalt(const float* __restrict__ e,
                                              float* __restrict__ out){
    __shared__ float l[128*25];
    int bid = blockIdx.x;
    int b = bid >> 9, n = bid & 511;
    int tid = threadIdx.x;
    for(int t = 0; t < 24; t++){
        l[tid*25 + t] = e[(((size_t)(b*24 + t))*512 + n)*128 + tid];
    }
    __syncthreads();
    float* ob = out + (size_t)b*1572864 + (size_t)n*24;
    for(int it = 0; it < 24; it++){
        int i = it*128 + tid;
        int c = i / 24, t = i % 24;
        ob[(size_t)c*12288 + t] = l[c*25 + t];
    }
}

// LayerNorm over C=128, one wave per token
__global__ __launch_bounds__(256) void ln_kernel(const float* __restrict__ in,
                                                 float* __restrict__ out,
                                                 const float* __restrict__ g,
                                                 const float* __restrict__ b){
    int w = threadIdx.x >> 6, lane = threadIdx.x & 63;
    int tok = blockIdx.x * 4 + w;
    const float* row = in + (size_t)tok * 128;
    float x0 = row[lane], x1 = row[lane + 64];
    float s  = x0 + x1;
    float s2 = x0*x0 + x1*x1;
    #pragma unroll
    for(int m = 1; m < 64; m <<= 1){
        s  += __shfl_xor(s,  m);
        s2 += __shfl_xor(s2, m);
    }
    float mean = s * (1.0f/128.0f);
    float var  = s2 * (1.0f/128.0f) - mean*mean;
    float rstd = rsqrtf(var + 1e-5f);
    float* o = out + (size_t)tok * 128;
    o[lane]      = (x0 - mean) * rstd * g[lane]      + b[lane];
    o[lane + 64] = (x1 - mean) * rstd * g[lane + 64] + b[lane + 64];
}

// ---------------------------------------------------------------------------
// fp16 MFMA GEMM: out[M,N] = A[M,K] @ W[K,N] (+bias)(+gelu)(+res).
// 128x64 tile, 256 thr (4 waves), mfma_f32_16x16x32_f16, fp32 accum.
// ---------------------------------------------------------------------------
#define LDA 40
template<bool BIAS, bool GELU, bool RES, bool OF16>
__global__ __launch_bounds__(256) void gemm_mfma(const float* __restrict__ A,
                                                 const float* __restrict__ W,
                                                 const float* __restrict__ bias,
                                                 const float* __restrict__ res,
                                                 void* __restrict__ outv,
                                                 int N, int K){
    __shared__ unsigned short As[128*LDA];
    __shared__ unsigned short Ws[64*LDA];
    const int tid = threadIdx.x;
    const int w = tid >> 6, l = tid & 63;
    const int m0 = blockIdx.y * 128;
    const int n0 = blockIdx.x * 64;

    f32x4 acc[2][4];
    #pragma unroll
    for(int i = 0; i < 2; i++)
        #pragma unroll
        for(int nt = 0; nt < 4; nt++) acc[i][nt] = (f32x4){0.f,0.f,0.f,0.f};

    for(int k0 = 0; k0 < K; k0 += 32){
        __syncthreads();
        #pragma unroll
        for(int p = 0; p < 2; p++){
            int r  = (tid >> 2) + p*64;
            int kq = (tid & 3) * 8;
            const float* src = A + (size_t)(m0 + r)*K + k0 + kq;
            float4 v0 = *(const float4*)(src);
            float4 v1 = *(const float4*)(src + 4);
            int4 pk;
            pk.x = (int)((unsigned)f2h(v0.x) | ((unsigned)f2h(v0.y) << 16));
            pk.y = (int)((unsigned)f2h(v0.z) | ((unsigned)f2h(v0.w) << 16));
            pk.z = (int)((unsigned)f2h(v1.x) | ((unsigned)f2h(v1.y) << 16));
            pk.w = (int)((unsigned)f2h(v1.z) | ((unsigned)f2h(v1.w) << 16));
            *(int4*)(&As[r*LDA + kq]) = pk;
        }
        {
            int n  = tid & 63;
            int kb = (tid >> 6) * 8;
            const float* src = W + (size_t)(k0 + kb)*N + n0 + n;
            float v0 = src[0],           v1 = src[(size_t)N];
            float v2 = src[(size_t)2*N], v3 = src[(size_t)3*N];
            float v4 = src[(size_t)4*N], v5 = src[(size_t)5*N];
            float v6 = src[(size_t)6*N], v7 = src[(size_t)7*N];
            int4 pk;
            pk.x = (int)((unsigned)f2h(v0) | ((unsigned)f2h(v1) << 16));
            pk.y = (int)((unsigned)f2h(v2) | ((unsigned)f2h(v3) << 16));
            pk.z = (int)((unsigned)f2h(v4) | ((unsigned)f2h(v5) << 16));
            pk.w = (int)((unsigned)f2h(v6) | ((unsigned)f2h(v7) << 16));
            *(int4*)(&Ws[n*LDA + kb]) = pk;
        }
        __syncthreads();
        half8 a0 = *(const half8*)(&As[(w*32      + (l & 15))*LDA + (l >> 4)*8]);
        half8 a1 = *(const half8*)(&As[(w*32 + 16 + (l & 15))*LDA + (l >> 4)*8]);
        #pragma unroll
        for(int nt = 0; nt < 4; nt++){
            half8 b = *(const half8*)(&Ws[(nt*16 + (l & 15))*LDA + (l >> 4)*8]);
            acc[0][nt] = __builtin_amdgcn_mfma_f32_16x16x32_f16(a0, b, acc[0][nt], 0, 0, 0);
            acc[1][nt] = __builtin_amdgcn_mfma_f32_16x16x32_f16(a1, b, acc[1][nt], 0, 0, 0);
        }
    }

    const int col = l & 15, rg = l >> 4;
    #pragma unroll
    for(int i = 0; i < 2; i++){
        #pragma unroll
        for(int nt = 0; nt < 4; nt++){
            int n = n0 + nt*16 + col;
            float bv = BIAS ? bias[n] : 0.f;
            #pragma unroll
            for(int reg = 0; reg < 4; reg++){
                int m = m0 + w*32 + i*16 + rg*4 + reg;
                float v = acc[i][nt][reg] + bv;
                if(GELU) v = gelu_exact(v);
                if(RES)  v += res[(size_t)m*N + n];
                if(OF16) ((unsigned short*)outv)[(size_t)m*N + n] = f2h(v);
                else     ((float*)outv)[(size_t)m*N + n] = v;
            }
        }
    }
}

// temporal windowed causal attention; qkv rows [q|k|v] 384 wide
__global__ __launch_bounds__(256) void tattn(const float* __restrict__ qkv,
                                             float* __restrict__ out){
    __shared__ float l[12*388];
    int w = blockIdx.x;
    const float* src = qkv + (size_t)w * 12 * 384;
    for(int i = threadIdx.x; i < 12*384; i += 256){
        int q = i / 384, c = i % 384;
        l[q*388 + c] = src[i];
    }
    __syncthreads();
    int h = threadIdx.x >> 6, lane = threadIdx.x & 63;
    if(lane < 12){
        int q = lane;
        const float scale = 0.17677669529663687f;
        float qv[32];
        #pragma unroll
        for(int d = 0; d < 32; d++) qv[d] = l[q*388 + h*32 + d];
        float sc[12];
        #pragma unroll
        for(int k = 0; k < 12; k++){
            float dot = 0.f;
            #pragma unroll
            for(int d = 0; d < 32; d++) dot += qv[d] * l[k*388 + 128 + h*32 + d];
            sc[k] = (k <= q) ? dot * scale : -1e30f;
        }
        float mx = sc[0];
        #pragma unroll
        for(int k = 1; k < 12; k++) mx = fmaxf(mx, sc[k]);
        float sum = 0.f;
        #pragma unroll
        for(int k = 0; k < 12; k++){ sc[k] = expf(sc[k] - mx); sum += sc[k]; }
        float inv = 1.0f / sum;
        float* orow = out + (size_t)(w*12 + q) * 128 + h*32;
        #pragma unroll
        for(int d = 0; d < 32; d++){
            float o = 0.f;
            #pragma unroll
            for(int k = 0; k < 12; k++) o += sc[k] * l[k*388 + 256 + h*32 + d];
            orow[d] = o * inv;
        }
    }
}

// ---------------------------------------------------------------------------
// fused spatial attention; skv rows fp16 (256 ch = 512 B).
// Phase 2 v3: fp16 packed accumulation (v_pk_add_f16), ds_read_b64 perm
// prefetch (4 indices/op), 4 independent chains. ~13 wave-instr / 4 rows.
// ---------------------------------------------------------------------------
__global__ __launch_bounds__(256) void sattn(const float* __restrict__ qbuf,
                                             const unsigned short* __restrict__ skv,
                                             const unsigned short* __restrict__ perm,
                                             const int* __restrict__ bnd,
                                             const unsigned char* __restrict__ mask,
                                             const unsigned char* __restrict__ gmap,
                                             const float* __restrict__ bias,
                                             float* __restrict__ out,
                                             int nb8){
    __shared__ float kv[2][17][256];
    __shared__ float ql[2][128];
    __shared__ float lg[2][4][17];
    __shared__ float al[2][4][17];
    __shared__ __align__(16) unsigned short pml[2][512];
    __shared__ int bndl[2][18];
    __shared__ int mkl[2][17];
    __shared__ int gml[2][17];

    int bid = blockIdx.x;
    int b  = (bid & 7) * nb8 + ((bid >> 3) >> 8);   // XCD-grouped bt
    int m0 = ((bid >> 3) & 255) * 2;
    int tid = threadIdx.x;

    { int mi = tid >> 7, c = tid & 127;
      ql[mi][c] = qbuf[((size_t)(b*512 + m0 + mi))*128 + c]; }
    for(int i = tid; i < 1024; i += 256){
        int mi = i >> 9, j = i & 511;
        pml[mi][j] = perm[(m0 + mi)*512 + j];
    }
    if(tid < 36){ int mi = tid/18, r = tid%18; bndl[mi][r] = bnd[(m0+mi)*18 + r]; }
    if(tid < 34){ int mi = tid/17, r = tid%17; mkl[mi][r] = mask[(m0+mi)*17 + r]; }
    if(tid >= 64 && tid < 98){
        int j = tid - 64; int mi = j/17, r = j%17;
        gml[mi][r] = gmap[(m0+mi)*17 + r];
    }
    __syncthreads();

    // phase 2: segmented bucket sums, fp16 packed accum, 4 chains
    { int g = tid >> 6, lane = tid & 63;
      const unsigned short* skvb = skv + (size_t)b*512*256 + lane*4;
      #pragma unroll
      for(int mi = 0; mi < 2; mi++){
          for(int r = 0; r < 17; r++){
              if(mkl[mi][r] || gml[mi][r] != g) continue;
              int s = bndl[mi][r], e = bndl[mi][r+1];
              h4 a0 = {0,0,0,0}, a1 = {0,0,0,0}, a2 = {0,0,0,0}, a3 = {0,0,0,0};
              int i = s;
              for(; i < e && (i & 3); i++)
                  a0 += *(const h4*)(skvb + (int)pml[mi][i] * 256);
              for(; i + 4 <= e; i += 4){
                  ushort4 p4 = *(const ushort4*)(&pml[mi][i]);   // ds_read_b64
                  a0 += *(const h4*)(skvb + (int)p4.x * 256);
                  a1 += *(const h4*)(skvb + (int)p4.y * 256);
                  a2 += *(const h4*)(skvb + (int)p4.z * 256);
                  a3 += *(const h4*)(skvb + (int)p4.w * 256);
              }
              for(; i < e; i++)
                  a0 += *(const h4*)(skvb + (int)pml[mi][i] * 256);
              h4 t = (a0 + a1) + (a2 + a3);
              float4 kvv = make_float4((float)t.x, (float)t.y, (float)t.z, (float)t.w);
              *(float4*)(&kv[mi][r][lane*4]) = kvv;
          }
      }
    }
    __syncthreads();

    // phase 3: logits
    { int h = tid >> 6; int mi = (tid >> 5) & 1; int d = tid & 31;
      float qv = ql[mi][h*32 + d];
      for(int r = 0; r < 17; r++){
          if(mkl[mi][r]) continue;
          float v = qv * kv[mi][r][h*32 + d];
          v += __shfl_xor(v, 16); v += __shfl_xor(v, 8);
          v += __shfl_xor(v, 4);  v += __shfl_xor(v, 2); v += __shfl_xor(v, 1);
          if(d == 0) lg[mi][h][r] = v * 0.17677669529663687f + bias[h*17 + r];
      }
    }
    __syncthreads();

    // phase 4: softmax over unmasked r
    if(tid < 8){
        int mi = tid >> 2, h = tid & 3;
        float mx = -1e30f;
        for(int r = 0; r < 17; r++) if(!mkl[mi][r]) mx = fmaxf(mx, lg[mi][h][r]);
        float sum = 0.f;
        for(int r = 0; r < 17; r++){
            if(!mkl[mi][r]){ float e = expf(lg[mi][h][r] - mx); al[mi][h][r] = e; sum += e; }
            else al[mi][h][r] = 0.f;
        }
        float inv = 1.0f / sum;
        for(int r = 0; r < 17; r++) al[mi][h][r] *= inv;
    }
    __syncthreads();

    // phase 5: out = sum_r a[r] * V[r]
    { int mi = tid >> 7, c = tid & 127, h = c >> 5;
      float o = 0.f;
      for(int r = 0; r < 17; r++){
          if(mkl[mi][r]) continue;
          o += al[mi][h][r] * kv[mi][r][128 + c];
      }
      out[((size_t)(b*512 + m0 + mi))*128 + c] = o;
    }
}

// ---------------------------------------------------------------------------
extern "C" void kernel_launch(void* const* d_in, const int* in_sizes, int n_in,
                              void* d_out, int out_size, void* d_ws, size_t ws_size,
                              hipStream_t stream){
    const float* x        = (const float*)d_in[0];
    const float* pos      = (const float*)d_in[1];
    const float* t_qkv_w  = (const float*)d_in[2];
    const float* t_proj_w = (const float*)d_in[3];
    const float* t_proj_b = (const float*)d_in[4];
    const float* t_ln_g   = (const float*)d_in[5];
    const float* t_ln_b   = (const float*)d_in[6];
    const float* t_ff_w1  = (const float*)d_in[7];
    const float* t_ff_b1  = (const float*)d_in[8];
    const float* t_ff_w2  = (const float*)d_in[9];
    const float* t_ff_b2  = (const float*)d_in[10];
    const float* assign   = (const float*)d_in[11];
    const unsigned char* s_mask_raw = (const unsigned char*)d_in[12];  // dict order!
    const float* s_q_w    = (const float*)d_in[13];
    const float* s_kv_w   = (const float*)d_in[14];
    const float* s_bias   = (const float*)d_in[15];
    const float* s_proj_w = (const float*)d_in[16];
    const float* s_proj_b = (const float*)d_in[17];
    const float* s_ln_g   = (const float*)d_in[18];
    const float* s_ln_b   = (const float*)d_in[19];
    const float* s_ff_w1  = (const float*)d_in[20];
    const float* s_ff_b1  = (const float*)d_in[21];
    const float* s_ff_w2  = (const float*)d_in[22];
    const float* s_ff_b2  = (const float*)d_in[23];

    float* ws = (float*)d_ws;
    float* Cb = (float*)d_out;   // reused as full-M scratch (q buf / LN out)

    // CH=1 (unchunked) needs ~153 MB of ws; CH=4 needs ~51.2 MB.
    const int CH = (ws_size >= (size_t)160*1024*1024) ? 1 : 4;
    float* A  = ws;
    float* TS = ws + TOK;
    float* E  = (CH==1) ? (ws + 5*(size_t)TOK) : (ws + TOK);
    float* SS = (CH==1) ? TS : A;
    char*  sb = (char*)(ws + ((CH==1)? 6*(size_t)TOK : 2*(size_t)TOK));
    unsigned char*  sec   = (unsigned char*)sb;              // 262144 B
    unsigned short* perm  = (unsigned short*)(sb + 262144);  // 524288 B
    int*            bnd   = (int*)(sb + 786432);             // 36864 B
    unsigned char*  maskn = (unsigned char*)(sb + 823296);   // 8704 B
    unsigned char*  gmap  = (unsigned char*)(sb + 832000);   // 8704 B

    const int rows = 49152 / CH;       // M rows per chunk (multiple of 128)
    const int nb   = 96 / CH;          // bt values per spatial chunk

    normalize_mask<<<1, 256, 0, stream>>>(s_mask_raw, maskn);
    build_sec<<<1024, 256, 0, stream>>>(assign, sec);
    build_perm<<<512, 64, 0, stream>>>(sec, maskn, perm, bnd, gmap);
    stage0<<<2048, 128, 0, stream>>>(x, pos, A);

    for(int d = 0; d < 2; d++){
        for(int c = 0; c < CH; c++){
            const float* Ac = A + (size_t)c*rows*128;
            gemm_mfma<false,false,false,false><<<dim3(6, rows/128), 256, 0, stream>>>(
                Ac, t_qkv_w + d*49152, nullptr, nullptr, TS, 384, 128);
            tattn<<<rows/12, 256, 0, stream>>>(TS, Cb + (size_t)c*rows*128);
        }
        gemm_mfma<true,false,true,false><<<dim3(2,384), 256, 0, stream>>>(
            Cb, t_proj_w + d*16384, t_proj_b + d*128, A, A, 128, 128);
        ln_kernel<<<12288, 256, 0, stream>>>(A, Cb, t_ln_g + d*128, t_ln_b + d*128);
        for(int c = 0; c < CH; c++){
            float* Ac = A + (size_t)c*rows*128;
            gemm_mfma<true,true,false,false><<<dim3(8, rows/128), 256, 0, stream>>>(
                Cb + (size_t)c*rows*128, t_ff_w1 + d*65536, t_ff_b1 + d*512,
                nullptr, TS, 512, 128);
            gemm_mfma<true,false,true,false><<<dim3(2, rows/128), 256, 0, stream>>>(
                TS, t_ff_w2 + d*65536, t_ff_b2 + d*128, Ac, Ac, 128, 512);
        }
    }

    t2s<<<24576, 256, 0, stream>>>(A, E);

    for(int d = 0; d < 2; d++){
        gemm_mfma<false,false,false,false><<<dim3(2,384), 256, 0, stream>>>(
            E, s_q_w + d*16384, nullptr, nullptr, Cb, 128, 128);
        for(int c = 0; c < CH; c++){
            float* Ec = E + (size_t)c*nb*512*128;
            unsigned short* skv_u = (unsigned short*)SS;            // nb*512*256 fp16
            float* att = SS + (size_t)nb*512*128;                    // after skv (f32 units)
            gemm_mfma<false,false,false,true><<<dim3(4, nb*512/128), 256, 0, stream>>>(
                Ec, s_kv_w + d*32768, nullptr, nullptr, skv_u, 256, 128);
            sattn<<<nb*256, 256, 0, stream>>>(
                Cb + (size_t)c*nb*512*128, skv_u, perm, bnd, maskn, gmap,
                s_bias + d*68, att, nb/8);
            gemm_mfma<true,false,true,false><<<dim3(2, nb*512/128), 256, 0, stream>>>(
                att, s_proj_w + d*16384, s_proj_b + d*128, Ec, Ec, 128, 128);
        }
        ln_kernel<<<12288, 256, 0, stream>>>(E, Cb, s_ln_g + d*128, s_ln_b + d*128);
        for(int c = 0; c < CH; c++){
            float* Ec = E + (size_t)c*rows*128;
            gemm_mfma<true,true,false,false><<<dim3(8, rows/128), 256, 0, stream>>>(
                Cb + (size_t)c*rows*128, s_ff_w1 + d*65536, s_ff_b1 + d*512,
                nullptr, SS, 512, 128);
            gemm_mfma<true,false,true,false><<<dim3(2, rows/128), 256, 0, stream>>>(
                SS, s_ff_w2 + d*65536, s_ff_b2 + d*128, Ec, Ec, 128, 512);
        }
    }

    finalt<<<2048, 128, 0, stream>>>(E, (float*)d_out);
}

// Round 8
// 1777.256 us; speedup vs baseline: 2.6397x; 1.2268x over previous
//
#include <hip/hip_runtime.h>
#include <math.h>

// B=4, C=128, N=512, T=24, D=2, H=4, hd=32, WS=12, R=17, MLP=512
#define TOK 6291456   // 49152 * 128 floats (one full token buffer)

typedef _Float16 half8 __attribute__((ext_vector_type(8)));
typedef _Float16 h8 __attribute__((ext_vector_type(8)));
typedef __attribute__((ext_vector_type(4))) float f32x4;

__device__ __forceinline__ float gelu_exact(float x){
    return 0.5f * x * (1.0f + erff(x * 0.70710678118654752f));
}
__device__ __forceinline__ unsigned short f2h(float f){
    return __builtin_bit_cast(unsigned short, (_Float16)f);
}

// ---------------------------------------------------------------------------
// s_mask normalizer (probe first 8704 bytes only; classify u8/i32/f32 layout)
// ---------------------------------------------------------------------------
__global__ void normalize_mask(const unsigned char* __restrict__ raw,
                               unsigned char* __restrict__ outm){
    __shared__ int nz[4];
    if(threadIdx.x < 4) nz[threadIdx.x] = 0;
    __syncthreads();
    for(int i = threadIdx.x; i < 8704; i += 256){
        if(raw[i]) atomicOr(&nz[i & 3], 1);
    }
    __syncthreads();
    int mode; // 0=u8, 1=i32, 2=f32
    if(nz[1] | nz[2] | nz[3]) mode = nz[0] ? 0 : 2;
    else                      mode = 1;
    for(int i = threadIdx.x; i < 8704; i += 256){
        unsigned char v;
        if(mode == 0)      v = (raw[i] != 0);
        else if(mode == 1) v = (raw[4*i] != 0);
        else               v = ((raw[4*i+2] | raw[4*i+3]) != 0);
        outm[i] = v;
    }
}

// sec[m][n] = argmax_r assignment[m][n][r]  (exact one-hot f32)
__global__ void build_sec(const float* __restrict__ assign,
                          unsigned char* __restrict__ sec){
    int id = blockIdx.x * 256 + threadIdx.x;
    if(id >= 512*512) return;
    const float* p = assign + (size_t)id * 17;
    int rr = 0;
    #pragma unroll
    for(int r = 0; r < 17; r++) if(p[r] > 0.5f) rr = r;
    sec[id] = (unsigned char)rr;
}

// counting sort of each sec row -> perm/bnd, plus greedy LPT bucket->wave map
__global__ __launch_bounds__(64) void build_perm(const unsigned char* __restrict__ sec,
                                                 const unsigned char* __restrict__ maskn,
                                                 unsigned short* __restrict__ perm,
                                                 int* __restrict__ bnd,
                                                 unsigned char* __restrict__ gmap){
    __shared__ unsigned char row[512];
    __shared__ int cnts[17];
    int m = blockIdx.x;
    int lane = threadIdx.x;
    for(int i = lane; i < 512; i += 64) row[i] = sec[m*512 + i];
    __syncthreads();
    int cnt = 0;
    if(lane < 17){
        for(int n = 0; n < 512; n++) cnt += (row[n] == lane);
        cnts[lane] = cnt;
    }
    int incl = cnt;
    for(int i = 1; i < 32; i <<= 1){
        int v = __shfl_up(incl, i);
        if(lane >= i) incl += v;
    }
    int start = incl - cnt;
    if(lane < 18) bnd[m*18 + lane] = start;
    if(lane < 17){
        int idx = start;
        for(int n = 0; n < 512; n++)
            if(row[n] == lane) perm[m*512 + (idx++)] = (unsigned short)n;
    }
    __syncthreads();
    if(lane == 0){
        int   sz[17]; int used[17]; int load[4] = {0,0,0,0};
        unsigned char gm[17];
        for(int r = 0; r < 17; r++){
            sz[r] = maskn[m*17 + r] ? 0 : cnts[r];
            used[r] = 0; gm[r] = 0;
        }
        for(int it = 0; it < 17; it++){
            int best = -1, bs = -1;
            for(int r = 0; r < 17; r++)
                if(!used[r] && sz[r] > bs){ bs = sz[r]; best = r; }
            int bin = 0;
            for(int g = 1; g < 4; g++) if(load[g] < load[bin]) bin = g;
            used[best] = 1; gm[best] = (unsigned char)bin; load[bin] += sz[best];
        }
        for(int r = 0; r < 17; r++) gmap[m*17 + r] = gm[r];
    }
}

// h[(b*N+n)*T+t][c] = x[b][c][n][t] + pos_emb[t][c]
__global__ __launch_bounds__(128) void stage0(const float* __restrict__ x,
                                              const float* __restrict__ pos,
                                              float* __restrict__ h){
    __shared__ float l[128*25];
    int bid = blockIdx.x;
    int b = bid >> 9, n = bid & 511;
    int tid = threadIdx.x;
    const float* xb = x + (size_t)b*1572864 + (size_t)n*24;
    for(int it = 0; it < 24; it++){
        int i = it*128 + tid;
        int c = i / 24, t = i % 24;
        l[c*25 + t] = xb[(size_t)c*12288 + t];
    }
    __syncthreads();
    float* hb = h + ((size_t)(b*512 + n)) * 24 * 128;
    for(int t = 0; t < 24; t++){
        hb[t*128 + tid] = l[tid*25 + t] + pos[t*128 + tid];
    }
}

// E[(b*T+t)*N+n][c] = A[(b*N+n)*T+t][c]
__global__ void t2s(const float* __restrict__ a, float* __restrict__ e){
    size_t idx = (size_t)blockIdx.x * 256 + threadIdx.x;
    int c = (int)(idx & 127);
    size_t rest = idx >> 7;
    int n = (int)(rest & 511); rest >>= 9;
    int t = (int)(rest % 24);
    int b = (int)(rest / 24);
    e[idx] = a[(((size_t)(b*512 + n))*24 + t)*128 + c];
}

// out[b][c][n][t] = E[(b*T+t)*N+n][c]
__global__ __launch_bounds__(128) void finalt(const float* __restrict__ e,
                                              float* __restrict__ out){
    __shared__ float l[128*25];
    int bid = blockIdx.x;
    int b = bid >> 9, n = bid & 511;
    int tid = threadIdx.x;
    for(int t = 0; t < 24; t++){
        l[tid*25 + t] = e[(((size_t)(b*24 + t))*512 + n)*128 + tid];
    }
    __syncthreads();
    float* ob = out + (size_t)b*1572864 + (size_t)n*24;
    for(int it = 0; it < 24; it++){
        int i = it*128 + tid;
        int c = i / 24, t = i % 24;
        ob[(size_t)c*12288 + t] = l[c*25 + t];
    }
}

// LayerNorm over C=128, one wave per token
__global__ __launch_bounds__(256) void ln_kernel(const float* __restrict__ in,
                                                 float* __restrict__ out,
                                                 const float* __restrict__ g,
                                                 const float* __restrict__ b){
    int w = threadIdx.x >> 6, lane = threadIdx.x & 63;
    int tok = blockIdx.x * 4 + w;
    const float* row = in + (size_t)tok * 128;
    float x0 = row[lane], x1 = row[lane + 64];
    float s  = x0 + x1;
    float s2 = x0*x0 + x1*x1;
    #pragma unroll
    for(int m = 1; m < 64; m <<= 1){
        s  += __shfl_xor(s,  m);
        s2 += __shfl_xor(s2, m);
    }
    float mean = s * (1.0f/128.0f);
    float var  = s2 * (1.0f/128.0f) - mean*mean;
    float rstd = rsqrtf(var + 1e-5f);
    float* o = out + (size_t)tok * 128;
    o[lane]      = (x0 - mean) * rstd * g[lane]      + b[lane];
    o[lane + 64] = (x1 - mean) * rstd * g[lane + 64] + b[lane + 64];
}

// ---------------------------------------------------------------------------
// fp16 MFMA GEMM: out[M,N] = A[M,K] @ W[K,N] (+bias)(+gelu)(+res).
// 128x64 tile, 256 thr (4 waves), mfma_f32_16x16x32_f16, fp32 accum.
// ---------------------------------------------------------------------------
#define LDA 40
template<bool BIAS, bool GELU, bool RES, bool OF16>
__global__ __launch_bounds__(256) void gemm_mfma(const float* __restrict__ A,
                                                 const float* __restrict__ W,
                                                 const float* __restrict__ bias,
                                                 const float* __restrict__ res,
                                                 void* __restrict__ outv,
                                                 int N, int K){
    __shared__ unsigned short As[128*LDA];
    __shared__ unsigned short Ws[64*LDA];
    const int tid = threadIdx.x;
    const int w = tid >> 6, l = tid & 63;
    const int m0 = blockIdx.y * 128;
    const int n0 = blockIdx.x * 64;

    f32x4 acc[2][4];
    #pragma unroll
    for(int i = 0; i < 2; i++)
        #pragma unroll
        for(int nt = 0; nt < 4; nt++) acc[i][nt] = (f32x4){0.f,0.f,0.f,0.f};

    for(int k0 = 0; k0 < K; k0 += 32){
        __syncthreads();
        #pragma unroll
        for(int p = 0; p < 2; p++){
            int r  = (tid >> 2) + p*64;
            int kq = (tid & 3) * 8;
            const float* src = A + (size_t)(m0 + r)*K + k0 + kq;
            float4 v0 = *(const float4*)(src);
            float4 v1 = *(const float4*)(src + 4);
            int4 pk;
            pk.x = (int)((unsigned)f2h(v0.x) | ((unsigned)f2h(v0.y) << 16));
            pk.y = (int)((unsigned)f2h(v0.z) | ((unsigned)f2h(v0.w) << 16));
            pk.z = (int)((unsigned)f2h(v1.x) | ((unsigned)f2h(v1.y) << 16));
            pk.w = (int)((unsigned)f2h(v1.z) | ((unsigned)f2h(v1.w) << 16));
            *(int4*)(&As[r*LDA + kq]) = pk;
        }
        {
            int n  = tid & 63;
            int kb = (tid >> 6) * 8;
            const float* src = W + (size_t)(k0 + kb)*N + n0 + n;
            float v0 = src[0],           v1 = src[(size_t)N];
            float v2 = src[(size_t)2*N], v3 = src[(size_t)3*N];
            float v4 = src[(size_t)4*N], v5 = src[(size_t)5*N];
            float v6 = src[(size_t)6*N], v7 = src[(size_t)7*N];
            int4 pk;
            pk.x = (int)((unsigned)f2h(v0) | ((unsigned)f2h(v1) << 16));
            pk.y = (int)((unsigned)f2h(v2) | ((unsigned)f2h(v3) << 16));
            pk.z = (int)((unsigned)f2h(v4) | ((unsigned)f2h(v5) << 16));
            pk.w = (int)((unsigned)f2h(v6) | ((unsigned)f2h(v7) << 16));
            *(int4*)(&Ws[n*LDA + kb]) = pk;
        }
        __syncthreads();
        half8 a0 = *(const half8*)(&As[(w*32      + (l & 15))*LDA + (l >> 4)*8]);
        half8 a1 = *(const half8*)(&As[(w*32 + 16 + (l & 15))*LDA + (l >> 4)*8]);
        #pragma unroll
        for(int nt = 0; nt < 4; nt++){
            half8 b = *(const half8*)(&Ws[(nt*16 + (l & 15))*LDA + (l >> 4)*8]);
            acc[0][nt] = __builtin_amdgcn_mfma_f32_16x16x32_f16(a0, b, acc[0][nt], 0, 0, 0);
            acc[1][nt] = __builtin_amdgcn_mfma_f32_16x16x32_f16(a1, b, acc[1][nt], 0, 0, 0);
        }
    }

    const int col = l & 15, rg = l >> 4;
    #pragma unroll
    for(int i = 0; i < 2; i++){
        #pragma unroll
        for(int nt = 0; nt < 4; nt++){
            int n = n0 + nt*16 + col;
            float bv = BIAS ? bias[n] : 0.f;
            #pragma unroll
            for(int reg = 0; reg < 4; reg++){
                int m = m0 + w*32 + i*16 + rg*4 + reg;
                float v = acc[i][nt][reg] + bv;
                if(GELU) v = gelu_exact(v);
                if(RES)  v += res[(size_t)m*N + n];
                if(OF16) ((unsigned short*)outv)[(size_t)m*N + n] = f2h(v);
                else     ((float*)outv)[(size_t)m*N + n] = v;
            }
        }
    }
}

// temporal windowed causal attention; qkv rows [q|k|v] 384 wide
__global__ __launch_bounds__(256) void tattn(const float* __restrict__ qkv,
                                             float* __restrict__ out){
    __shared__ float l[12*388];
    int w = blockIdx.x;
    const float* src = qkv + (size_t)w * 12 * 384;
    for(int i = threadIdx.x; i < 12*384; i += 256){
        int q = i / 384, c = i % 384;
        l[q*388 + c] = src[i];
    }
    __syncthreads();
    int h = threadIdx.x >> 6, lane = threadIdx.x & 63;
    if(lane < 12){
        int q = lane;
        const float scale = 0.17677669529663687f;
        float qv[32];
        #pragma unroll
        for(int d = 0; d < 32; d++) qv[d] = l[q*388 + h*32 + d];
        float sc[12];
        #pragma unroll
        for(int k = 0; k < 12; k++){
            float dot = 0.f;
            #pragma unroll
            for(int d = 0; d < 32; d++) dot += qv[d] * l[k*388 + 128 + h*32 + d];
            sc[k] = (k <= q) ? dot * scale : -1e30f;
        }
        float mx = sc[0];
        #pragma unroll
        for(int k = 1; k < 12; k++) mx = fmaxf(mx, sc[k]);
        float sum = 0.f;
        #pragma unroll
        for(int k = 0; k < 12; k++){ sc[k] = expf(sc[k] - mx); sum += sc[k]; }
        float inv = 1.0f / sum;
        float* orow = out + (size_t)(w*12 + q) * 128 + h*32;
        #pragma unroll
        for(int d = 0; d < 32; d++){
            float o = 0.f;
            #pragma unroll
            for(int k = 0; k < 12; k++) o += sc[k] * l[k*388 + 256 + h*32 + d];
            orow[d] = o * inv;
        }
    }
}

// ---------------------------------------------------------------------------
// fused spatial attention; skv rows fp16 (256 ch = 512 B).
// Phase 2 v4: TWO rows per global_load_dwordx4 (lanes 0-31 row i, 32-63 row
// i+1; lane owns 8 fp16 ch at (l&31)*8). 2 chains = 4 rows/iter. Parity
// partials combined with one shfl_xor(32) per bucket. kv LDS is fp16.
// ---------------------------------------------------------------------------
__global__ __launch_bounds__(256) void sattn(const float* __restrict__ qbuf,
                                             const unsigned short* __restrict__ skv,
                                             const unsigned short* __restrict__ perm,
                                             const int* __restrict__ bnd,
                                             const unsigned char* __restrict__ mask,
                                             const unsigned char* __restrict__ gmap,
                                             const float* __restrict__ bias,
                                             float* __restrict__ out,
                                             int nb8){
    __shared__ _Float16 kvh[2][17][256];
    __shared__ float ql[2][128];
    __shared__ float lg[2][4][17];
    __shared__ float al[2][4][17];
    __shared__ __align__(16) unsigned short pml[2][512];
    __shared__ int bndl[2][18];
    __shared__ int mkl[2][17];
    __shared__ int gml[2][17];

    int bid = blockIdx.x;
    int b  = (bid & 7) * nb8 + ((bid >> 3) >> 8);   // XCD-grouped bt
    int m0 = ((bid >> 3) & 255) * 2;
    int tid = threadIdx.x;

    { int mi = tid >> 7, c = tid & 127;
      ql[mi][c] = qbuf[((size_t)(b*512 + m0 + mi))*128 + c]; }
    for(int i = tid; i < 1024; i += 256){
        int mi = i >> 9, j = i & 511;
        pml[mi][j] = perm[(m0 + mi)*512 + j];
    }
    if(tid < 36){ int mi = tid/18, r = tid%18; bndl[mi][r] = bnd[(m0+mi)*18 + r]; }
    if(tid < 34){ int mi = tid/17, r = tid%17; mkl[mi][r] = mask[(m0+mi)*17 + r]; }
    if(tid >= 64 && tid < 98){
        int j = tid - 64; int mi = j/17, r = j%17;
        gml[mi][r] = gmap[(m0+mi)*17 + r];
    }
    __syncthreads();

    // phase 2: segmented bucket sums; 2 rows per b128 load, fp16 packed accum
    { int g = tid >> 6, lane = tid & 63;
      int half = lane >> 5, cl = lane & 31;
      const unsigned short* skvb = skv + (size_t)b*512*256 + cl*8;
      #pragma unroll
      for(int mi = 0; mi < 2; mi++){
          for(int r = 0; r < 17; r++){
              if(mkl[mi][r] || gml[mi][r] != g) continue;
              int s = bndl[mi][r], e = bndl[mi][r+1];
              h8 a0 = {0,0,0,0,0,0,0,0}, a1 = a0;
              int i = s;
              if(i < e && (i & 1)){              // peel to even index
                  if(half == 0)
                      a0 += *(const h8*)(skvb + (int)pml[mi][i] * 256);
                  i++;
              }
              for(; i + 4 <= e; i += 4){
                  ushort2 p0 = *(const ushort2*)(&pml[mi][i]);
                  ushort2 p1 = *(const ushort2*)(&pml[mi][i+2]);
                  int i0 = half ? (int)p0.y : (int)p0.x;
                  int i1 = half ? (int)p1.y : (int)p1.x;
                  a0 += *(const h8*)(skvb + i0 * 256);
                  a1 += *(const h8*)(skvb + i1 * 256);
              }
              if(i + 2 <= e){
                  ushort2 p0 = *(const ushort2*)(&pml[mi][i]);
                  int i0 = half ? (int)p0.y : (int)p0.x;
                  a0 += *(const h8*)(skvb + i0 * 256);
                  i += 2;
              }
              if(i < e){                          // single tail row
                  if(half == 0)
                      a0 += *(const h8*)(skvb + (int)pml[mi][i] * 256);
              }
              h8 t = a0 + a1;
              float4 f = __builtin_bit_cast(float4, t);
              float4 o;
              o.x = __shfl_xor(f.x, 32);
              o.y = __shfl_xor(f.y, 32);
              o.z = __shfl_xor(f.z, 32);
              o.w = __shfl_xor(f.w, 32);
              t = t + __builtin_bit_cast(h8, o);
              if(half == 0)
                  *(h8*)(&kvh[mi][r][cl*8]) = t;  // lanes 0-31: 16B LDS write
          }
      }
    }
    __syncthreads();

    // phase 3: logits
    { int h = tid >> 6; int mi = (tid >> 5) & 1; int d = tid & 31;
      float qv = ql[mi][h*32 + d];
      for(int r = 0; r < 17; r++){
          if(mkl[mi][r]) continue;
          float v = qv * (float)kvh[mi][r][h*32 + d];
          v += __shfl_xor(v, 16); v += __shfl_xor(v, 8);
          v += __shfl_xor(v, 4);  v += __shfl_xor(v, 2); v += __shfl_xor(v, 1);
          if(d == 0) lg[mi][h][r] = v * 0.17677669529663687f + bias[h*17 + r];
      }
    }
    __syncthreads();

    // phase 4: softmax over unmasked r
    if(tid < 8){
        int mi = tid >> 2, h = tid & 3;
        float mx = -1e30f;
        for(int r = 0; r < 17; r++) if(!mkl[mi][r]) mx = fmaxf(mx, lg[mi][h][r]);
        float sum = 0.f;
        for(int r = 0; r < 17; r++){
            if(!mkl[mi][r]){ float e = expf(lg[mi][h][r] - mx); al[mi][h][r] = e; sum += e; }
            else al[mi][h][r] = 0.f;
        }
        float inv = 1.0f / sum;
        for(int r = 0; r < 17; r++) al[mi][h][r] *= inv;
    }
    __syncthreads();

    // phase 5: out = sum_r a[r] * V[r]
    { int mi = tid >> 7, c = tid & 127, h = c >> 5;
      float o = 0.f;
      for(int r = 0; r < 17; r++){
          if(mkl[mi][r]) continue;
          o += al[mi][h][r] * (float)kvh[mi][r][128 + c];
      }
      out[((size_t)(b*512 + m0 + mi))*128 + c] = o;
    }
}

// ---------------------------------------------------------------------------
extern "C" void kernel_launch(void* const* d_in, const int* in_sizes, int n_in,
                              void* d_out, int out_size, void* d_ws, size_t ws_size,
                              hipStream_t stream){
    const float* x        = (const float*)d_in[0];
    const float* pos      = (const float*)d_in[1];
    const float* t_qkv_w  = (const float*)d_in[2];
    const float* t_proj_w = (const float*)d_in[3];
    const float* t_proj_b = (const float*)d_in[4];
    const float* t_ln_g   = (const float*)d_in[5];
    const float* t_ln_b   = (const float*)d_in[6];
    const float* t_ff_w1  = (const float*)d_in[7];
    const float* t_ff_b1  = (const float*)d_in[8];
    const float* t_ff_w2  = (const float*)d_in[9];
    const float* t_ff_b2  = (const float*)d_in[10];
    const float* assign   = (const float*)d_in[11];
    const unsigned char* s_mask_raw = (const unsigned char*)d_in[12];  // dict order!
    const float* s_q_w    = (const float*)d_in[13];
    const float* s_kv_w   = (const float*)d_in[14];
    const float* s_bias   = (const float*)d_in[15];
    const float* s_proj_w = (const float*)d_in[16];
    const float* s_proj_b = (const float*)d_in[17];
    const float* s_ln_g   = (const float*)d_in[18];
    const float* s_ln_b   = (const float*)d_in[19];
    const float* s_ff_w1  = (const float*)d_in[20];
    const float* s_ff_b1  = (const float*)d_in[21];
    const float* s_ff_w2  = (const float*)d_in[22];
    const float* s_ff_b2  = (const float*)d_in[23];

    float* ws = (float*)d_ws;
    float* Cb = (float*)d_out;   // reused as full-M scratch (q buf / LN out)

    // CH=1 (unchunked) needs ~153 MB of ws; CH=4 needs ~51.2 MB.
    const int CH = (ws_size >= (size_t)160*1024*1024) ? 1 : 4;
    float* A  = ws;
    float* TS = ws + TOK;
    float* E  = (CH==1) ? (ws + 5*(size_t)TOK) : (ws + TOK);
    float* SS = (CH==1) ? TS : A;
    char*  sb = (char*)(ws + ((CH==1)? 6*(size_t)TOK : 2*(size_t)TOK));
    unsigned char*  sec   = (unsigned char*)sb;              // 262144 B
    unsigned short* perm  = (unsigned short*)(sb + 262144);  // 524288 B
    int*            bnd   = (int*)(sb + 786432);             // 36864 B
    unsigned char*  maskn = (unsigned char*)(sb + 823296);   // 8704 B
    unsigned char*  gmap  = (unsigned char*)(sb + 832000);   // 8704 B

    const int rows = 49152 / CH;       // M rows per chunk (multiple of 128)
    const int nb   = 96 / CH;          // bt values per spatial chunk

    normalize_mask<<<1, 256, 0, stream>>>(s_mask_raw, maskn);
    build_sec<<<1024, 256, 0, stream>>>(assign, sec);
    build_perm<<<512, 64, 0, stream>>>(sec, maskn, perm, bnd, gmap);
    stage0<<<2048, 128, 0, stream>>>(x, pos, A);

    for(int d = 0; d < 2; d++){
        for(int c = 0; c < CH; c++){
            const float* Ac = A + (size_t)c*rows*128;
            gemm_mfma<false,false,false,false><<<dim3(6, rows/128), 256, 0, stream>>>(
                Ac, t_qkv_w + d*49152, nullptr, nullptr, TS, 384, 128);
            tattn<<<rows/12, 256, 0, stream>>>(TS, Cb + (size_t)c*rows*128);
        }
        gemm_mfma<true,false,true,false><<<dim3(2,384), 256, 0, stream>>>(
            Cb, t_proj_w + d*16384, t_proj_b + d*128, A, A, 128, 128);
        ln_kernel<<<12288, 256, 0, stream>>>(A, Cb, t_ln_g + d*128, t_ln_b + d*128);
        for(int c = 0; c < CH; c++){
            float* Ac = A + (size_t)c*rows*128;
            gemm_mfma<true,true,false,false><<<dim3(8, rows/128), 256, 0, stream>>>(
                Cb + (size_t)c*rows*128, t_ff_w1 + d*65536, t_ff_b1 + d*512,
                nullptr, TS, 512, 128);
            gemm_mfma<true,false,true,false><<<dim3(2, rows/128), 256, 0, stream>>>(
                TS, t_ff_w2 + d*65536, t_ff_b2 + d*128, Ac, Ac, 128, 512);
        }
    }

    t2s<<<24576, 256, 0, stream>>>(A, E);

    for(int d = 0; d < 2; d++){
        gemm_mfma<false,false,false,false><<<dim3(2,384), 256, 0, stream>>>(
            E, s_q_w + d*16384, nullptr, nullptr, Cb, 128, 128);
        for(int c = 0; c < CH; c++){
            float* Ec = E + (size_t)c*nb*512*128;
            unsigned short* skv_u = (unsigned short*)SS;            // nb*512*256 fp16
            float* att = SS + (size_t)nb*512*128;                    // after skv (f32 units)
            gemm_mfma<false,false,false,true><<<dim3(4, nb*512/128), 256, 0, stream>>>(
                Ec, s_kv_w + d*32768, nullptr, nullptr, skv_u, 256, 128);
            sattn<<<nb*256, 256, 0, stream>>>(
                Cb + (size_t)c*nb*512*128, skv_u, perm, bnd, maskn, gmap,
                s_bias + d*68, att, nb/8);
            gemm_mfma<true,false,true,false><<<dim3(2, nb*512/128), 256, 0, stream>>>(
                att, s_proj_w + d*16384, s_proj_b + d*128, Ec, Ec, 128, 128);
        }
        ln_kernel<<<12288, 256, 0, stream>>>(E, Cb, s_ln_g + d*128, s_ln_b + d*128);
        for(int c = 0; c < CH; c++){
            float* Ec = E + (size_t)c*rows*128;
            gemm_mfma<true,true,false,false><<<dim3(8, rows/128), 256, 0, stream>>>(
                Cb + (size_t)c*rows*128, s_ff_w1 + d*65536, s_ff_b1 + d*512,
                nullptr, SS, 512, 128);
            gemm_mfma<true,false,true,false><<<dim3(2, rows/128), 256, 0, stream>>>(
                SS, s_ff_w2 + d*65536, s_ff_b2 + d*128, Ec, Ec, 128, 512);
        }
    }

    finalt<<<2048, 128, 0, stream>>>(E, (float*)d_out);
}

// Round 10
// 1608.229 us; speedup vs baseline: 2.9171x; 1.1051x over previous
//
#include <hip/hip_runtime.h>
#include <math.h>

// B=4, C=128, N=512, T=24, D=2, H=4, hd=32, WS=12, R=17, MLP=512
#define TOK 6291456   // 49152 * 128 floats (one full token buffer)

typedef _Float16 half8 __attribute__((ext_vector_type(8)));
typedef _Float16 h8 __attribute__((ext_vector_type(8)));
typedef __fp16 fp16x2 __attribute__((ext_vector_type(2)));
typedef __attribute__((ext_vector_type(4))) float f32x4;

__device__ __forceinline__ float gelu_exact(float x){
    return 0.5f * x * (1.0f + erff(x * 0.70710678118654752f));
}
__device__ __forceinline__ unsigned short f2h(float f){
    return __builtin_bit_cast(unsigned short, (_Float16)f);
}
__device__ __forceinline__ int pk2(float a, float b){
    fp16x2 t = __builtin_amdgcn_cvt_pkrtz(a, b);
    return __builtin_bit_cast(int, t);
}

// ---------------------------------------------------------------------------
// s_mask normalizer (probe first 8704 bytes only; classify u8/i32/f32 layout)
// ---------------------------------------------------------------------------
__global__ void normalize_mask(const unsigned char* __restrict__ raw,
                               unsigned char* __restrict__ outm){
    __shared__ int nz[4];
    if(threadIdx.x < 4) nz[threadIdx.x] = 0;
    __syncthreads();
    for(int i = threadIdx.x; i < 8704; i += 256){
        if(raw[i]) atomicOr(&nz[i & 3], 1);
    }
    __syncthreads();
    int mode; // 0=u8, 1=i32, 2=f32
    if(nz[1] | nz[2] | nz[3]) mode = nz[0] ? 0 : 2;
    else                      mode = 1;
    for(int i = threadIdx.x; i < 8704; i += 256){
        unsigned char v;
        if(mode == 0)      v = (raw[i] != 0);
        else if(mode == 1) v = (raw[4*i] != 0);
        else               v = ((raw[4*i+2] | raw[4*i+3]) != 0);
        outm[i] = v;
    }
}

// sec[m][n] = argmax_r assignment[m][n][r]  (exact one-hot f32)
__global__ void build_sec(const float* __restrict__ assign,
                          unsigned char* __restrict__ sec){
    int id = blockIdx.x * 256 + threadIdx.x;
    if(id >= 512*512) return;
    const float* p = assign + (size_t)id * 17;
    int rr = 0;
    #pragma unroll
    for(int r = 0; r < 17; r++) if(p[r] > 0.5f) rr = r;
    sec[id] = (unsigned char)rr;
}

// counting sort of each sec row -> perm/bnd, plus greedy LPT bucket->wave map
__global__ __launch_bounds__(64) void build_perm(const unsigned char* __restrict__ sec,
                                                 const unsigned char* __restrict__ maskn,
                                                 unsigned short* __restrict__ perm,
                                                 int* __restrict__ bnd,
                                                 unsigned char* __restrict__ gmap){
    __shared__ unsigned char row[512];
    __shared__ int cnts[17];
    int m = blockIdx.x;
    int lane = threadIdx.x;
    for(int i = lane; i < 512; i += 64) row[i] = sec[m*512 + i];
    __syncthreads();
    int cnt = 0;
    if(lane < 17){
        for(int n = 0; n < 512; n++) cnt += (row[n] == lane);
        cnts[lane] = cnt;
    }
    int incl = cnt;
    for(int i = 1; i < 32; i <<= 1){
        int v = __shfl_up(incl, i);
        if(lane >= i) incl += v;
    }
    int start = incl - cnt;
    if(lane < 18) bnd[m*18 + lane] = start;
    if(lane < 17){
        int idx = start;
        for(int n = 0; n < 512; n++)
            if(row[n] == lane) perm[m*512 + (idx++)] = (unsigned short)n;
    }
    __syncthreads();
    if(lane == 0){
        int   sz[17]; int used[17]; int load[4] = {0,0,0,0};
        unsigned char gm[17];
        for(int r = 0; r < 17; r++){
            sz[r] = maskn[m*17 + r] ? 0 : cnts[r];
            used[r] = 0; gm[r] = 0;
        }
        for(int it = 0; it < 17; it++){
            int best = -1, bs = -1;
            for(int r = 0; r < 17; r++)
                if(!used[r] && sz[r] > bs){ bs = sz[r]; best = r; }
            int bin = 0;
            for(int g = 1; g < 4; g++) if(load[g] < load[bin]) bin = g;
            used[best] = 1; gm[best] = (unsigned char)bin; load[bin] += sz[best];
        }
        for(int r = 0; r < 17; r++) gmap[m*17 + r] = gm[r];
    }
}

// ---------------------------------------------------------------------------
// weight prep: convert all 18 weight matrices (f32 [K][N]) to fp16 [N][K].
// segment table hard-coded; 786432 output halves total.
// ---------------------------------------------------------------------------
__global__ void wprep(const float* __restrict__ qkv, const float* __restrict__ tproj,
                      const float* __restrict__ tff1, const float* __restrict__ tff2,
                      const float* __restrict__ sq,   const float* __restrict__ skv,
                      const float* __restrict__ sproj,const float* __restrict__ sff1,
                      const float* __restrict__ sff2, unsigned short* __restrict__ wt){
    const int base[19] = {0,49152,98304,114688,131072,196608,262144,327680,
                          393216,409600,425984,458752,491520,507904,524288,
                          589824,655360,720896,786432};
    for(int gid = blockIdx.x*256 + threadIdx.x; gid < 786432; gid += gridDim.x*256){
        int seg = 0;
        while(gid >= base[seg+1]) seg++;
        int local = gid - base[seg];
        const float* src; int logK;
        switch(seg >> 1){
            case 0: src = qkv;   logK = 7; break;
            case 1: src = tproj; logK = 7; break;
            case 2: src = tff1;  logK = 7; break;
            case 3: src = tff2;  logK = 9; break;
            case 4: src = sq;    logK = 7; break;
            case 5: src = skv;   logK = 7; break;
            case 6: src = sproj; logK = 7; break;
            case 7: src = sff1;  logK = 7; break;
            default: src = sff2; logK = 9; break;
        }
        int sz = base[seg+1] - base[seg];
        int K = 1 << logK, N = sz >> logK;
        src += (seg & 1) * sz;
        int n = local >> logK, k = local & (K - 1);
        wt[gid] = f2h(src[k*N + n]);
    }
}

// h[(b*N+n)*T+t][c] = x[b][c][n][t] + pos_emb[t][c]
__global__ __launch_bounds__(128) void stage0(const float* __restrict__ x,
                                              const float* __restrict__ pos,
                                              float* __restrict__ h){
    __shared__ float l[128*25];
    int bid = blockIdx.x;
    int b = bid >> 9, n = bid & 511;
    int tid = threadIdx.x;
    const float* xb = x + (size_t)b*1572864 + (size_t)n*24;
    for(int it = 0; it < 24; it++){
        int i = it*128 + tid;
        int c = i / 24, t = i % 24;
        l[c*25 + t] = xb[(size_t)c*12288 + t];
    }
    __syncthreads();
    float* hb = h + ((size_t)(b*512 + n)) * 24 * 128;
    for(int t = 0; t < 24; t++){
        hb[t*128 + tid] = l[tid*25 + t] + pos[t*128 + tid];
    }
}

// E[(b*T+t)*N+n][c] = A[(b*N+n)*T+t][c]
__global__ void t2s(const float* __restrict__ a, float* __restrict__ e){
    size_t idx = (size_t)blockIdx.x * 256 + threadIdx.x;
    int c = (int)(idx & 127);
    size_t rest = idx >> 7;
    int n = (int)(rest & 511); rest >>= 9;
    int t = (int)(rest % 24);
    int b = (int)(rest / 24);
    e[idx] = a[(((size_t)(b*512 + n))*24 + t)*128 + c];
}

// out[b][c][n][t] = E[(b*T+t)*N+n][c]
__global__ __launch_bounds__(128) void finalt(const float* __restrict__ e,
                                              float* __restrict__ out){
    __shared__ float l[128*25];
    int bid = blockIdx.x;
    int b = bid >> 9, n = bid & 511;
    int tid = threadIdx.x;
    for(int t = 0; t < 24; t++){
        l[tid*25 + t] = e[(((size_t)(b*24 + t))*512 + n)*128 + tid];
    }
    __syncthreads();
    float* ob = out + (size_t)b*1572864 + (size_t)n*24;
    for(int it = 0; it < 24; it++){
        int i = it*128 + tid;
        int c = i / 24, t = i % 24;
        ob[(size_t)c*12288 + t] = l[c*25 + t];
    }
}

// LayerNorm over C=128, one wave per token
__global__ __launch_bounds__(256) void ln_kernel(const float* __restrict__ in,
                                                 float* __restrict__ out,
                                                 const float* __restrict__ g,
                                                 const float* __restrict__ b){
    int w = threadIdx.x >> 6, lane = threadIdx.x & 63;
    int tok = blockIdx.x * 4 + w;
    const float* row = in + (size_t)tok * 128;
    float x0 = row[lane], x1 = row[lane + 64];
    float s  = x0 + x1;
    float s2 = x0*x0 + x1*x1;
    #pragma unroll
    for(int m = 1; m < 64; m <<= 1){
        s  += __shfl_xor(s,  m);
        s2 += __shfl_xor(s2, m);
    }
    float mean = s * (1.0f/128.0f);
    float var  = s2 * (1.0f/128.0f) - mean*mean;
    float rstd = rsqrtf(var + 1e-5f);
    float* o = out + (size_t)tok * 128;
    o[lane]      = (x0 - mean) * rstd * g[lane]      + b[lane];
    o[lane + 64] = (x1 - mean) * rstd * g[lane + 64] + b[lane + 64];
}

// ---------------------------------------------------------------------------
// fp16 MFMA GEMM v2: out[M,N] = A[M,K] @ W[K,N] (+bias)(+gelu)(+res).
// W is PRE-TRANSPOSED fp16 [N][K] (wprep). A f32 -> cvt_pkrtz -> LDS.
// Register prefetch pipeline: next k-tile loads overlap current MFMAs.
// 128x64 tile, 256 thr (4 waves), mfma_f32_16x16x32_f16, fp32 accum.
// ---------------------------------------------------------------------------
#define LDA 40
template<bool BIAS, bool GELU, bool RES, bool OF16>
__global__ __launch_bounds__(256) void gemm2(const float* __restrict__ A,
                                             const unsigned short* __restrict__ Wt,
                                             const float* __restrict__ bias,
                                             const float* __restrict__ res,
                                             void* __restrict__ outv,
                                             int N, int K){
    __shared__ unsigned short As[128*LDA];
    __shared__ unsigned short Ws[64*LDA];
    const int tid = threadIdx.x;
    const int w = tid >> 6, l = tid & 63;
    const int m0 = blockIdx.y * 128;
    const int n0 = blockIdx.x * 64;
    const int r  = tid >> 2;          // 0..63
    const int kq = (tid & 3) * 8;     // 0,8,16,24

    const float* ap0 = A + (size_t)(m0 + r)*K + kq;
    const float* ap1 = ap0 + (size_t)64*K;
    const unsigned short* wp = Wt + (size_t)(n0 + r)*K + kq;

    float4 a00 = *(const float4*)(ap0);
    float4 a01 = *(const float4*)(ap0 + 4);
    float4 a10 = *(const float4*)(ap1);
    float4 a11 = *(const float4*)(ap1 + 4);
    int4   wv  = *(const int4*)(wp);

    f32x4 acc[2][4];
    #pragma unroll
    for(int i = 0; i < 2; i++)
        #pragma unroll
        for(int nt = 0; nt < 4; nt++) acc[i][nt] = (f32x4){0.f,0.f,0.f,0.f};

    for(int k0 = 0; k0 < K; k0 += 32){
        __syncthreads();
        int4 pa0, pa1;
        pa0.x = pk2(a00.x, a00.y); pa0.y = pk2(a00.z, a00.w);
        pa0.z = pk2(a01.x, a01.y); pa0.w = pk2(a01.z, a01.w);
        pa1.x = pk2(a10.x, a10.y); pa1.y = pk2(a10.z, a10.w);
        pa1.z = pk2(a11.x, a11.y); pa1.w = pk2(a11.z, a11.w);
        *(int4*)(&As[r*LDA + kq])      = pa0;
        *(int4*)(&As[(r+64)*LDA + kq]) = pa1;
        *(int4*)(&Ws[r*LDA + kq])      = wv;
        __syncthreads();
        if(k0 + 32 < K){
            ap0 += 32; ap1 += 32; wp += 32;
            a00 = *(const float4*)(ap0);
            a01 = *(const float4*)(ap0 + 4);
            a10 = *(const float4*)(ap1);
            a11 = *(const float4*)(ap1 + 4);
            wv  = *(const int4*)(wp);
        }
        half8 fa0 = *(const half8*)(&As[(w*32      + (l & 15))*LDA + (l >> 4)*8]);
        half8 fa1 = *(const half8*)(&As[(w*32 + 16 + (l & 15))*LDA + (l >> 4)*8]);
        #pragma unroll
        for(int nt = 0; nt < 4; nt++){
            half8 b = *(const half8*)(&Ws[(nt*16 + (l & 15))*LDA + (l >> 4)*8]);
            acc[0][nt] = __builtin_amdgcn_mfma_f32_16x16x32_f16(fa0, b, acc[0][nt], 0, 0, 0);
            acc[1][nt] = __builtin_amdgcn_mfma_f32_16x16x32_f16(fa1, b, acc[1][nt], 0, 0, 0);
        }
    }

    // epilogue: C/D layout col=lane&15, row=(lane>>4)*4+reg
    const int col = l & 15, rg = l >> 4;
    #pragma unroll
    for(int i = 0; i < 2; i++){
        #pragma unroll
        for(int nt = 0; nt < 4; nt++){
            int n = n0 + nt*16 + col;
            float bv = BIAS ? bias[n] : 0.f;
            #pragma unroll
            for(int reg = 0; reg < 4; reg++){
                int m = m0 + w*32 + i*16 + rg*4 + reg;
                float v = acc[i][nt][reg] + bv;
                if(GELU) v = gelu_exact(v);
                if(RES)  v += res[(size_t)m*N + n];
                if(OF16) ((unsigned short*)outv)[(size_t)m*N + n] = f2h(v);
                else     ((float*)outv)[(size_t)m*N + n] = v;
            }
        }
    }
}

// temporal windowed causal attention; qkv rows [q|k|v] 384 wide
__global__ __launch_bounds__(256) void tattn(const float* __restrict__ qkv,
                                             float* __restrict__ out){
    __shared__ float l[12*388];
    int w = blockIdx.x;
    const float* src = qkv + (size_t)w * 12 * 384;
    for(int i = threadIdx.x; i < 12*384; i += 256){
        int q = i / 384, c = i % 384;
        l[q*388 + c] = src[i];
    }
    __syncthreads();
    int h = threadIdx.x >> 6, lane = threadIdx.x & 63;
    if(lane < 12){
        int q = lane;
        const float scale = 0.17677669529663687f;
        float qv[32];
        #pragma unroll
        for(int d = 0; d < 32; d++) qv[d] = l[q*388 + h*32 + d];
        float sc[12];
        #pragma unroll
        for(int k = 0; k < 12; k++){
            float dot = 0.f;
            #pragma unroll
            for(int d = 0; d < 32; d++) dot += qv[d] * l[k*388 + 128 + h*32 + d];
            sc[k] = (k <= q) ? dot * scale : -1e30f;
        }
        float mx = sc[0];
        #pragma unroll
        for(int k = 1; k < 12; k++) mx = fmaxf(mx, sc[k]);
        float sum = 0.f;
        #pragma unroll
        for(int k = 0; k < 12; k++){ sc[k] = expf(sc[k] - mx); sum += sc[k]; }
        float inv = 1.0f / sum;
        float* orow = out + (size_t)(w*12 + q) * 128 + h*32;
        #pragma unroll
        for(int d = 0; d < 32; d++){
            float o = 0.f;
            #pragma unroll
            for(int k = 0; k < 12; k++) o += sc[k] * l[k*388 + 256 + h*32 + d];
            orow[d] = o * inv;
        }
    }
}

// ---------------------------------------------------------------------------
// fused spatial attention; skv rows fp16 (256 ch = 512 B).
// Phase 2 v5: two rows per b128 load (half-waves), FOUR chains = 8 rows/iter.
// ---------------------------------------------------------------------------
__global__ __launch_bounds__(256) void sattn(const float* __restrict__ qbuf,
                                             const unsigned short* __restrict__ skv,
                                             const unsigned short* __restrict__ perm,
                                             const int* __restrict__ bnd,
                                             const unsigned char* __restrict__ mask,
                                             const unsigned char* __restrict__ gmap,
                                             const float* __restrict__ bias,
                                             float* __restrict__ out,
                                             int nb8){
    __shared__ _Float16 kvh[2][17][256];
    __shared__ float ql[2][128];
    __shared__ float lg[2][4][17];
    __shared__ float al[2][4][17];
    __shared__ __align__(16) unsigned short pml[2][512];
    __shared__ int bndl[2][18];
    __shared__ int mkl[2][17];
    __shared__ int gml[2][17];

    int bid = blockIdx.x;
    int b  = (bid & 7) * nb8 + ((bid >> 3) >> 8);   // XCD-grouped bt
    int m0 = ((bid >> 3) & 255) * 2;
    int tid = threadIdx.x;

    { int mi = tid >> 7, c = tid & 127;
      ql[mi][c] = qbuf[((size_t)(b*512 + m0 + mi))*128 + c]; }
    for(int i = tid; i < 1024; i += 256){
        int mi = i >> 9, j = i & 511;
        pml[mi][j] = perm[(m0 + mi)*512 + j];
    }
    if(tid < 36){ int mi = tid/18, r = tid%18; bndl[mi][r] = bnd[(m0+mi)*18 + r]; }
    if(tid < 34){ int mi = tid/17, r = tid%17; mkl[mi][r] = mask[(m0+mi)*17 + r]; }
    if(tid >= 64 && tid < 98){
        int j = tid - 64; int mi = j/17, r = j%17;
        gml[mi][r] = gmap[(m0+mi)*17 + r];
    }
    __syncthreads();

    // phase 2: segmented bucket sums; 2 rows/load, 4 chains (8 rows/iter)
    { int g = tid >> 6, lane = tid & 63;
      int half = lane >> 5, cl = lane & 31;
      const unsigned short* skvb = skv + (size_t)b*512*256 + cl*8;
      #pragma unroll
      for(int mi = 0; mi < 2; mi++){
          for(int r = 0; r < 17; r++){
              if(mkl[mi][r] || gml[mi][r] != g) continue;
              int s = bndl[mi][r], e = bndl[mi][r+1];
              h8 a0 = {0,0,0,0,0,0,0,0}, a1 = a0, a2 = a0, a3 = a0;
              int i = s;
              if(i < e && (i & 1)){              // peel to even index
                  if(half == 0)
                      a0 += *(const h8*)(skvb + (int)pml[mi][i] * 256);
                  i++;
              }
              for(; i + 8 <= e; i += 8){
                  ushort2 p0 = *(const ushort2*)(&pml[mi][i]);
                  ushort2 p1 = *(const ushort2*)(&pml[mi][i+2]);
                  ushort2 p2 = *(const ushort2*)(&pml[mi][i+4]);
                  ushort2 p3 = *(const ushort2*)(&pml[mi][i+6]);
                  a0 += *(const h8*)(skvb + (half ? (int)p0.y : (int)p0.x) * 256);
                  a1 += *(const h8*)(skvb + (half ? (int)p1.y : (int)p1.x) * 256);
                  a2 += *(const h8*)(skvb + (half ? (int)p2.y : (int)p2.x) * 256);
                  a3 += *(const h8*)(skvb + (half ? (int)p3.y : (int)p3.x) * 256);
              }
              if(i + 4 <= e){
                  ushort2 p0 = *(const ushort2*)(&pml[mi][i]);
                  ushort2 p1 = *(const ushort2*)(&pml[mi][i+2]);
                  a0 += *(const h8*)(skvb + (half ? (int)p0.y : (int)p0.x) * 256);
                  a1 += *(const h8*)(skvb + (half ? (int)p1.y : (int)p1.x) * 256);
                  i += 4;
              }
              if(i + 2 <= e){
                  ushort2 p0 = *(const ushort2*)(&pml[mi][i]);
                  a0 += *(const h8*)(skvb + (half ? (int)p0.y : (int)p0.x) * 256);
                  i += 2;
              }
              if(i < e){                          // single tail row
                  if(half == 0)
                      a0 += *(const h8*)(skvb + (int)pml[mi][i] * 256);
              }
              h8 t = (a0 + a1) + (a2 + a3);
              float4 f = __builtin_bit_cast(float4, t);
              float4 o;
              o.x = __shfl_xor(f.x, 32);
              o.y = __shfl_xor(f.y, 32);
              o.z = __shfl_xor(f.z, 32);
              o.w = __shfl_xor(f.w, 32);
              t = t + __builtin_bit_cast(h8, o);
              if(half == 0)
                  *(h8*)(&kvh[mi][r][cl*8]) = t;
          }
      }
    }
    __syncthreads();

    // phase 3: logits
    { int h = tid >> 6; int mi = (tid >> 5) & 1; int d = tid & 31;
      float qv = ql[mi][h*32 + d];
      for(int r = 0; r < 17; r++){
          if(mkl[mi][r]) continue;
          float v = qv * (float)kvh[mi][r][h*32 + d];
          v += __shfl_xor(v, 16); v += __shfl_xor(v, 8);
          v += __shfl_xor(v, 4);  v += __shfl_xor(v, 2); v += __shfl_xor(v, 1);
          if(d == 0) lg[mi][h][r] = v * 0.17677669529663687f + bias[h*17 + r];
      }
    }
    __syncthreads();

    // phase 4: softmax over unmasked r
    if(tid < 8){
        int mi = tid >> 2, h = tid & 3;
        float mx = -1e30f;
        for(int r = 0; r < 17; r++) if(!mkl[mi][r]) mx = fmaxf(mx, lg[mi][h][r]);
        float sum = 0.f;
        for(int r = 0; r < 17; r++){
            if(!mkl[mi][r]){ float e = expf(lg[mi][h][r] - mx); al[mi][h][r] = e; sum += e; }
            else al[mi][h][r] = 0.f;
        }
        float inv = 1.0f / sum;
        for(int r = 0; r < 17; r++) al[mi][h][r] *= inv;
    }
    __syncthreads();

    // phase 5: out = sum_r a[r] * V[r]
    { int mi = tid >> 7, c = tid & 127, h = c >> 5;
      float o = 0.f;
      for(int r = 0; r < 17; r++){
          if(mkl[mi][r]) continue;
          o += al[mi][h][r] * (float)kvh[mi][r][128 + c];
      }
      out[((size_t)(b*512 + m0 + mi))*128 + c] = o;
    }
}

// ---------------------------------------------------------------------------
extern "C" void kernel_launch(void* const* d_in, const int* in_sizes, int n_in,
                              void* d_out, int out_size, void* d_ws, size_t ws_size,
                              hipStream_t stream){
    const float* x        = (const float*)d_in[0];
    const float* pos      = (const float*)d_in[1];
    const float* t_qkv_w  = (const float*)d_in[2];
    const float* t_proj_w = (const float*)d_in[3];
    const float* t_proj_b = (const float*)d_in[4];
    const float* t_ln_g   = (const float*)d_in[5];
    const float* t_ln_b   = (const float*)d_in[6];
    const float* t_ff_w1  = (const float*)d_in[7];
    const float* t_ff_b1  = (const float*)d_in[8];
    const float* t_ff_w2  = (const float*)d_in[9];
    const float* t_ff_b2  = (const float*)d_in[10];
    const float* assign   = (const float*)d_in[11];
    const unsigned char* s_mask_raw = (const unsigned char*)d_in[12];  // dict order!
    const float* s_q_w    = (const float*)d_in[13];
    const float* s_kv_w   = (const float*)d_in[14];
    const float* s_bias   = (const float*)d_in[15];
    const float* s_proj_w = (const float*)d_in[16];
    const float* s_proj_b = (const float*)d_in[17];
    const float* s_ln_g   = (const float*)d_in[18];
    const float* s_ln_b   = (const float*)d_in[19];
    const float* s_ff_w1  = (const float*)d_in[20];
    const float* s_ff_b1  = (const float*)d_in[21];
    const float* s_ff_w2  = (const float*)d_in[22];
    const float* s_ff_b2  = (const float*)d_in[23];

    float* ws = (float*)d_ws;
    float* Cb = (float*)d_out;   // reused as full-M scratch (q buf / LN out)

    const int CH = (ws_size >= (size_t)168*1024*1024) ? 1 : 4;
    float* A  = ws;
    float* TS = ws + TOK;
    float* E  = (CH==1) ? (ws + 5*(size_t)TOK) : (ws + TOK);
    float* SS = (CH==1) ? TS : A;
    char*  sb = (char*)(ws + ((CH==1)? 6*(size_t)TOK : 2*(size_t)TOK));
    unsigned char*  sec   = (unsigned char*)sb;              // 262144 B
    unsigned short* perm  = (unsigned short*)(sb + 262144);  // 524288 B
    int*            bnd   = (int*)(sb + 786432);             // 36864 B
    unsigned char*  maskn = (unsigned char*)(sb + 823296);   // 8704 B
    unsigned char*  gmap  = (unsigned char*)(sb + 832000);   // 8704 B
    unsigned short* wt    = (unsigned short*)(sb + 1048576); // 1572864 B fp16 weights

    const int rows = 49152 / CH;       // M rows per chunk (multiple of 128)
    const int nb   = 96 / CH;          // bt values per spatial chunk

    wprep<<<1024, 256, 0, stream>>>(t_qkv_w, t_proj_w, t_ff_w1, t_ff_w2,
                                    s_q_w, s_kv_w, s_proj_w, s_ff_w1, s_ff_w2, wt);
    normalize_mask<<<1, 256, 0, stream>>>(s_mask_raw, maskn);
    build_sec<<<1024, 256, 0, stream>>>(assign, sec);
    build_perm<<<512, 64, 0, stream>>>(sec, maskn, perm, bnd, gmap);
    stage0<<<2048, 128, 0, stream>>>(x, pos, A);

    for(int d = 0; d < 2; d++){
        for(int c = 0; c < CH; c++){
            const float* Ac = A + (size_t)c*rows*128;
            gemm2<false,false,false,false><<<dim3(6, rows/128), 256, 0, stream>>>(
                Ac, wt + d*49152, nullptr, nullptr, TS, 384, 128);
            tattn<<<rows/12, 256, 0, stream>>>(TS, Cb + (size_t)c*rows*128);
        }
        gemm2<true,false,true,false><<<dim3(2,384), 256, 0, stream>>>(
            Cb, wt + 98304 + d*16384, t_proj_b + d*128, A, A, 128, 128);
        ln_kernel<<<12288, 256, 0, stream>>>(A, Cb, t_ln_g + d*128, t_ln_b + d*128);
        for(int c = 0; c < CH; c++){
            float* Ac = A + (size_t)c*rows*128;
            gemm2<true,true,false,false><<<dim3(8, rows/128), 256, 0, stream>>>(
                Cb + (size_t)c*rows*128, wt + 131072 + d*65536, t_ff_b1 + d*512,
                nullptr, TS, 512, 128);
            gemm2<true,false,true,false><<<dim3(2, rows/128), 256, 0, stream>>>(
                TS, wt + 262144 + d*65536, t_ff_b2 + d*128, Ac, Ac, 128, 512);
        }
    }

    t2s<<<24576, 256, 0, stream>>>(A, E);

    for(int d = 0; d < 2; d++){
        gemm2<false,false,false,false><<<dim3(2,384), 256, 0, stream>>>(
            E, wt + 393216 + d*16384, nullptr, nullptr, Cb, 128, 128);
        for(int c = 0; c < CH; c++){
            float* Ec = E + (size_t)c*nb*512*128;
            unsigned short* skv_u = (unsigned short*)SS;            // nb*512*256 fp16
            float* att = SS + (size_t)nb*512*128;                    // after skv (f32 units)
            gemm2<false,false,false,true><<<dim3(4, nb*512/128), 256, 0, stream>>>(
                Ec, wt + 425984 + d*32768, nullptr, nullptr, skv_u, 256, 128);
            sattn<<<nb*256, 256, 0, stream>>>(
                Cb + (size_t)c*nb*512*128, skv_u, perm, bnd, maskn, gmap,
                s_bias + d*68, att, nb/8);
            gemm2<true,false,true,false><<<dim3(2, nb*512/128), 256, 0, stream>>>(
                att, wt + 491520 + d*16384, s_proj_b + d*128, Ec, Ec, 128, 128);
        }
        ln_kernel<<<12288, 256, 0, stream>>>(E, Cb, s_ln_g + d*128, s_ln_b + d*128);
        for(int c = 0; c < CH; c++){
            float* Ec = E + (size_t)c*rows*128;
            gemm2<true,true,false,false><<<dim3(8, rows/128), 256, 0, stream>>>(
                Cb + (size_t)c*rows*128, wt + 524288 + d*65536, s_ff_b1 + d*512,
                nullptr, SS, 512, 128);
            gemm2<true,false,true,false><<<dim3(2, rows/128), 256, 0, stream>>>(
                SS, wt + 655360 + d*65536, s_ff_b2 + d*128, Ec, Ec, 128, 512);
        }
    }

    finalt<<<2048, 128, 0, stream>>>(E, (float*)d_out);
}

// Round 11
// 1416.424 us; speedup vs baseline: 3.3121x; 1.1354x over previous
//
#include <hip/hip_runtime.h>
#include <math.h>

// B=4, C=128, N=512, T=24, D=2, H=4, hd=32, WS=12, R=17, MLP=512
#define TOK 6291456   // element count of one token buffer (now fp16 halves)

typedef _Float16 half8 __attribute__((ext_vector_type(8)));
typedef _Float16 h8 __attribute__((ext_vector_type(8)));
typedef __attribute__((ext_vector_type(4))) float f32x4;

__device__ __forceinline__ float gelu_exact(float x){
    return 0.5f * x * (1.0f + erff(x * 0.70710678118654752f));
}
__device__ __forceinline__ unsigned short f2h(float f){
    return __builtin_bit_cast(unsigned short, (_Float16)f);
}
__device__ __forceinline__ float h2f(unsigned short s){
    return (float)__builtin_bit_cast(_Float16, s);
}

// ---------------------------------------------------------------------------
// s_mask normalizer (probe first 8704 bytes only; classify u8/i32/f32 layout)
// ---------------------------------------------------------------------------
__global__ void normalize_mask(const unsigned char* __restrict__ raw,
                               unsigned char* __restrict__ outm){
    __shared__ int nz[4];
    if(threadIdx.x < 4) nz[threadIdx.x] = 0;
    __syncthreads();
    for(int i = threadIdx.x; i < 8704; i += 256){
        if(raw[i]) atomicOr(&nz[i & 3], 1);
    }
    __syncthreads();
    int mode; // 0=u8, 1=i32, 2=f32
    if(nz[1] | nz[2] | nz[3]) mode = nz[0] ? 0 : 2;
    else                      mode = 1;
    for(int i = threadIdx.x; i < 8704; i += 256){
        unsigned char v;
        if(mode == 0)      v = (raw[i] != 0);
        else if(mode == 1) v = (raw[4*i] != 0);
        else               v = ((raw[4*i+2] | raw[4*i+3]) != 0);
        outm[i] = v;
    }
}

// sec[m][n] = argmax_r assignment[m][n][r]  (exact one-hot f32)
__global__ void build_sec(const float* __restrict__ assign,
                          unsigned char* __restrict__ sec){
    int id = blockIdx.x * 256 + threadIdx.x;
    if(id >= 512*512) return;
    const float* p = assign + (size_t)id * 17;
    int rr = 0;
    #pragma unroll
    for(int r = 0; r < 17; r++) if(p[r] > 0.5f) rr = r;
    sec[id] = (unsigned char)rr;
}

// counting sort of each sec row -> perm/bnd, plus greedy LPT bucket->wave map
__global__ __launch_bounds__(64) void build_perm(const unsigned char* __restrict__ sec,
                                                 const unsigned char* __restrict__ maskn,
                                                 unsigned short* __restrict__ perm,
                                                 int* __restrict__ bnd,
                                                 unsigned char* __restrict__ gmap){
    __shared__ unsigned char row[512];
    __shared__ int cnts[17];
    int m = blockIdx.x;
    int lane = threadIdx.x;
    for(int i = lane; i < 512; i += 64) row[i] = sec[m*512 + i];
    __syncthreads();
    int cnt = 0;
    if(lane < 17){
        for(int n = 0; n < 512; n++) cnt += (row[n] == lane);
        cnts[lane] = cnt;
    }
    int incl = cnt;
    for(int i = 1; i < 32; i <<= 1){
        int v = __shfl_up(incl, i);
        if(lane >= i) incl += v;
    }
    int start = incl - cnt;
    if(lane < 18) bnd[m*18 + lane] = start;
    if(lane < 17){
        int idx = start;
        for(int n = 0; n < 512; n++)
            if(row[n] == lane) perm[m*512 + (idx++)] = (unsigned short)n;
    }
    __syncthreads();
    if(lane == 0){
        int   sz[17]; int used[17]; int load[4] = {0,0,0,0};
        unsigned char gm[17];
        for(int r = 0; r < 17; r++){
            sz[r] = maskn[m*17 + r] ? 0 : cnts[r];
            used[r] = 0; gm[r] = 0;
        }
        for(int it = 0; it < 17; it++){
            int best = -1, bs = -1;
            for(int r = 0; r < 17; r++)
                if(!used[r] && sz[r] > bs){ bs = sz[r]; best = r; }
            int bin = 0;
            for(int g = 1; g < 4; g++) if(load[g] < load[bin]) bin = g;
            used[best] = 1; gm[best] = (unsigned char)bin; load[bin] += sz[best];
        }
        for(int r = 0; r < 17; r++) gmap[m*17 + r] = gm[r];
    }
}

// ---------------------------------------------------------------------------
// weight prep: convert all 18 weight matrices (f32 [K][N]) to fp16 [N][K].
// ---------------------------------------------------------------------------
__global__ void wprep(const float* __restrict__ qkv, const float* __restrict__ tproj,
                      const float* __restrict__ tff1, const float* __restrict__ tff2,
                      const float* __restrict__ sq,   const float* __restrict__ skv,
                      const float* __restrict__ sproj,const float* __restrict__ sff1,
                      const float* __restrict__ sff2, unsigned short* __restrict__ wt){
    const int base[19] = {0,49152,98304,114688,131072,196608,262144,327680,
                          393216,409600,425984,458752,491520,507904,524288,
                          589824,655360,720896,786432};
    for(int gid = blockIdx.x*256 + threadIdx.x; gid < 786432; gid += gridDim.x*256){
        int seg = 0;
        while(gid >= base[seg+1]) seg++;
        int local = gid - base[seg];
        const float* src; int logK;
        switch(seg >> 1){
            case 0: src = qkv;   logK = 7; break;
            case 1: src = tproj; logK = 7; break;
            case 2: src = tff1;  logK = 7; break;
            case 3: src = tff2;  logK = 9; break;
            case 4: src = sq;    logK = 7; break;
            case 5: src = skv;   logK = 7; break;
            case 6: src = sproj; logK = 7; break;
            case 7: src = sff1;  logK = 7; break;
            default: src = sff2; logK = 9; break;
        }
        int sz = base[seg+1] - base[seg];
        int K = 1 << logK, N = sz >> logK;
        src += (seg & 1) * sz;
        int n = local >> logK, k = local & (K - 1);
        wt[gid] = f2h(src[k*N + n]);
    }
}

// h[(b*N+n)*T+t][c] = fp16( x[b][c][n][t] + pos_emb[t][c] )
__global__ __launch_bounds__(128) void stage0(const float* __restrict__ x,
                                              const float* __restrict__ pos,
                                              unsigned short* __restrict__ h){
    __shared__ float l[128*25];
    int bid = blockIdx.x;
    int b = bid >> 9, n = bid & 511;
    int tid = threadIdx.x;
    const float* xb = x + (size_t)b*1572864 + (size_t)n*24;
    for(int it = 0; it < 24; it++){
        int i = it*128 + tid;
        int c = i / 24, t = i % 24;
        l[c*25 + t] = xb[(size_t)c*12288 + t];
    }
    __syncthreads();
    unsigned short* hb = h + ((size_t)(b*512 + n)) * 24 * 128;
    for(int t = 0; t < 24; t++){
        hb[t*128 + tid] = f2h(l[tid*25 + t] + pos[t*128 + tid]);
    }
}

// E[(b*T+t)*N+n][c] = A[(b*N+n)*T+t][c]  (fp16)
__global__ void t2s(const unsigned short* __restrict__ a,
                    unsigned short* __restrict__ e){
    size_t idx = (size_t)blockIdx.x * 256 + threadIdx.x;
    int c = (int)(idx & 127);
    size_t rest = idx >> 7;
    int n = (int)(rest & 511); rest >>= 9;
    int t = (int)(rest % 24);
    int b = (int)(rest / 24);
    e[idx] = a[(((size_t)(b*512 + n))*24 + t)*128 + c];
}

// out[b][c][n][t] = f32( E[(b*T+t)*N+n][c] )
__global__ __launch_bounds__(128) void finalt(const unsigned short* __restrict__ e,
                                              float* __restrict__ out){
    __shared__ float l[128*25];
    int bid = blockIdx.x;
    int b = bid >> 9, n = bid & 511;
    int tid = threadIdx.x;
    for(int t = 0; t < 24; t++){
        l[tid*25 + t] = h2f(e[(((size_t)(b*24 + t))*512 + n)*128 + tid]);
    }
    __syncthreads();
    float* ob = out + (size_t)b*1572864 + (size_t)n*24;
    for(int it = 0; it < 24; it++){
        int i = it*128 + tid;
        int c = i / 24, t = i % 24;
        ob[(size_t)c*12288 + t] = l[c*25 + t];
    }
}

// LayerNorm over C=128, fp16 in/out, fp32 math; one wave per token
__global__ __launch_bounds__(256) void ln_kernel(const unsigned short* __restrict__ in,
                                                 unsigned short* __restrict__ out,
                                                 const float* __restrict__ g,
                                                 const float* __restrict__ b){
    int w = threadIdx.x >> 6, lane = threadIdx.x & 63;
    int tok = blockIdx.x * 4 + w;
    const unsigned short* row = in + (size_t)tok * 128;
    float x0 = h2f(row[lane]), x1 = h2f(row[lane + 64]);
    float s  = x0 + x1;
    float s2 = x0*x0 + x1*x1;
    #pragma unroll
    for(int m = 1; m < 64; m <<= 1){
        s  += __shfl_xor(s,  m);
        s2 += __shfl_xor(s2, m);
    }
    float mean = s * (1.0f/128.0f);
    float var  = s2 * (1.0f/128.0f) - mean*mean;
    float rstd = rsqrtf(var + 1e-5f);
    unsigned short* o = out + (size_t)tok * 128;
    o[lane]      = f2h((x0 - mean) * rstd * g[lane]      + b[lane]);
    o[lane + 64] = f2h((x1 - mean) * rstd * g[lane + 64] + b[lane + 64]);
}

// ---------------------------------------------------------------------------
// fp16 MFMA GEMM v3: out = A @ W (+bias)(+gelu)(+res). ALL fp16 operands:
// A fp16 [M][K], W pre-transposed fp16 [N][K], res/out fp16. fp32 accum.
// Staging is pure b128 copy (no cvt). Register prefetch overlaps next k-tile.
// 128x64 tile, 256 thr (4 waves), mfma_f32_16x16x32_f16.
// ---------------------------------------------------------------------------
#define LDA 40
template<bool BIAS, bool GELU, bool RES>
__global__ __launch_bounds__(256) void gemm3(const unsigned short* __restrict__ A,
                                             const unsigned short* __restrict__ Wt,
                                             const float* __restrict__ bias,
                                             const unsigned short* __restrict__ res,
                                             unsigned short* __restrict__ out,
                                             int N, int K){
    __shared__ unsigned short As[128*LDA];
    __shared__ unsigned short Ws[64*LDA];
    const int tid = threadIdx.x;
    const int w = tid >> 6, l = tid & 63;
    const int m0 = blockIdx.y * 128;
    const int n0 = blockIdx.x * 64;
    const int r  = tid >> 2;          // 0..63
    const int kq = (tid & 3) * 8;     // 0,8,16,24

    const unsigned short* ap0 = A + (size_t)(m0 + r)*K + kq;
    const unsigned short* ap1 = ap0 + (size_t)64*K;
    const unsigned short* wp  = Wt + (size_t)(n0 + r)*K + kq;

    int4 av0 = *(const int4*)(ap0);
    int4 av1 = *(const int4*)(ap1);
    int4 wv  = *(const int4*)(wp);

    f32x4 acc[2][4];
    #pragma unroll
    for(int i = 0; i < 2; i++)
        #pragma unroll
        for(int nt = 0; nt < 4; nt++) acc[i][nt] = (f32x4){0.f,0.f,0.f,0.f};

    for(int k0 = 0; k0 < K; k0 += 32){
        __syncthreads();
        *(int4*)(&As[r*LDA + kq])      = av0;
        *(int4*)(&As[(r+64)*LDA + kq]) = av1;
        *(int4*)(&Ws[r*LDA + kq])      = wv;
        __syncthreads();
        if(k0 + 32 < K){
            ap0 += 32; ap1 += 32; wp += 32;
            av0 = *(const int4*)(ap0);
            av1 = *(const int4*)(ap1);
            wv  = *(const int4*)(wp);
        }
        half8 fa0 = *(const half8*)(&As[(w*32      + (l & 15))*LDA + (l >> 4)*8]);
        half8 fa1 = *(const half8*)(&As[(w*32 + 16 + (l & 15))*LDA + (l >> 4)*8]);
        #pragma unroll
        for(int nt = 0; nt < 4; nt++){
            half8 b = *(const half8*)(&Ws[(nt*16 + (l & 15))*LDA + (l >> 4)*8]);
            acc[0][nt] = __builtin_amdgcn_mfma_f32_16x16x32_f16(fa0, b, acc[0][nt], 0, 0, 0);
            acc[1][nt] = __builtin_amdgcn_mfma_f32_16x16x32_f16(fa1, b, acc[1][nt], 0, 0, 0);
        }
    }

    // epilogue: C/D layout col=lane&15, row=(lane>>4)*4+reg
    const int col = l & 15, rg = l >> 4;
    #pragma unroll
    for(int i = 0; i < 2; i++){
        #pragma unroll
        for(int nt = 0; nt < 4; nt++){
            int n = n0 + nt*16 + col;
            float bv = BIAS ? bias[n] : 0.f;
            #pragma unroll
            for(int reg = 0; reg < 4; reg++){
                int m = m0 + w*32 + i*16 + rg*4 + reg;
                float v = acc[i][nt][reg] + bv;
                if(GELU) v = gelu_exact(v);
                if(RES)  v += h2f(res[(size_t)m*N + n]);
                out[(size_t)m*N + n] = f2h(v);
            }
        }
    }
}

// temporal windowed causal attention; qkv fp16 rows [q|k|v] 384 wide
__global__ __launch_bounds__(256) void tattn(const unsigned short* __restrict__ qkv,
                                             unsigned short* __restrict__ out){
    __shared__ unsigned short l[12*388];
    int w = blockIdx.x;
    const unsigned short* src = qkv + (size_t)w * 12 * 384;
    for(int i = threadIdx.x; i < 1152; i += 256){
        int q = i / 96, c4 = i % 96;
        *(ushort4*)(&l[q*388 + c4*4]) = *(const ushort4*)(src + q*384 + c4*4);
    }
    __syncthreads();
    int h = threadIdx.x >> 6, lane = threadIdx.x & 63;
    if(lane < 12){
        int q = lane;
        const float scale = 0.17677669529663687f;
        float qv[32];
        #pragma unroll
        for(int d = 0; d < 32; d++) qv[d] = h2f(l[q*388 + h*32 + d]);
        float sc[12];
        #pragma unroll
        for(int k = 0; k < 12; k++){
            float dot = 0.f;
            #pragma unroll
            for(int d = 0; d < 32; d++) dot += qv[d] * h2f(l[k*388 + 128 + h*32 + d]);
            sc[k] = (k <= q) ? dot * scale : -1e30f;
        }
        float mx = sc[0];
        #pragma unroll
        for(int k = 1; k < 12; k++) mx = fmaxf(mx, sc[k]);
        float sum = 0.f;
        #pragma unroll
        for(int k = 0; k < 12; k++){ sc[k] = expf(sc[k] - mx); sum += sc[k]; }
        float inv = 1.0f / sum;
        unsigned short* orow = out + (size_t)(w*12 + q) * 128 + h*32;
        #pragma unroll
        for(int d = 0; d < 32; d++){
            float o = 0.f;
            #pragma unroll
            for(int k = 0; k < 12; k++) o += sc[k] * h2f(l[k*388 + 256 + h*32 + d]);
            orow[d] = f2h(o * inv);
        }
    }
}

// ---------------------------------------------------------------------------
// fused spatial attention; skv rows fp16 (256 ch = 512 B), qbuf/out fp16.
// Phase 2: two rows per b128 load (half-waves), four chains = 8 rows/iter.
// ---------------------------------------------------------------------------
__global__ __launch_bounds__(256) void sattn(const unsigned short* __restrict__ qbuf,
                                             const unsigned short* __restrict__ skv,
                                             const unsigned short* __restrict__ perm,
                                             const int* __restrict__ bnd,
                                             const unsigned char* __restrict__ mask,
                                             const unsigned char* __restrict__ gmap,
                                             const float* __restrict__ bias,
                                             unsigned short* __restrict__ out,
                                             int nb8){
    __shared__ _Float16 kvh[2][17][256];
    __shared__ float ql[2][128];
    __shared__ float lg[2][4][17];
    __shared__ float al[2][4][17];
    __shared__ __align__(16) unsigned short pml[2][512];
    __shared__ int bndl[2][18];
    __shared__ int mkl[2][17];
    __shared__ int gml[2][17];

    int bid = blockIdx.x;
    int b  = (bid & 7) * nb8 + ((bid >> 3) >> 8);   // XCD-grouped bt
    int m0 = ((bid >> 3) & 255) * 2;
    int tid = threadIdx.x;

    { int mi = tid >> 7, c = tid & 127;
      ql[mi][c] = h2f(qbuf[((size_t)(b*512 + m0 + mi))*128 + c]); }
    for(int i = tid; i < 1024; i += 256){
        int mi = i >> 9, j = i & 511;
        pml[mi][j] = perm[(m0 + mi)*512 + j];
    }
    if(tid < 36){ int mi = tid/18, r = tid%18; bndl[mi][r] = bnd[(m0+mi)*18 + r]; }
    if(tid < 34){ int mi = tid/17, r = tid%17; mkl[mi][r] = mask[(m0+mi)*17 + r]; }
    if(tid >= 64 && tid < 98){
        int j = tid - 64; int mi = j/17, r = j%17;
        gml[mi][r] = gmap[(m0+mi)*17 + r];
    }
    __syncthreads();

    // phase 2: segmented bucket sums; 2 rows/load, 4 chains (8 rows/iter)
    { int g = tid >> 6, lane = tid & 63;
      int half = lane >> 5, cl = lane & 31;
      const unsigned short* skvb = skv + (size_t)b*512*256 + cl*8;
      #pragma unroll
      for(int mi = 0; mi < 2; mi++){
          for(int r = 0; r < 17; r++){
              if(mkl[mi][r] || gml[mi][r] != g) continue;
              int s = bndl[mi][r], e = bndl[mi][r+1];
              h8 a0 = {0,0,0,0,0,0,0,0}, a1 = a0, a2 = a0, a3 = a0;
              int i = s;
              if(i < e && (i & 1)){              // peel to even index
                  if(half == 0)
                      a0 += *(const h8*)(skvb + (int)pml[mi][i] * 256);
                  i++;
              }
              for(; i + 8 <= e; i += 8){
                  ushort2 p0 = *(const ushort2*)(&pml[mi][i]);
                  ushort2 p1 = *(const ushort2*)(&pml[mi][i+2]);
                  ushort2 p2 = *(const ushort2*)(&pml[mi][i+4]);
                  ushort2 p3 = *(const ushort2*)(&pml[mi][i+6]);
                  a0 += *(const h8*)(skvb + (half ? (int)p0.y : (int)p0.x) * 256);
                  a1 += *(const h8*)(skvb + (half ? (int)p1.y : (int)p1.x) * 256);
                  a2 += *(const h8*)(skvb + (half ? (int)p2.y : (int)p2.x) * 256);
                  a3 += *(const h8*)(skvb + (half ? (int)p3.y : (int)p3.x) * 256);
              }
              if(i + 4 <= e){
                  ushort2 p0 = *(const ushort2*)(&pml[mi][i]);
                  ushort2 p1 = *(const ushort2*)(&pml[mi][i+2]);
                  a0 += *(const h8*)(skvb + (half ? (int)p0.y : (int)p0.x) * 256);
                  a1 += *(const h8*)(skvb + (half ? (int)p1.y : (int)p1.x) * 256);
                  i += 4;
              }
              if(i + 2 <= e){
                  ushort2 p0 = *(const ushort2*)(&pml[mi][i]);
                  a0 += *(const h8*)(skvb + (half ? (int)p0.y : (int)p0.x) * 256);
                  i += 2;
              }
              if(i < e){                          // single tail row
                  if(half == 0)
                      a0 += *(const h8*)(skvb + (int)pml[mi][i] * 256);
              }
              h8 t = (a0 + a1) + (a2 + a3);
              float4 f = __builtin_bit_cast(float4, t);
              float4 o;
              o.x = __shfl_xor(f.x, 32);
              o.y = __shfl_xor(f.y, 32);
              o.z = __shfl_xor(f.z, 32);
              o.w = __shfl_xor(f.w, 32);
              t = t + __builtin_bit_cast(h8, o);
              if(half == 0)
                  *(h8*)(&kvh[mi][r][cl*8]) = t;
          }
      }
    }
    __syncthreads();

    // phase 3: logits
    { int h = tid >> 6; int mi = (tid >> 5) & 1; int d = tid & 31;
      float qv = ql[mi][h*32 + d];
      for(int r = 0; r < 17; r++){
          if(mkl[mi][r]) continue;
          float v = qv * (float)kvh[mi][r][h*32 + d];
          v += __shfl_xor(v, 16); v += __shfl_xor(v, 8);
          v += __shfl_xor(v, 4);  v += __shfl_xor(v, 2); v += __shfl_xor(v, 1);
          if(d == 0) lg[mi][h][r] = v * 0.17677669529663687f + bias[h*17 + r];
      }
    }
    __syncthreads();

    // phase 4: softmax over unmasked r
    if(tid < 8){
        int mi = tid >> 2, h = tid & 3;
        float mx = -1e30f;
        for(int r = 0; r < 17; r++) if(!mkl[mi][r]) mx = fmaxf(mx, lg[mi][h][r]);
        float sum = 0.f;
        for(int r = 0; r < 17; r++){
            if(!mkl[mi][r]){ float e = expf(lg[mi][h][r] - mx); al[mi][h][r] = e; sum += e; }
            else al[mi][h][r] = 0.f;
        }
        float inv = 1.0f / sum;
        for(int r = 0; r < 17; r++) al[mi][h][r] *= inv;
    }
    __syncthreads();

    // phase 5: out = sum_r a[r] * V[r]
    { int mi = tid >> 7, c = tid & 127, h = c >> 5;
      float o = 0.f;
      for(int r = 0; r < 17; r++){
          if(mkl[mi][r]) continue;
          o += al[mi][h][r] * (float)kvh[mi][r][128 + c];
      }
      out[((size_t)(b*512 + m0 + mi))*128 + c] = f2h(o);
    }
}

// ---------------------------------------------------------------------------
extern "C" void kernel_launch(void* const* d_in, const int* in_sizes, int n_in,
                              void* d_out, int out_size, void* d_ws, size_t ws_size,
                              hipStream_t stream){
    const float* x        = (const float*)d_in[0];
    const float* pos      = (const float*)d_in[1];
    const float* t_qkv_w  = (const float*)d_in[2];
    const float* t_proj_w = (const float*)d_in[3];
    const float* t_proj_b = (const float*)d_in[4];
    const float* t_ln_g   = (const float*)d_in[5];
    const float* t_ln_b   = (const float*)d_in[6];
    const float* t_ff_w1  = (const float*)d_in[7];
    const float* t_ff_b1  = (const float*)d_in[8];
    const float* t_ff_w2  = (const float*)d_in[9];
    const float* t_ff_b2  = (const float*)d_in[10];
    const float* assign   = (const float*)d_in[11];
    const unsigned char* s_mask_raw = (const unsigned char*)d_in[12];  // dict order!
    const float* s_q_w    = (const float*)d_in[13];
    const float* s_kv_w   = (const float*)d_in[14];
    const float* s_bias   = (const float*)d_in[15];
    const float* s_proj_w = (const float*)d_in[16];
    const float* s_proj_b = (const float*)d_in[17];
    const float* s_ln_g   = (const float*)d_in[18];
    const float* s_ln_b   = (const float*)d_in[19];
    const float* s_ff_w1  = (const float*)d_in[20];
    const float* s_ff_b1  = (const float*)d_in[21];
    const float* s_ff_w2  = (const float*)d_in[22];
    const float* s_ff_b2  = (const float*)d_in[23];

    float* ws = (float*)d_ws;
    // activation buffers are fp16 now but keep the float-unit byte offsets
    // (2x over-allocated) to preserve the proven layout.
    const int CH = (ws_size >= (size_t)168*1024*1024) ? 1 : 4;
    unsigned short* A  = (unsigned short*)ws;
    unsigned short* TS = (unsigned short*)(ws + TOK);
    unsigned short* E  = (unsigned short*)((CH==1) ? (ws + 5*(size_t)TOK) : (ws + TOK));
    unsigned short* SS = (CH==1) ? TS : A;
    unsigned short* Cb = (unsigned short*)d_out;  // fp16 scratch inside f32 d_out
    char*  sb = (char*)(ws + ((CH==1)? 6*(size_t)TOK : 2*(size_t)TOK));
    unsigned char*  sec   = (unsigned char*)sb;              // 262144 B
    unsigned short* perm  = (unsigned short*)(sb + 262144);  // 524288 B
    int*            bnd   = (int*)(sb + 786432);             // 36864 B
    unsigned char*  maskn = (unsigned char*)(sb + 823296);   // 8704 B
    unsigned char*  gmap  = (unsigned char*)(sb + 832000);   // 8704 B
    unsigned short* wt    = (unsigned short*)(sb + 1048576); // 1572864 B fp16 weights

    const int rows = 49152 / CH;       // M rows per chunk (multiple of 128)
    const int nb   = 96 / CH;          // bt values per spatial chunk

    wprep<<<1024, 256, 0, stream>>>(t_qkv_w, t_proj_w, t_ff_w1, t_ff_w2,
                                    s_q_w, s_kv_w, s_proj_w, s_ff_w1, s_ff_w2, wt);
    normalize_mask<<<1, 256, 0, stream>>>(s_mask_raw, maskn);
    build_sec<<<1024, 256, 0, stream>>>(assign, sec);
    build_perm<<<512, 64, 0, stream>>>(sec, maskn, perm, bnd, gmap);
    stage0<<<2048, 128, 0, stream>>>(x, pos, A);

    for(int d = 0; d < 2; d++){
        for(int c = 0; c < CH; c++){
            const unsigned short* Ac = A + (size_t)c*rows*128;
            gemm3<false,false,false><<<dim3(6, rows/128), 256, 0, stream>>>(
                Ac, wt + d*49152, nullptr, nullptr, TS, 384, 128);
            tattn<<<rows/12, 256, 0, stream>>>(TS, Cb + (size_t)c*rows*128);
        }
        gemm3<true,false,true><<<dim3(2,384), 256, 0, stream>>>(
            Cb, wt + 98304 + d*16384, t_proj_b + d*128, A, A, 128, 128);
        ln_kernel<<<12288, 256, 0, stream>>>(A, Cb, t_ln_g + d*128, t_ln_b + d*128);
        for(int c = 0; c < CH; c++){
            unsigned short* Ac = A + (size_t)c*rows*128;
            gemm3<true,true,false><<<dim3(8, rows/128), 256, 0, stream>>>(
                Cb + (size_t)c*rows*128, wt + 131072 + d*65536, t_ff_b1 + d*512,
                nullptr, TS, 512, 128);
            gemm3<true,false,true><<<dim3(2, rows/128), 256, 0, stream>>>(
                TS, wt + 262144 + d*65536, t_ff_b2 + d*128, Ac, Ac, 128, 512);
        }
    }

    t2s<<<24576, 256, 0, stream>>>(A, E);

    for(int d = 0; d < 2; d++){
        gemm3<false,false,false><<<dim3(2,384), 256, 0, stream>>>(
            E, wt + 393216 + d*16384, nullptr, nullptr, Cb, 128, 128);
        for(int c = 0; c < CH; c++){
            unsigned short* Ec = E + (size_t)c*nb*512*128;
            unsigned short* skv_u = SS;                              // nb*512*256 fp16
            unsigned short* att = (unsigned short*)((float*)SS + (size_t)nb*512*128);
            gemm3<false,false,false><<<dim3(4, nb*512/128), 256, 0, stream>>>(
                Ec, wt + 425984 + d*32768, nullptr, nullptr, skv_u, 256, 128);
            sattn<<<nb*256, 256, 0, stream>>>(
                Cb + (size_t)c*nb*512*128, skv_u, perm, bnd, maskn, gmap,
                s_bias + d*68, att, nb/8);
            gemm3<true,false,true><<<dim3(2, nb*512/128), 256, 0, stream>>>(
                att, wt + 491520 + d*16384, s_proj_b + d*128, Ec, Ec, 128, 128);
        }
        ln_kernel<<<12288, 256, 0, stream>>>(E, Cb, s_ln_g + d*128, s_ln_b + d*128);
        for(int c = 0; c < CH; c++){
            unsigned short* Ec = E + (size_t)c*rows*128;
            gemm3<true,true,false><<<dim3(8, rows/128), 256, 0, stream>>>(
                Cb + (size_t)c*rows*128, wt + 524288 + d*65536, s_ff_b1 + d*512,
                nullptr, SS, 512, 128);
            gemm3<true,false,true><<<dim3(2, rows/128), 256, 0, stream>>>(
                SS, wt + 655360 + d*65536, s_ff_b2 + d*128, Ec, Ec, 128, 512);
        }
    }

    finalt<<<2048, 128, 0, stream>>>(E, (float*)d_out);
}